// Round 13
// baseline (350.962 us; speedup 1.0000x reference)
//
#include <hip/hip_runtime.h>
#include <stdint.h>

#define T_LEN 1024
#define MEM_LEN 1024
#define C_LEN 2048
#define B_SZ 4
#define DM_ 1024
#define NH 16
#define HD 64

typedef __attribute__((ext_vector_type(8))) short short8;
typedef __attribute__((ext_vector_type(4))) float f32x4;
typedef __attribute__((ext_vector_type(4))) unsigned short ushort4v;
typedef __attribute__((ext_vector_type(4))) float float4v;

__device__ __forceinline__ unsigned short f2bf(float f) {
  union { float f; unsigned int u; } v; v.f = f;
  unsigned int r = v.u + 0x7fffu + ((v.u >> 16) & 1u);
  return (unsigned short)(r >> 16);
}
__device__ __forceinline__ float bf2f(unsigned short b) {
  union { unsigned int u; float f; } v; v.u = ((unsigned int)b) << 16;
  return v.f;
}
__device__ __forceinline__ f32x4 mfma16(short8 a, short8 b, f32x4 c) {
  return __builtin_amdgcn_mfma_f32_16x16x32_bf16(a, b, c, 0, 0, 0);
}

// ---------------- converts ----------------
__global__ void k_cat_convert(const float* __restrict__ m, const float* __restrict__ h,
                              unsigned short* __restrict__ outB) {
  int idx = blockIdx.x * 256 + threadIdx.x;
  const int MQ = (MEM_LEN * B_SZ * DM_) / 4;
  float4v v;
  if (idx < MQ) v = ((const float4v*)m)[idx];
  else          v = ((const float4v*)h)[idx - MQ];
  ushort4v o;
  o.x = f2bf(v.x); o.y = f2bf(v.y); o.z = f2bf(v.z); o.w = f2bf(v.w);
  ((ushort4v*)outB)[idx] = o;
}

__global__ void k_f32_to_bf16(const float* __restrict__ in, unsigned short* __restrict__ outB, int nq) {
  int idx = blockIdx.x * 256 + threadIdx.x;
  if (idx >= nq) return;
  float4v v = ((const float4v*)in)[idx];
  ushort4v o;
  o.x = f2bf(v.x); o.y = f2bf(v.y); o.z = f2bf(v.z); o.w = f2bf(v.w);
  ((ushort4v*)outB)[idx] = o;
}

// transpose f32 [R][Ccols] -> bf16 [Ccols][R]
__global__ void k_transpose_bf16(const float* __restrict__ in, unsigned short* __restrict__ out,
                                 int R, int Ccols) {
  __shared__ float tile[32][33];
  int c0 = blockIdx.x * 32, r0 = blockIdx.y * 32;
  int tx = threadIdx.x & 31, ty = threadIdx.x >> 5;
#pragma unroll
  for (int p = 0; p < 4; ++p)
    tile[ty + 8 * p][tx] = in[(size_t)(r0 + ty + 8 * p) * Ccols + c0 + tx];
  __syncthreads();
#pragma unroll
  for (int p = 0; p < 4; ++p)
    out[(size_t)(c0 + ty + 8 * p) * R + r0 + tx] = f2bf(tile[tx][ty + 8 * p]);
}

// ---------------- GEMM with direct-layout epilogues, XCD-swizzled grid ----------------
template <int MODE>
__global__ __launch_bounds__(256) void k_gemm(const unsigned short* __restrict__ A,
                                              const unsigned short* __restrict__ BT,
                                              void* __restrict__ out1, void* __restrict__ out2,
                                              int M, int N, int K, int ldc) {
  __shared__ unsigned short As[128 * 64];
  __shared__ unsigned short Bs[128 * 64];
  const int tid = threadIdx.x;
  const int w = tid >> 6, l = tid & 63;
  const int wm = w >> 1, wn = w & 1;
  const int lg = l >> 4, lr = l & 15;
  const int gx = gridDim.x;
  const int pid = blockIdx.y * gx + blockIdx.x;
  const int xcd = pid & 7;
  const int idx = pid >> 3;
  const int cb = idx % gx;
  const int rb = (idx / gx) * 8 + xcd;
  const int m0 = rb * 128, n0 = cb * 128;
  f32x4 acc[4][4] = {};
  const int lrow8 = l >> 3;
  const int scol = (l & 7) * 8;
  const unsigned short* Abase = A + (size_t)m0 * K;
  const unsigned short* Bbase = BT + (size_t)n0 * K;
  for (int kt = 0; kt < K; kt += 64) {
    __syncthreads();
#pragma unroll
    for (int q = 0; q < 4; ++q) {
      int chunk = w * 4 + q;
      int row = chunk * 8 + lrow8;
      __builtin_amdgcn_global_load_lds(
          (const __attribute__((address_space(1))) void*)(Abase + (size_t)row * K + kt + scol),
          (__attribute__((address_space(3))) void*)(As + chunk * 512), 16, 0, 0);
      __builtin_amdgcn_global_load_lds(
          (const __attribute__((address_space(1))) void*)(Bbase + (size_t)row * K + kt + scol),
          (__attribute__((address_space(3))) void*)(Bs + chunk * 512), 16, 0, 0);
    }
    __syncthreads();
#pragma unroll
    for (int ks = 0; ks < 2; ++ks) {
      short8 a[4], bb[4];
#pragma unroll
      for (int mi = 0; mi < 4; ++mi)
        a[mi] = *(const short8*)&As[(wm * 64 + mi * 16 + lr) * 64 + ks * 32 + lg * 8];
#pragma unroll
      for (int ni = 0; ni < 4; ++ni)
        bb[ni] = *(const short8*)&Bs[(wn * 64 + ni * 16 + lr) * 64 + ks * 32 + lg * 8];
#pragma unroll
      for (int mi = 0; mi < 4; ++mi)
#pragma unroll
        for (int ni = 0; ni < 4; ++ni)
          acc[mi][ni] = mfma16(a[mi], bb[ni], acc[mi][ni]);
    }
  }
#pragma unroll
  for (int mi = 0; mi < 4; ++mi)
#pragma unroll
    for (int ni = 0; ni < 4; ++ni)
#pragma unroll
      for (int r = 0; r < 4; ++r) {
        int row = m0 + wm * 64 + mi * 16 + lg * 4 + r;
        int cc = n0 + wn * 64 + ni * 16 + lr;
        float val = acc[mi][ni][r];
        if (MODE == 1) {
          ((float*)out1)[(size_t)row * ldc + cc] = val;
        } else if (MODE == 2) {
          int nn = (cc & 1023) >> 6, d = cc & 63;
          int c = row >> 2, b = row & 3;
          size_t addr = ((size_t)((b * 16 + nn) * 2048 + c)) * 64 + d;
          unsigned short* dst = (cc < 1024) ? (unsigned short*)out1 : (unsigned short*)out2;
          dst[addr] = f2bf(val);
        } else if (MODE == 3) {
          int nn = cc >> 6, d = cc & 63;
          int t = row >> 2, b = row & 3;
          ((unsigned short*)out1)[((size_t)((b * 16 + nn) * 1024 + t)) * 64 + d] = f2bf(val);
        } else {  // MODE 4
          int nn = cc >> 6, d = cc & 63;
          ((unsigned short*)out1)[((size_t)(nn * 2048 + row)) * 64 + d] = f2bf(val);
        }
      }
}

// ---------------- V transpose: Vp[b][n][c][d] -> VT[b][n][d][c] ----------------
__global__ void k_vt(const unsigned short* __restrict__ Vp, unsigned short* __restrict__ VT) {
  __shared__ unsigned short tile[64][72];
  int c0 = blockIdx.x * 64;
  int n = blockIdx.y, b = blockIdx.z;
  int t = threadIdx.x;
  const unsigned short* src = Vp + ((size_t)((b * 16 + n) * 2048 + c0)) * 64;
#pragma unroll
  for (int p = 0; p < 16; ++p) {
    int idx = p * 256 + t;
    int r = idx >> 6, d = idx & 63;
    tile[d][r] = src[(size_t)r * 64 + d];
  }
  __syncthreads();
#pragma unroll
  for (int p = 0; p < 16; ++p) {
    int idx = p * 256 + t;
    int d = idx >> 6, c = idx & 63;
    VT[(size_t)((b * 16 + n) * 64 + d) * 2048 + c0 + c] = tile[d][c];
  }
}

// ---------------- bias dot scalars ----------------
__global__ void k_bias_dots(const unsigned short* __restrict__ Kp,
                            const unsigned short* __restrict__ Rkp,
                            const float* __restrict__ rwb, const float* __restrict__ rrb,
                            float* __restrict__ uk, float* __restrict__ vr) {
  int gid = blockIdx.x * 256 + threadIdx.x;
  if (gid < B_SZ * NH * C_LEN) {
    int bn = gid >> 11;
    int n = bn & 15;
    const unsigned short* kp = Kp + (size_t)gid * 64;
    float s = 0.f;
#pragma unroll
    for (int q = 0; q < 8; ++q) {
      short8 v = *(const short8*)&kp[q * 8];
#pragma unroll
      for (int e = 0; e < 8; ++e)
        s += bf2f((unsigned short)v[e]) * rwb[n * 64 + q * 8 + e];
    }
    uk[gid] = s;
  } else {
    int g2 = gid - B_SZ * NH * C_LEN;
    int n = g2 >> 11;
    const unsigned short* rp = Rkp + (size_t)g2 * 64;
    float s = 0.f;
#pragma unroll
    for (int q = 0; q < 8; ++q) {
      short8 v = *(const short8*)&rp[q * 8];
#pragma unroll
      for (int e = 0; e < 8; ++e)
        s += bf2f((unsigned short)v[e]) * rrb[n * 64 + q * 8 + e];
    }
    vr[g2] = s;
  }
}

// ---------------- split-j flash attention, 8 waves/block (QBLK=128) ----------------
// K/V tiles (32 KB) shared by 8 waves instead of 4 -> LDS/wave halves:
// 50 KB/block, 3 blocks/CU x 512 thr = 6 waves/SIMD (was 3). Per-wave loop
// body identical to the R10/R12 best. Counted vmcnt(2) staging, no-max
// softmax, split-j S=3, XCD swizzle, T5 setprio on MFMA clusters.
__device__ __forceinline__ void stage_tile(const unsigned short* __restrict__ Kbase,
                                           const unsigned short* __restrict__ Vbase,
                                           unsigned short* ksBuf, unsigned short* vsBuf,
                                           int j0, int tid) {
  int row = tid >> 3;          // 0..63
  int slot = tid & 7;
  int ss = slot ^ (row & 7);   // source pre-swizzle (rule #21)
  __builtin_amdgcn_global_load_lds(
      (const __attribute__((address_space(1))) void*)(Kbase + (size_t)(j0 + row) * 64 + ss * 8),
      (__attribute__((address_space(3))) void*)(ksBuf + tid * 8), 16, 0, 0);
  __builtin_amdgcn_global_load_lds(
      (const __attribute__((address_space(1))) void*)(Vbase + (size_t)row * 2048 + j0 + ss * 8),
      (__attribute__((address_space(3))) void*)(vsBuf + tid * 8), 16, 0, 0);
}

__global__ __launch_bounds__(512) void k_attn(const unsigned short* __restrict__ Qp,
                                              const unsigned short* __restrict__ Kp,
                                              const unsigned short* __restrict__ VT,
                                              const unsigned short* __restrict__ Rkp,
                                              const float* __restrict__ uk,
                                              const float* __restrict__ vr,
                                              unsigned short* __restrict__ po,
                                              float* __restrict__ psumG) {
  __shared__ __align__(16) unsigned short Ks[2][64 * 64];
  __shared__ __align__(16) unsigned short Vs[2][64 * 64];
  __shared__ unsigned short P[8][16][72];
  const int tid = threadIdx.x;
  const int w = tid >> 6, l = tid & 63;          // w 0..7
  const int lg = l >> 4, lr = l & 15;
  // XCD-locality: all 24 (xt,s) blocks of one bn land on one XCD (L%8 const)
  const int L = blockIdx.x;
  const int bnlo = L & 7;
  const int rest = L >> 3;            // 0..191
  const int bnhi = rest / 24;
  const int inner = rest - bnhi * 24; // 0..23
  const int xt = inner / 3;           // 0..7 (128-row q block)
  const int s  = inner - xt * 3;
  const int bn = bnhi * 8 + bnlo;
  const int i0 = xt * 128;
  const int n = bn & 15, b = bn >> 4;
  const int wrow = i0 + w * 16;

  const int ntile = 2 * xt + 18;
  const int t0 = (s * ntile) / 3;
  const int t1 = ((s + 1) * ntile) / 3;   // chunk length 6..11

  const unsigned short* Kbase = Kp + (size_t)bn * 2048 * 64;
  const unsigned short* Vbase = VT + (size_t)bn * 64 * 2048;
  const unsigned short* Rkbase = Rkp + (size_t)n * 2048 * 64;

  short8 aq0, aq1;
  {
    const unsigned short* qp = Qp + (size_t)(bn * 1024 + wrow + lr) * 64 + lg * 8;
    aq0 = *(const short8*)qp;
    aq1 = *(const short8*)(qp + 32);
  }
  float psum[4];
  f32x4 o[4];
#pragma unroll
  for (int r = 0; r < 4; ++r) psum[r] = 0.f;
#pragma unroll
  for (int df = 0; df < 4; ++df) o[df] = (f32x4){0.f, 0.f, 0.f, 0.f};

  const float* ukp = uk + (size_t)bn * 2048;
  const float* vrp = vr + (size_t)n * 2048;

  // prologue: stage tiles t0, t0+1 (4 loads/thread outstanding)
  stage_tile(Kbase, Vbase, Ks[0], Vs[0], t0 * 64, tid);
  stage_tile(Kbase, Vbase, Ks[1], Vs[1], (t0 + 1) * 64, tid);

  const float EXPC = 0.18033688011112042f;  // 0.125 * log2(e)

  for (int jt = t0; jt < t1; ++jt) {
    const int j0 = jt * 64;
    const int cur = (jt - t0) & 1;
    if (jt + 1 < t1) { asm volatile("s_waitcnt vmcnt(2)" ::: "memory"); }
    else             { asm volatile("s_waitcnt vmcnt(0)" ::: "memory"); }
    __builtin_amdgcn_s_barrier();

    f32x4 sac[4];
#pragma unroll
    for (int jf = 0; jf < 4; ++jf) sac[jf] = (f32x4){0.f, 0.f, 0.f, 0.f};
    // AC = q . k  (from swizzled LDS)
    __builtin_amdgcn_s_setprio(1);
#pragma unroll
    for (int jf = 0; jf < 4; ++jf) {
      int row = jf * 16 + lr;
      int rx = row & 7;
      short8 k0 = *(const short8*)&Ks[cur][row * 64 + ((lg ^ rx) * 8)];
      short8 k1 = *(const short8*)&Ks[cur][row * 64 + (((4 + lg) ^ rx) * 8)];
      sac[jf] = mfma16(aq0, k0, sac[jf]);
      sac[jf] = mfma16(aq1, k1, sac[jf]);
    }
    __builtin_amdgcn_s_setprio(0);
    // BD band fragments, kept in registers
    const int kbw = j0 + 1008 - i0 - w * 16;   // >= 0 (min 1008-896-112 = 0)
    f32x4 gb[5];
#pragma unroll
    for (int jg = 0; jg < 5; ++jg) {
      int rowK = kbw + jg * 16 + lr;
      short8 b0 = {}, b1 = {};
      float vrv = 0.f;
      if (rowK < C_LEN) {
        const unsigned short* rp = Rkbase + (size_t)rowK * 64 + lg * 8;
        b0 = *(const short8*)rp;
        b1 = *(const short8*)(rp + 32);
        vrv = vrp[rowK];
      }
      f32x4 g = (f32x4){0.f, 0.f, 0.f, 0.f};
      g = mfma16(aq0, b0, g);
      g = mfma16(aq1, b1, g);
#pragma unroll
      for (int r = 0; r < 4; ++r) g[r] += vrv;
      gb[jg] = g;
    }
    float ukv[4];
#pragma unroll
    for (int jf = 0; jf < 4; ++jf) ukv[jf] = ukp[j0 + jf * 16 + lr];
    // shuffle-gather the diagonal band; p = exp2(score*C) directly (no max)
    float p[4][4];
#pragma unroll
    for (int r = 0; r < 4; ++r) {
      const int R = lg * 4 + r;
      const int delta = lr + 15 - R;
      const int src = (l & 48) | (delta & 15);
      float v0 = __shfl(gb[0][r], src);
      float v1 = __shfl(gb[1][r], src);
      float v2 = __shfl(gb[2][r], src);
      float v3 = __shfl(gb[3][r], src);
      float v4 = __shfl(gb[4][r], src);
      const bool hi = delta >= 16;
      float bd0 = hi ? v1 : v0;
      float bd1 = hi ? v2 : v1;
      float bd2 = hi ? v3 : v2;
      float bd3 = hi ? v4 : v3;
      const int jlim = i0 + w * 16 + R + MEM_LEN;
      int j = j0 + lr;
      p[0][r] = (j > jlim) ? 0.f : exp2f((sac[0][r] + bd0 + ukv[0]) * EXPC);
      j += 16;
      p[1][r] = (j > jlim) ? 0.f : exp2f((sac[1][r] + bd1 + ukv[1]) * EXPC);
      j += 16;
      p[2][r] = (j > jlim) ? 0.f : exp2f((sac[2][r] + bd2 + ukv[2]) * EXPC);
      j += 16;
      p[3][r] = (j > jlim) ? 0.f : exp2f((sac[3][r] + bd3 + ukv[3]) * EXPC);
    }
#pragma unroll
    for (int jf = 0; jf < 4; ++jf)
#pragma unroll
      for (int r = 0; r < 4; ++r) psum[r] += p[jf][r];
#pragma unroll
    for (int jf = 0; jf < 4; ++jf)
#pragma unroll
      for (int r = 0; r < 4; ++r)
        P[w][lg * 4 + r][jf * 16 + lr] = f2bf(p[jf][r]);
    // PV (V from swizzled LDS), no rescale
    __builtin_amdgcn_s_setprio(1);
#pragma unroll
    for (int ks = 0; ks < 2; ++ks) {
      short8 ap = *(const short8*)&P[w][lr][ks * 32 + lg * 8];
#pragma unroll
      for (int df = 0; df < 4; ++df) {
        int row = df * 16 + lr;
        int rx = row & 7;
        short8 vv = *(const short8*)&Vs[cur][row * 64 + (((ks * 4 + lg) ^ rx) * 8)];
        o[df] = mfma16(ap, vv, o[df]);
      }
    }
    __builtin_amdgcn_s_setprio(0);
    __builtin_amdgcn_s_barrier();
    if (jt + 2 < t1)
      stage_tile(Kbase, Vbase, Ks[cur], Vs[cur], (jt + 2) * 64, tid);
  }
  // write partials (o as bf16): pbase over (bn, xt128, s); 128 rows x 64 d
  const int pbase = (bn * 8 + xt) * 3 + s;
  unsigned short* poB = po + (size_t)pbase * 8192;
#pragma unroll
  for (int r = 0; r < 4; ++r) {
    float v = psum[r];
    v += __shfl_xor(v, 1);
    v += __shfl_xor(v, 2);
    v += __shfl_xor(v, 4);
    v += __shfl_xor(v, 8);
    if (lr == 0) psumG[(size_t)pbase * 128 + w * 16 + lg * 4 + r] = v;
  }
#pragma unroll
  for (int df = 0; df < 4; ++df)
#pragma unroll
    for (int r = 0; r < 4; ++r)
      poB[(w * 16 + lg * 4 + r) * 64 + df * 16 + lr] = f2bf(o[df][r]);
}

// combine split partials, normalize, emit bf16 vec[t][b][n*64+d]
// one block per (bn, xt128): 128 rows x 64 d
__global__ __launch_bounds__(256) void k_ared(const unsigned short* __restrict__ po,
                                              const float* __restrict__ psumG,
                                              unsigned short* __restrict__ vec) {
  const int idx = blockIdx.x;      // bn*8 + xt  (0..511)
  const int tid = threadIdx.x;
  const int bn = idx >> 3, xt = idx & 7;
  const int b = bn >> 4, n = bn & 15;
  const int base = idx * 3;
  __shared__ float rs[128];
  if (tid < 128)
    rs[tid] = psumG[(size_t)base * 128 + tid] +
              psumG[(size_t)(base + 1) * 128 + tid] +
              psumG[(size_t)(base + 2) * 128 + tid];
  __syncthreads();
  const ushort4v* p0 = (const ushort4v*)(po + (size_t)(base + 0) * 8192);
  const ushort4v* p1 = (const ushort4v*)(po + (size_t)(base + 1) * 8192);
  const ushort4v* p2 = (const ushort4v*)(po + (size_t)(base + 2) * 8192);
#pragma unroll
  for (int k = 0; k < 8; ++k) {
    int e = tid + k * 256;          // ushort4 index 0..2047
    int row = e >> 4, d4 = e & 15;
    ushort4v a = p0[e], bb = p1[e], c = p2[e];
    float inv = 1.f / rs[row];
    int t = xt * 128 + row;
    ushort4v ov;
    ov.x = f2bf((bf2f(a.x) + bf2f(bb.x) + bf2f(c.x)) * inv);
    ov.y = f2bf((bf2f(a.y) + bf2f(bb.y) + bf2f(c.y)) * inv);
    ov.z = f2bf((bf2f(a.z) + bf2f(bb.z) + bf2f(c.z)) * inv);
    ov.w = f2bf((bf2f(a.w) + bf2f(bb.w) + bf2f(c.w)) * inv);
    *(ushort4v*)&vec[(size_t)(t * 4 + b) * 1024 + n * 64 + d4 * 4] = ov;
  }
}

// ---------------- residual + layernorm ----------------
__global__ __launch_bounds__(256) void k_ln(const float* __restrict__ xg, const float* __restrict__ h,
                                            const float* __restrict__ gamma, const float* __restrict__ beta,
                                            float* __restrict__ out) {
  const int row = blockIdx.x;
  const int t = threadIdx.x;
  __shared__ float red1[4], red2[4];
  float4v xv = ((const float4v*)(xg + (size_t)row * 1024))[t];
  float4v hv = ((const float4v*)(h + (size_t)row * 1024))[t];
  float x0 = xv.x + hv.x, x1 = xv.y + hv.y, x2 = xv.z + hv.z, x3 = xv.w + hv.w;
  float s = x0 + x1 + x2 + x3;
#pragma unroll
  for (int off = 1; off < 64; off <<= 1) s += __shfl_xor(s, off);
  if ((t & 63) == 0) red1[t >> 6] = s;
  __syncthreads();
  float mean = (red1[0] + red1[1] + red1[2] + red1[3]) * (1.f / 1024.f);
  float d0 = x0 - mean, d1 = x1 - mean, d2 = x2 - mean, d3 = x3 - mean;
  float q = d0 * d0 + d1 * d1 + d2 * d2 + d3 * d3;
#pragma unroll
  for (int off = 1; off < 64; off <<= 1) q += __shfl_xor(q, off);
  if ((t & 63) == 0) red2[t >> 6] = q;
  __syncthreads();
  float var = (red2[0] + red2[1] + red2[2] + red2[3]) * (1.f / 1024.f);
  float rs = rsqrtf(var + 1e-5f);
  float4v gv = ((const float4v*)gamma)[t];
  float4v bv = ((const float4v*)beta)[t];
  float4v ov;
  ov.x = d0 * rs * gv.x + bv.x;
  ov.y = d1 * rs * gv.y + bv.y;
  ov.z = d2 * rs * gv.z + bv.z;
  ov.w = d3 * rs * gv.w + bv.w;
  ((float4v*)(out + (size_t)row * 1024))[t] = ov;
}

extern "C" void kernel_launch(void* const* d_in, const int* in_sizes, int n_in,
                              void* d_out, int out_size, void* d_ws, size_t ws_size,
                              hipStream_t stream) {
  (void)in_sizes; (void)n_in; (void)out_size; (void)ws_size;
  const float* h    = (const float*)d_in[0];
  const float* m    = (const float*)d_in[1];
  const float* r    = (const float*)d_in[2];
  const float* Wqkv = (const float*)d_in[4];
  const float* Wr   = (const float*)d_in[5];
  const float* Wo   = (const float*)d_in[6];
  const float* rwb  = (const float*)d_in[7];
  const float* rrb  = (const float*)d_in[8];
  const float* gam  = (const float*)d_in[9];
  const float* bet  = (const float*)d_in[10];
  float* out = (float*)d_out;

  char* ws = (char*)d_ws;
  unsigned short* catB   = (unsigned short*)(ws + 0);          // 16 MB
  unsigned short* WqkvT  = (unsigned short*)(ws + 16777216);   // 6 MB
  unsigned short* WrT    = (unsigned short*)(ws + 23068672);   // 2 MB
  unsigned short* WoT    = (unsigned short*)(ws + 25165824);   // 2 MB
  unsigned short* Vp     = (unsigned short*)(ws + 27262976);   // 16 MB
  unsigned short* po     = (unsigned short*)(ws + 44040192);   // 24 MB bf16 partials
  unsigned short* VT     = (unsigned short*)(ws + 81788928);   // 16 MB
  float* uk              = (float*)(ws + 98566144);            // 0.5 MB
  float* vr              = (float*)(ws + 99090432);            // 0.125 MB
  unsigned short* vec    = (unsigned short*)(ws + 99221504);   // 8 MB
  float* xbuf            = (float*)(ws + 107610112);           // 16 MB
  unsigned short* rB     = (unsigned short*)(ws + 124387328);  // 4 MB (reused as psumG)
  unsigned short* Kp     = (unsigned short*)(ws + 128581632);  // 16 MB
  unsigned short* Qp     = (unsigned short*)(ws + 145358848);  // 8 MB
  unsigned short* Rkp    = (unsigned short*)(ws + 153747456);  // 4 MB -> ~158 MB total
  float* psumG = (float*)(ws + 124387328);                     // over dead rB

  hipLaunchKernelGGL(k_cat_convert, dim3(8192), dim3(256), 0, stream, m, h, catB);
  hipLaunchKernelGGL(k_f32_to_bf16, dim3(2048), dim3(256), 0, stream, r, rB, 524288);
  hipLaunchKernelGGL(k_transpose_bf16, dim3(96, 32), dim3(256), 0, stream, Wqkv, WqkvT, 1024, 3072);
  hipLaunchKernelGGL(k_transpose_bf16, dim3(32, 32), dim3(256), 0, stream, Wr, WrT, 1024, 1024);
  hipLaunchKernelGGL(k_transpose_bf16, dim3(32, 32), dim3(256), 0, stream, Wo, WoT, 1024, 1024);
  hipLaunchKernelGGL(k_gemm<2>, dim3(16, 64), dim3(256), 0, stream,
                     catB, WqkvT + (size_t)1024 * 1024, (void*)Kp, (void*)Vp, 8192, 2048, 1024, 0);
  hipLaunchKernelGGL(k_gemm<3>, dim3(8, 32), dim3(256), 0, stream,
                     catB + (size_t)4096 * 1024, WqkvT, (void*)Qp, nullptr, 4096, 1024, 1024, 0);
  hipLaunchKernelGGL(k_gemm<4>, dim3(8, 16), dim3(256), 0, stream,
                     rB, WrT, (void*)Rkp, nullptr, 2048, 1024, 1024, 0);
  hipLaunchKernelGGL(k_vt, dim3(32, 16, 4), dim3(256), 0, stream, Vp, VT);
  hipLaunchKernelGGL(k_bias_dots, dim3(640), dim3(256), 0, stream, Kp, Rkp, rwb, rrb, uk, vr);
  hipLaunchKernelGGL(k_attn, dim3(1536), dim3(512), 0, stream, Qp, Kp, VT, Rkp, uk, vr, po, psumG);
  hipLaunchKernelGGL(k_ared, dim3(512), dim3(256), 0, stream, po, psumG, vec);
  hipLaunchKernelGGL(k_gemm<1>, dim3(8, 32), dim3(256), 0, stream,
                     vec, WoT, (void*)xbuf, nullptr, 4096, 1024, 1024, 1024);
  hipLaunchKernelGGL(k_ln, dim3(4096), dim3(256), 0, stream, xbuf, h, gam, bet, out);
}

// Round 14
// 327.978 us; speedup vs baseline: 1.0701x; 1.0701x over previous
//
#include <hip/hip_runtime.h>
#include <stdint.h>

#define T_LEN 1024
#define MEM_LEN 1024
#define C_LEN 2048
#define B_SZ 4
#define DM_ 1024
#define NH 16
#define HD 64

typedef __attribute__((ext_vector_type(8))) short short8;
typedef __attribute__((ext_vector_type(4))) float f32x4;
typedef __attribute__((ext_vector_type(4))) unsigned short ushort4v;
typedef __attribute__((ext_vector_type(4))) float float4v;

__device__ __forceinline__ unsigned short f2bf(float f) {
  union { float f; unsigned int u; } v; v.f = f;
  unsigned int r = v.u + 0x7fffu + ((v.u >> 16) & 1u);
  return (unsigned short)(r >> 16);
}
__device__ __forceinline__ float bf2f(unsigned short b) {
  union { unsigned int u; float f; } v; v.u = ((unsigned int)b) << 16;
  return v.f;
}
__device__ __forceinline__ unsigned int cvtpk(float lo, float hi) {
  unsigned int r;
  asm("v_cvt_pk_bf16_f32 %0, %1, %2" : "=v"(r) : "v"(lo), "v"(hi));
  return r;
}
__device__ __forceinline__ f32x4 mfma16(short8 a, short8 b, f32x4 c) {
  return __builtin_amdgcn_mfma_f32_16x16x32_bf16(a, b, c, 0, 0, 0);
}

// ---------------- converts ----------------
__global__ void k_cat_convert(const float* __restrict__ m, const float* __restrict__ h,
                              unsigned short* __restrict__ outB) {
  int idx = blockIdx.x * 256 + threadIdx.x;
  const int MQ = (MEM_LEN * B_SZ * DM_) / 4;
  float4v v;
  if (idx < MQ) v = ((const float4v*)m)[idx];
  else          v = ((const float4v*)h)[idx - MQ];
  ushort4v o;
  o.x = f2bf(v.x); o.y = f2bf(v.y); o.z = f2bf(v.z); o.w = f2bf(v.w);
  ((ushort4v*)outB)[idx] = o;
}

__global__ void k_f32_to_bf16(const float* __restrict__ in, unsigned short* __restrict__ outB, int nq) {
  int idx = blockIdx.x * 256 + threadIdx.x;
  if (idx >= nq) return;
  float4v v = ((const float4v*)in)[idx];
  ushort4v o;
  o.x = f2bf(v.x); o.y = f2bf(v.y); o.z = f2bf(v.z); o.w = f2bf(v.w);
  ((ushort4v*)outB)[idx] = o;
}

// transpose f32 [R][Ccols] -> bf16 [Ccols][R]
__global__ void k_transpose_bf16(const float* __restrict__ in, unsigned short* __restrict__ out,
                                 int R, int Ccols) {
  __shared__ float tile[32][33];
  int c0 = blockIdx.x * 32, r0 = blockIdx.y * 32;
  int tx = threadIdx.x & 31, ty = threadIdx.x >> 5;
#pragma unroll
  for (int p = 0; p < 4; ++p)
    tile[ty + 8 * p][tx] = in[(size_t)(r0 + ty + 8 * p) * Ccols + c0 + tx];
  __syncthreads();
#pragma unroll
  for (int p = 0; p < 4; ++p)
    out[(size_t)(c0 + ty + 8 * p) * R + r0 + tx] = f2bf(tile[tx][ty + 8 * p]);
}

// ---------------- GEMM with direct-layout epilogues, XCD-swizzled grid ----------------
template <int MODE>
__global__ __launch_bounds__(256) void k_gemm(const unsigned short* __restrict__ A,
                                              const unsigned short* __restrict__ BT,
                                              void* __restrict__ out1, void* __restrict__ out2,
                                              int M, int N, int K, int ldc) {
  __shared__ unsigned short As[128 * 64];
  __shared__ unsigned short Bs[128 * 64];
  const int tid = threadIdx.x;
  const int w = tid >> 6, l = tid & 63;
  const int wm = w >> 1, wn = w & 1;
  const int lg = l >> 4, lr = l & 15;
  const int gx = gridDim.x;
  const int pid = blockIdx.y * gx + blockIdx.x;
  const int xcd = pid & 7;
  const int idx = pid >> 3;
  const int cb = idx % gx;
  const int rb = (idx / gx) * 8 + xcd;
  const int m0 = rb * 128, n0 = cb * 128;
  f32x4 acc[4][4] = {};
  const int lrow8 = l >> 3;
  const int scol = (l & 7) * 8;
  const unsigned short* Abase = A + (size_t)m0 * K;
  const unsigned short* Bbase = BT + (size_t)n0 * K;
  for (int kt = 0; kt < K; kt += 64) {
    __syncthreads();
#pragma unroll
    for (int q = 0; q < 4; ++q) {
      int chunk = w * 4 + q;
      int row = chunk * 8 + lrow8;
      __builtin_amdgcn_global_load_lds(
          (const __attribute__((address_space(1))) void*)(Abase + (size_t)row * K + kt + scol),
          (__attribute__((address_space(3))) void*)(As + chunk * 512), 16, 0, 0);
      __builtin_amdgcn_global_load_lds(
          (const __attribute__((address_space(1))) void*)(Bbase + (size_t)row * K + kt + scol),
          (__attribute__((address_space(3))) void*)(Bs + chunk * 512), 16, 0, 0);
    }
    __syncthreads();
#pragma unroll
    for (int ks = 0; ks < 2; ++ks) {
      short8 a[4], bb[4];
#pragma unroll
      for (int mi = 0; mi < 4; ++mi)
        a[mi] = *(const short8*)&As[(wm * 64 + mi * 16 + lr) * 64 + ks * 32 + lg * 8];
#pragma unroll
      for (int ni = 0; ni < 4; ++ni)
        bb[ni] = *(const short8*)&Bs[(wn * 64 + ni * 16 + lr) * 64 + ks * 32 + lg * 8];
#pragma unroll
      for (int mi = 0; mi < 4; ++mi)
#pragma unroll
        for (int ni = 0; ni < 4; ++ni)
          acc[mi][ni] = mfma16(a[mi], bb[ni], acc[mi][ni]);
    }
  }
#pragma unroll
  for (int mi = 0; mi < 4; ++mi)
#pragma unroll
    for (int ni = 0; ni < 4; ++ni)
#pragma unroll
      for (int r = 0; r < 4; ++r) {
        int row = m0 + wm * 64 + mi * 16 + lg * 4 + r;
        int cc = n0 + wn * 64 + ni * 16 + lr;
        float val = acc[mi][ni][r];
        if (MODE == 1) {
          ((float*)out1)[(size_t)row * ldc + cc] = val;
        } else if (MODE == 2) {
          int nn = (cc & 1023) >> 6, d = cc & 63;
          int c = row >> 2, b = row & 3;
          size_t addr = ((size_t)((b * 16 + nn) * 2048 + c)) * 64 + d;
          unsigned short* dst = (cc < 1024) ? (unsigned short*)out1 : (unsigned short*)out2;
          dst[addr] = f2bf(val);
        } else if (MODE == 3) {
          int nn = cc >> 6, d = cc & 63;
          int t = row >> 2, b = row & 3;
          ((unsigned short*)out1)[((size_t)((b * 16 + nn) * 1024 + t)) * 64 + d] = f2bf(val);
        } else {  // MODE 4
          int nn = cc >> 6, d = cc & 63;
          ((unsigned short*)out1)[((size_t)(nn * 2048 + row)) * 64 + d] = f2bf(val);
        }
      }
}

// ---------------- V transpose: Vp[b][n][c][d] -> VT[b][n][d][c] ----------------
__global__ void k_vt(const unsigned short* __restrict__ Vp, unsigned short* __restrict__ VT) {
  __shared__ unsigned short tile[64][72];
  int c0 = blockIdx.x * 64;
  int n = blockIdx.y, b = blockIdx.z;
  int t = threadIdx.x;
  const unsigned short* src = Vp + ((size_t)((b * 16 + n) * 2048 + c0)) * 64;
#pragma unroll
  for (int p = 0; p < 16; ++p) {
    int idx = p * 256 + t;
    int r = idx >> 6, d = idx & 63;
    tile[d][r] = src[(size_t)r * 64 + d];
  }
  __syncthreads();
#pragma unroll
  for (int p = 0; p < 16; ++p) {
    int idx = p * 256 + t;
    int d = idx >> 6, c = idx & 63;
    VT[(size_t)((b * 16 + n) * 64 + d) * 2048 + c0 + c] = tile[d][c];
  }
}

// ---------------- split-j flash attention (4-wave KVBLK=64; bias-folded Q) ----------------
__device__ __forceinline__ void stage_tile(const unsigned short* __restrict__ Kbase,
                                           const unsigned short* __restrict__ Vbase,
                                           unsigned short* ksBuf, unsigned short* vsBuf,
                                           int j0, int tid) {
#pragma unroll
  for (int q = 0; q < 2; ++q) {
    int chunk = q * 256 + tid;   // 0..511
    int row = chunk >> 3;        // 0..63
    int slot = chunk & 7;
    int ss = slot ^ (row & 7);   // source pre-swizzle (rule #21)
    __builtin_amdgcn_global_load_lds(
        (const __attribute__((address_space(1))) void*)(Kbase + (size_t)(j0 + row) * 64 + ss * 8),
        (__attribute__((address_space(3))) void*)(ksBuf + chunk * 8), 16, 0, 0);
    __builtin_amdgcn_global_load_lds(
        (const __attribute__((address_space(1))) void*)(Vbase + (size_t)row * 2048 + j0 + ss * 8),
        (__attribute__((address_space(3))) void*)(vsBuf + chunk * 8), 16, 0, 0);
  }
}

__global__ __launch_bounds__(256) void k_attn(const unsigned short* __restrict__ Qp,
                                              const unsigned short* __restrict__ Kp,
                                              const unsigned short* __restrict__ VT,
                                              const unsigned short* __restrict__ Rkp,
                                              const float* __restrict__ rwb,
                                              const float* __restrict__ rrb,
                                              unsigned short* __restrict__ po,
                                              float* __restrict__ psumG) {
  __shared__ __align__(16) unsigned short Ks[2][64 * 64];
  __shared__ __align__(16) unsigned short Vs[2][64 * 64];
  __shared__ unsigned short P[4][16][72];
  const int tid = threadIdx.x;
  const int w = tid >> 6, l = tid & 63;
  const int lg = l >> 4, lr = l & 15;
  // XCD-locality: all 48 (xt,s) blocks of one bn land on one XCD (L%8 const)
  const int L = blockIdx.x;
  const int bnlo = L & 7;
  const int rest = L >> 3;          // 0..383
  const int bnhi = rest / 48;
  const int inner = rest - bnhi * 48;  // 0..47
  const int xt = inner / 3;
  const int s  = inner - xt * 3;
  const int bn = bnhi * 8 + bnlo;
  const int i0 = xt * 64;
  const int n = bn & 15, b = bn >> 4;
  const int wrow = i0 + w * 16;

  const int ntile = xt + 17;
  const int t0 = (s * ntile) / 3;
  const int t1 = ((s + 1) * ntile) / 3;   // chunk length 5..11

  const unsigned short* Kbase = Kp + (size_t)bn * 2048 * 64;
  const unsigned short* Vbase = VT + (size_t)bn * 64 * 2048;
  const unsigned short* Rkbase = Rkp + (size_t)n * 2048 * 64;

  // Q fragments with biases folded in: aqU = bf16(q+u) for AC, aqV = bf16(q+v) for BD.
  short8 aq0u, aq1u, aq0v, aq1v;
  {
    const unsigned short* qp = Qp + (size_t)(bn * 1024 + wrow + lr) * 64 + lg * 8;
    short8 q0 = *(const short8*)qp;
    short8 q1 = *(const short8*)(qp + 32);
    const float* up = rwb + n * 64 + lg * 8;
    const float* vp = rrb + n * 64 + lg * 8;
#pragma unroll
    for (int e = 0; e < 8; ++e) {
      float q0f = bf2f((unsigned short)q0[e]);
      float q1f = bf2f((unsigned short)q1[e]);
      aq0u[e] = (short)f2bf(q0f + up[e]);
      aq1u[e] = (short)f2bf(q1f + up[e + 32]);
      aq0v[e] = (short)f2bf(q0f + vp[e]);
      aq1v[e] = (short)f2bf(q1f + vp[e + 32]);
    }
  }
  float psum[4];
  f32x4 o[4];
#pragma unroll
  for (int r = 0; r < 4; ++r) psum[r] = 0.f;
#pragma unroll
  for (int df = 0; df < 4; ++df) o[df] = (f32x4){0.f, 0.f, 0.f, 0.f};

  // prologue: stage tiles t0, t0+1 (8 loads/thread outstanding)
  stage_tile(Kbase, Vbase, Ks[0], Vs[0], t0 * 64, tid);
  stage_tile(Kbase, Vbase, Ks[1], Vs[1], (t0 + 1) * 64, tid);

  const float EXPC = 0.18033688011112042f;  // 0.125 * log2(e)

  for (int jt = t0; jt < t1; ++jt) {
    const int j0 = jt * 64;
    const int cur = (jt - t0) & 1;
    if (jt + 1 < t1) { asm volatile("s_waitcnt vmcnt(4)" ::: "memory"); }
    else             { asm volatile("s_waitcnt vmcnt(0)" ::: "memory"); }
    __builtin_amdgcn_s_barrier();

    f32x4 sac[4];
#pragma unroll
    for (int jf = 0; jf < 4; ++jf) sac[jf] = (f32x4){0.f, 0.f, 0.f, 0.f};
    // AC+uk = (q+u) . k  (from swizzled LDS)
#pragma unroll
    for (int jf = 0; jf < 4; ++jf) {
      int row = jf * 16 + lr;
      int rx = row & 7;
      short8 k0 = *(const short8*)&Ks[cur][row * 64 + ((lg ^ rx) * 8)];
      short8 k1 = *(const short8*)&Ks[cur][row * 64 + (((4 + lg) ^ rx) * 8)];
      sac[jf] = mfma16(aq0u, k0, sac[jf]);
      sac[jf] = mfma16(aq1u, k1, sac[jf]);
    }
    // BD+vr band fragments = (q+v) . rk, kept in registers
    const int kbw = j0 + 1008 - i0 - w * 16;
    f32x4 gb[5];
#pragma unroll
    for (int jg = 0; jg < 5; ++jg) {
      int rowK = kbw + jg * 16 + lr;
      short8 b0 = {}, b1 = {};
      if (rowK < C_LEN) {
        const unsigned short* rp = Rkbase + (size_t)rowK * 64 + lg * 8;
        b0 = *(const short8*)rp;
        b1 = *(const short8*)(rp + 32);
      }
      f32x4 g = (f32x4){0.f, 0.f, 0.f, 0.f};
      g = mfma16(aq0v, b0, g);
      g = mfma16(aq1v, b1, g);
      gb[jg] = g;
    }
    // shuffle-gather the diagonal band; p = exp2(score*C) (no max);
    // mask only on tiles overlapping this wave's diagonal (wave-uniform).
    const bool needMask = (j0 + 63 > i0 + w * 16 + MEM_LEN);
    float p[4][4];
#pragma unroll
    for (int r = 0; r < 4; ++r) {
      const int R = lg * 4 + r;
      const int delta = lr + 15 - R;
      const int src = (l & 48) | (delta & 15);
      float v0 = __shfl(gb[0][r], src);
      float v1 = __shfl(gb[1][r], src);
      float v2 = __shfl(gb[2][r], src);
      float v3 = __shfl(gb[3][r], src);
      float v4 = __shfl(gb[4][r], src);
      const bool hi = delta >= 16;
      float bd0 = hi ? v1 : v0;
      float bd1 = hi ? v2 : v1;
      float bd2 = hi ? v3 : v2;
      float bd3 = hi ? v4 : v3;
      float e0 = exp2f((sac[0][r] + bd0) * EXPC);
      float e1 = exp2f((sac[1][r] + bd1) * EXPC);
      float e2 = exp2f((sac[2][r] + bd2) * EXPC);
      float e3 = exp2f((sac[3][r] + bd3) * EXPC);
      if (needMask) {
        const int jlim = i0 + w * 16 + R + MEM_LEN;
        int j = j0 + lr;
        e0 = (j > jlim) ? 0.f : e0;  j += 16;
        e1 = (j > jlim) ? 0.f : e1;  j += 16;
        e2 = (j > jlim) ? 0.f : e2;  j += 16;
        e3 = (j > jlim) ? 0.f : e3;
      }
      p[0][r] = e0; p[1][r] = e1; p[2][r] = e2; p[3][r] = e3;
    }
#pragma unroll
    for (int jf = 0; jf < 4; ++jf)
#pragma unroll
      for (int r = 0; r < 4; ++r) psum[r] += p[jf][r];
    // P -> bf16 LDS via packed converts (2 cvt_pk + 2 shifts per r)
#pragma unroll
    for (int r = 0; r < 4; ++r) {
      unsigned int a01 = cvtpk(p[0][r], p[1][r]);
      unsigned int a23 = cvtpk(p[2][r], p[3][r]);
      const int R = lg * 4 + r;
      P[w][R][lr]      = (unsigned short)a01;
      P[w][R][16 + lr] = (unsigned short)(a01 >> 16);
      P[w][R][32 + lr] = (unsigned short)a23;
      P[w][R][48 + lr] = (unsigned short)(a23 >> 16);
    }
    // PV (V from swizzled LDS), no rescale
#pragma unroll
    for (int ks = 0; ks < 2; ++ks) {
      short8 ap = *(const short8*)&P[w][lr][ks * 32 + lg * 8];
#pragma unroll
      for (int df = 0; df < 4; ++df) {
        int row = df * 16 + lr;
        int rx = row & 7;
        short8 vv = *(const short8*)&Vs[cur][row * 64 + (((ks * 4 + lg) ^ rx) * 8)];
        o[df] = mfma16(ap, vv, o[df]);
      }
    }
    __builtin_amdgcn_s_barrier();
    if (jt + 2 < t1)
      stage_tile(Kbase, Vbase, Ks[cur], Vs[cur], (jt + 2) * 64, tid);
  }
  // write partials (o as bf16)
  const int pbase = (bn * 16 + xt) * 3 + s;
  unsigned short* poB = po + (size_t)pbase * 4096;
#pragma unroll
  for (int r = 0; r < 4; ++r) {
    float v = psum[r];
    v += __shfl_xor(v, 1);
    v += __shfl_xor(v, 2);
    v += __shfl_xor(v, 4);
    v += __shfl_xor(v, 8);
    if (lr == 0) psumG[pbase * 64 + w * 16 + lg * 4 + r] = v;
  }
#pragma unroll
  for (int df = 0; df < 4; ++df)
#pragma unroll
    for (int r = 0; r < 4; ++r)
      poB[(w * 16 + lg * 4 + r) * 64 + df * 16 + lr] = f2bf(o[df][r]);
}

// combine split partials, normalize, emit bf16 vec[t][b][n*64+d]
__global__ __launch_bounds__(256) void k_ared(const unsigned short* __restrict__ po,
                                              const float* __restrict__ psumG,
                                              unsigned short* __restrict__ vec) {
  const int idx = blockIdx.x;      // bn*16 + xt
  const int tid = threadIdx.x;
  const int bn = idx >> 4, xt = idx & 15;
  const int b = bn >> 4, n = bn & 15;
  __shared__ float rs[64];
  if (tid < 64) {
    const float* q = psumG + idx * 192;
    rs[tid] = q[tid] + q[tid + 64] + q[tid + 128];
  }
  __syncthreads();
  const ushort4v* p0 = (const ushort4v*)(po + (size_t)(idx * 3 + 0) * 4096);
  const ushort4v* p1 = (const ushort4v*)(po + (size_t)(idx * 3 + 1) * 4096);
  const ushort4v* p2 = (const ushort4v*)(po + (size_t)(idx * 3 + 2) * 4096);
#pragma unroll
  for (int k = 0; k < 4; ++k) {
    int e = tid + k * 256;          // ushort4 index 0..1023
    int row = e >> 4, d4 = e & 15;
    ushort4v a = p0[e], bb = p1[e], c = p2[e];
    float inv = 1.f / rs[row];
    int t = xt * 64 + row;
    ushort4v ov;
    ov.x = f2bf((bf2f(a.x) + bf2f(bb.x) + bf2f(c.x)) * inv);
    ov.y = f2bf((bf2f(a.y) + bf2f(bb.y) + bf2f(c.y)) * inv);
    ov.z = f2bf((bf2f(a.z) + bf2f(bb.z) + bf2f(c.z)) * inv);
    ov.w = f2bf((bf2f(a.w) + bf2f(bb.w) + bf2f(c.w)) * inv);
    *(ushort4v*)&vec[(size_t)(t * 4 + b) * 1024 + n * 64 + d4 * 4] = ov;
  }
}

// ---------------- residual + layernorm ----------------
__global__ __launch_bounds__(256) void k_ln(const float* __restrict__ xg, const float* __restrict__ h,
                                            const float* __restrict__ gamma, const float* __restrict__ beta,
                                            float* __restrict__ out) {
  const int row = blockIdx.x;
  const int t = threadIdx.x;
  __shared__ float red1[4], red2[4];
  float4v xv = ((const float4v*)(xg + (size_t)row * 1024))[t];
  float4v hv = ((const float4v*)(h + (size_t)row * 1024))[t];
  float x0 = xv.x + hv.x, x1 = xv.y + hv.y, x2 = xv.z + hv.z, x3 = xv.w + hv.w;
  float s = x0 + x1 + x2 + x3;
#pragma unroll
  for (int off = 1; off < 64; off <<= 1) s += __shfl_xor(s, off);
  if ((t & 63) == 0) red1[t >> 6] = s;
  __syncthreads();
  float mean = (red1[0] + red1[1] + red1[2] + red1[3]) * (1.f / 1024.f);
  float d0 = x0 - mean, d1 = x1 - mean, d2 = x2 - mean, d3 = x3 - mean;
  float q = d0 * d0 + d1 * d1 + d2 * d2 + d3 * d3;
#pragma unroll
  for (int off = 1; off < 64; off <<= 1) q += __shfl_xor(q, off);
  if ((t & 63) == 0) red2[t >> 6] = q;
  __syncthreads();
  float var = (red2[0] + red2[1] + red2[2] + red2[3]) * (1.f / 1024.f);
  float rs = rsqrtf(var + 1e-5f);
  float4v gv = ((const float4v*)gamma)[t];
  float4v bv = ((const float4v*)beta)[t];
  float4v ov;
  ov.x = d0 * rs * gv.x + bv.x;
  ov.y = d1 * rs * gv.y + bv.y;
  ov.z = d2 * rs * gv.z + bv.z;
  ov.w = d3 * rs * gv.w + bv.w;
  ((float4v*)(out + (size_t)row * 1024))[t] = ov;
}

extern "C" void kernel_launch(void* const* d_in, const int* in_sizes, int n_in,
                              void* d_out, int out_size, void* d_ws, size_t ws_size,
                              hipStream_t stream) {
  (void)in_sizes; (void)n_in; (void)out_size; (void)ws_size;
  const float* h    = (const float*)d_in[0];
  const float* m    = (const float*)d_in[1];
  const float* r    = (const float*)d_in[2];
  const float* Wqkv = (const float*)d_in[4];
  const float* Wr   = (const float*)d_in[5];
  const float* Wo   = (const float*)d_in[6];
  const float* rwb  = (const float*)d_in[7];
  const float* rrb  = (const float*)d_in[8];
  const float* gam  = (const float*)d_in[9];
  const float* bet  = (const float*)d_in[10];
  float* out = (float*)d_out;

  char* ws = (char*)d_ws;
  unsigned short* catB   = (unsigned short*)(ws + 0);          // 16 MB
  unsigned short* WqkvT  = (unsigned short*)(ws + 16777216);   // 6 MB
  unsigned short* WrT    = (unsigned short*)(ws + 23068672);   // 2 MB
  unsigned short* WoT    = (unsigned short*)(ws + 25165824);   // 2 MB
  unsigned short* Vp     = (unsigned short*)(ws + 27262976);   // 16 MB
  unsigned short* po     = (unsigned short*)(ws + 44040192);   // 24 MB bf16 partials
  unsigned short* VT     = (unsigned short*)(ws + 81788928);   // 16 MB
  unsigned short* vec    = (unsigned short*)(ws + 99221504);   // 8 MB
  float* xbuf            = (float*)(ws + 107610112);           // 16 MB
  unsigned short* rB     = (unsigned short*)(ws + 124387328);  // 4 MB (reused as psumG)
  unsigned short* Kp     = (unsigned short*)(ws + 128581632);  // 16 MB
  unsigned short* Qp     = (unsigned short*)(ws + 145358848);  // 8 MB
  unsigned short* Rkp    = (unsigned short*)(ws + 153747456);  // 4 MB -> ~158 MB total
  float* psumG = (float*)(ws + 124387328);                     // over dead rB

  hipLaunchKernelGGL(k_cat_convert, dim3(8192), dim3(256), 0, stream, m, h, catB);
  hipLaunchKernelGGL(k_f32_to_bf16, dim3(2048), dim3(256), 0, stream, r, rB, 524288);
  hipLaunchKernelGGL(k_transpose_bf16, dim3(96, 32), dim3(256), 0, stream, Wqkv, WqkvT, 1024, 3072);
  hipLaunchKernelGGL(k_transpose_bf16, dim3(32, 32), dim3(256), 0, stream, Wr, WrT, 1024, 1024);
  hipLaunchKernelGGL(k_transpose_bf16, dim3(32, 32), dim3(256), 0, stream, Wo, WoT, 1024, 1024);
  hipLaunchKernelGGL(k_gemm<2>, dim3(16, 64), dim3(256), 0, stream,
                     catB, WqkvT + (size_t)1024 * 1024, (void*)Kp, (void*)Vp, 8192, 2048, 1024, 0);
  hipLaunchKernelGGL(k_gemm<3>, dim3(8, 32), dim3(256), 0, stream,
                     catB + (size_t)4096 * 1024, WqkvT, (void*)Qp, nullptr, 4096, 1024, 1024, 0);
  hipLaunchKernelGGL(k_gemm<4>, dim3(8, 16), dim3(256), 0, stream,
                     rB, WrT, (void*)Rkp, nullptr, 2048, 1024, 1024, 0);
  hipLaunchKernelGGL(k_vt, dim3(32, 16, 4), dim3(256), 0, stream, Vp, VT);
  hipLaunchKernelGGL(k_attn, dim3(3072), dim3(256), 0, stream, Qp, Kp, VT, Rkp, rwb, rrb, po, psumG);
  hipLaunchKernelGGL(k_ared, dim3(1024), dim3(256), 0, stream, po, psumG, vec);
  hipLaunchKernelGGL(k_gemm<1>, dim3(8, 32), dim3(256), 0, stream,
                     vec, WoT, (void*)xbuf, nullptr, 4096, 1024, 1024, 1024);
  hipLaunchKernelGGL(k_ln, dim3(4096), dim3(256), 0, stream, xbuf, h, gam, bet, out);
}

// Round 15
// 322.921 us; speedup vs baseline: 1.0868x; 1.0157x over previous
//
#include <hip/hip_runtime.h>
#include <stdint.h>

#define T_LEN 1024
#define MEM_LEN 1024
#define C_LEN 2048
#define B_SZ 4
#define DM_ 1024
#define NH 16
#define HD 64

typedef __attribute__((ext_vector_type(8))) short short8;
typedef __attribute__((ext_vector_type(4))) float f32x4;
typedef __attribute__((ext_vector_type(4))) unsigned short ushort4v;
typedef __attribute__((ext_vector_type(8))) unsigned short ushort8v;
typedef __attribute__((ext_vector_type(4))) float float4v;

__device__ __forceinline__ unsigned short f2bf(float f) {
  union { float f; unsigned int u; } v; v.f = f;
  unsigned int r = v.u + 0x7fffu + ((v.u >> 16) & 1u);
  return (unsigned short)(r >> 16);
}
__device__ __forceinline__ float bf2f(unsigned short b) {
  union { unsigned int u; float f; } v; v.u = ((unsigned int)b) << 16;
  return v.f;
}
__device__ __forceinline__ unsigned int cvtpk(float lo, float hi) {
  unsigned int r;
  asm("v_cvt_pk_bf16_f32 %0, %1, %2" : "=v"(r) : "v"(lo), "v"(hi));
  return r;
}
__device__ __forceinline__ f32x4 mfma16(short8 a, short8 b, f32x4 c) {
  return __builtin_amdgcn_mfma_f32_16x16x32_bf16(a, b, c, 0, 0, 0);
}

// ---------------- fused converts: cat=[m;h] -> catB, r -> rB ----------------
__global__ void k_convert_all(const float* __restrict__ m, const float* __restrict__ h,
                              const float* __restrict__ r,
                              unsigned short* __restrict__ catB,
                              unsigned short* __restrict__ rB) {
  int idx = blockIdx.x * 256 + threadIdx.x;
  const int MQ = (MEM_LEN * B_SZ * DM_) / 4;      // 1M quads
  const int CQ = 2 * MQ;                           // cat total quads (2M)
  float4v v;
  unsigned short* dst;
  int di;
  if (idx < MQ)      { v = ((const float4v*)m)[idx];       dst = catB; di = idx; }
  else if (idx < CQ) { v = ((const float4v*)h)[idx - MQ];  dst = catB; di = idx; }
  else               { v = ((const float4v*)r)[idx - CQ];  dst = rB;   di = idx - CQ; }
  ushort4v o;
  o.x = f2bf(v.x); o.y = f2bf(v.y); o.z = f2bf(v.z); o.w = f2bf(v.w);
  ((ushort4v*)dst)[di] = o;
}

// fused transpose of the three weights: z=0 Wqkv(1024x3072), z=1 Wr, z=2 Wo (1024x1024)
__global__ void k_transpose_w(const float* __restrict__ Wqkv, const float* __restrict__ Wr,
                              const float* __restrict__ Wo,
                              unsigned short* __restrict__ WqkvT, unsigned short* __restrict__ WrT,
                              unsigned short* __restrict__ WoT) {
  __shared__ float tile[32][33];
  const int z = blockIdx.z;
  const int Ccols = (z == 0) ? 3072 : 1024;
  if (blockIdx.x * 32 >= Ccols) return;
  const float* in = (z == 0) ? Wqkv : (z == 1) ? Wr : Wo;
  unsigned short* out = (z == 0) ? WqkvT : (z == 1) ? WrT : WoT;
  int c0 = blockIdx.x * 32, r0 = blockIdx.y * 32;
  int tx = threadIdx.x & 31, ty = threadIdx.x >> 5;
#pragma unroll
  for (int p = 0; p < 4; ++p)
    tile[ty + 8 * p][tx] = in[(size_t)(r0 + ty + 8 * p) * Ccols + c0 + tx];
  __syncthreads();
#pragma unroll
  for (int p = 0; p < 4; ++p)
    out[(size_t)(c0 + ty + 8 * p) * 1024 + r0 + tx] = f2bf(tile[tx][ty + 8 * p]);
}

// ---------------- GEMM with direct-layout epilogues, XCD-swizzled grid ----------------
template <int MODE>
__global__ __launch_bounds__(256) void k_gemm(const unsigned short* __restrict__ A,
                                              const unsigned short* __restrict__ BT,
                                              void* __restrict__ out1, void* __restrict__ out2,
                                              int M, int N, int K, int ldc) {
  __shared__ unsigned short As[128 * 64];
  __shared__ unsigned short Bs[128 * 64];
  const int tid = threadIdx.x;
  const int w = tid >> 6, l = tid & 63;
  const int wm = w >> 1, wn = w & 1;
  const int lg = l >> 4, lr = l & 15;
  const int gx = gridDim.x;
  const int pid = blockIdx.y * gx + blockIdx.x;
  const int xcd = pid & 7;
  const int idx = pid >> 3;
  const int cb = idx % gx;
  const int rb = (idx / gx) * 8 + xcd;
  const int m0 = rb * 128, n0 = cb * 128;
  f32x4 acc[4][4] = {};
  const int lrow8 = l >> 3;
  const int scol = (l & 7) * 8;
  const unsigned short* Abase = A + (size_t)m0 * K;
  const unsigned short* Bbase = BT + (size_t)n0 * K;
  for (int kt = 0; kt < K; kt += 64) {
    __syncthreads();
#pragma unroll
    for (int q = 0; q < 4; ++q) {
      int chunk = w * 4 + q;
      int row = chunk * 8 + lrow8;
      __builtin_amdgcn_global_load_lds(
          (const __attribute__((address_space(1))) void*)(Abase + (size_t)row * K + kt + scol),
          (__attribute__((address_space(3))) void*)(As + chunk * 512), 16, 0, 0);
      __builtin_amdgcn_global_load_lds(
          (const __attribute__((address_space(1))) void*)(Bbase + (size_t)row * K + kt + scol),
          (__attribute__((address_space(3))) void*)(Bs + chunk * 512), 16, 0, 0);
    }
    __syncthreads();
#pragma unroll
    for (int ks = 0; ks < 2; ++ks) {
      short8 a[4], bb[4];
#pragma unroll
      for (int mi = 0; mi < 4; ++mi)
        a[mi] = *(const short8*)&As[(wm * 64 + mi * 16 + lr) * 64 + ks * 32 + lg * 8];
#pragma unroll
      for (int ni = 0; ni < 4; ++ni)
        bb[ni] = *(const short8*)&Bs[(wn * 64 + ni * 16 + lr) * 64 + ks * 32 + lg * 8];
#pragma unroll
      for (int mi = 0; mi < 4; ++mi)
#pragma unroll
        for (int ni = 0; ni < 4; ++ni)
          acc[mi][ni] = mfma16(a[mi], bb[ni], acc[mi][ni]);
    }
  }
#pragma unroll
  for (int mi = 0; mi < 4; ++mi)
#pragma unroll
    for (int ni = 0; ni < 4; ++ni)
#pragma unroll
      for (int r = 0; r < 4; ++r) {
        int row = m0 + wm * 64 + mi * 16 + lg * 4 + r;
        int cc = n0 + wn * 64 + ni * 16 + lr;
        float val = acc[mi][ni][r];
        if (MODE == 1) {
          ((float*)out1)[(size_t)row * ldc + cc] = val;
        } else if (MODE == 2) {
          int nn = (cc & 1023) >> 6, d = cc & 63;
          int c = row >> 2, b = row & 3;
          size_t addr = ((size_t)((b * 16 + nn) * 2048 + c)) * 64 + d;
          unsigned short* dst = (cc < 1024) ? (unsigned short*)out1 : (unsigned short*)out2;
          dst[addr] = f2bf(val);
        } else if (MODE == 3) {
          int nn = cc >> 6, d = cc & 63;
          int t = row >> 2, b = row & 3;
          ((unsigned short*)out1)[((size_t)((b * 16 + nn) * 1024 + t)) * 64 + d] = f2bf(val);
        } else {  // MODE 4
          int nn = cc >> 6, d = cc & 63;
          ((unsigned short*)out1)[((size_t)(nn * 2048 + row)) * 64 + d] = f2bf(val);
        }
      }
}

// ---------------- V transpose: Vp[b][n][c][d] -> VT[b][n][d][c] ----------------
__global__ void k_vt(const unsigned short* __restrict__ Vp, unsigned short* __restrict__ VT) {
  __shared__ unsigned short tile[64][72];
  int c0 = blockIdx.x * 64;
  int n = blockIdx.y, b = blockIdx.z;
  int t = threadIdx.x;
  const unsigned short* src = Vp + ((size_t)((b * 16 + n) * 2048 + c0)) * 64;
#pragma unroll
  for (int p = 0; p < 16; ++p) {
    int idx = p * 256 + t;
    int r = idx >> 6, d = idx & 63;
    tile[d][r] = src[(size_t)r * 64 + d];
  }
  __syncthreads();
#pragma unroll
  for (int p = 0; p < 16; ++p) {
    int idx = p * 256 + t;
    int d = idx >> 6, c = idx & 63;
    VT[(size_t)((b * 16 + n) * 64 + d) * 2048 + c0 + c] = tile[d][c];
  }
}

// ---------------- split-j flash attention (4-wave KVBLK=64; bias-folded Q; setprio) -------
__device__ __forceinline__ void stage_tile(const unsigned short* __restrict__ Kbase,
                                           const unsigned short* __restrict__ Vbase,
                                           unsigned short* ksBuf, unsigned short* vsBuf,
                                           int j0, int tid) {
#pragma unroll
  for (int q = 0; q < 2; ++q) {
    int chunk = q * 256 + tid;   // 0..511
    int row = chunk >> 3;        // 0..63
    int slot = chunk & 7;
    int ss = slot ^ (row & 7);   // source pre-swizzle (rule #21)
    __builtin_amdgcn_global_load_lds(
        (const __attribute__((address_space(1))) void*)(Kbase + (size_t)(j0 + row) * 64 + ss * 8),
        (__attribute__((address_space(3))) void*)(ksBuf + chunk * 8), 16, 0, 0);
    __builtin_amdgcn_global_load_lds(
        (const __attribute__((address_space(1))) void*)(Vbase + (size_t)row * 2048 + j0 + ss * 8),
        (__attribute__((address_space(3))) void*)(vsBuf + chunk * 8), 16, 0, 0);
  }
}

__global__ __launch_bounds__(256) void k_attn(const unsigned short* __restrict__ Qp,
                                              const unsigned short* __restrict__ Kp,
                                              const unsigned short* __restrict__ VT,
                                              const unsigned short* __restrict__ Rkp,
                                              const float* __restrict__ rwb,
                                              const float* __restrict__ rrb,
                                              unsigned short* __restrict__ po,
                                              float* __restrict__ psumG) {
  __shared__ __align__(16) unsigned short Ks[2][64 * 64];
  __shared__ __align__(16) unsigned short Vs[2][64 * 64];
  __shared__ unsigned short P[4][16][72];
  const int tid = threadIdx.x;
  const int w = tid >> 6, l = tid & 63;
  const int lg = l >> 4, lr = l & 15;
  const int L = blockIdx.x;
  const int bnlo = L & 7;
  const int rest = L >> 3;
  const int bnhi = rest / 48;
  const int inner = rest - bnhi * 48;
  const int xt = inner / 3;
  const int s  = inner - xt * 3;
  const int bn = bnhi * 8 + bnlo;
  const int i0 = xt * 64;
  const int n = bn & 15, b = bn >> 4;
  const int wrow = i0 + w * 16;

  const int ntile = xt + 17;
  const int t0 = (s * ntile) / 3;
  const int t1 = ((s + 1) * ntile) / 3;

  const unsigned short* Kbase = Kp + (size_t)bn * 2048 * 64;
  const unsigned short* Vbase = VT + (size_t)bn * 64 * 2048;
  const unsigned short* Rkbase = Rkp + (size_t)n * 2048 * 64;

  short8 aq0u, aq1u, aq0v, aq1v;
  {
    const unsigned short* qp = Qp + (size_t)(bn * 1024 + wrow + lr) * 64 + lg * 8;
    short8 q0 = *(const short8*)qp;
    short8 q1 = *(const short8*)(qp + 32);
    const float* up = rwb + n * 64 + lg * 8;
    const float* vp = rrb + n * 64 + lg * 8;
#pragma unroll
    for (int e = 0; e < 8; ++e) {
      float q0f = bf2f((unsigned short)q0[e]);
      float q1f = bf2f((unsigned short)q1[e]);
      aq0u[e] = (short)f2bf(q0f + up[e]);
      aq1u[e] = (short)f2bf(q1f + up[e + 32]);
      aq0v[e] = (short)f2bf(q0f + vp[e]);
      aq1v[e] = (short)f2bf(q1f + vp[e + 32]);
    }
  }
  float psum[4];
  f32x4 o[4];
#pragma unroll
  for (int r = 0; r < 4; ++r) psum[r] = 0.f;
#pragma unroll
  for (int df = 0; df < 4; ++df) o[df] = (f32x4){0.f, 0.f, 0.f, 0.f};

  stage_tile(Kbase, Vbase, Ks[0], Vs[0], t0 * 64, tid);
  stage_tile(Kbase, Vbase, Ks[1], Vs[1], (t0 + 1) * 64, tid);

  const float EXPC = 0.18033688011112042f;

  for (int jt = t0; jt < t1; ++jt) {
    const int j0 = jt * 64;
    const int cur = (jt - t0) & 1;
    if (jt + 1 < t1) { asm volatile("s_waitcnt vmcnt(4)" ::: "memory"); }
    else             { asm volatile("s_waitcnt vmcnt(0)" ::: "memory"); }
    __builtin_amdgcn_s_barrier();

    f32x4 sac[4];
#pragma unroll
    for (int jf = 0; jf < 4; ++jf) sac[jf] = (f32x4){0.f, 0.f, 0.f, 0.f};
    __builtin_amdgcn_s_setprio(1);
#pragma unroll
    for (int jf = 0; jf < 4; ++jf) {
      int row = jf * 16 + lr;
      int rx = row & 7;
      short8 k0 = *(const short8*)&Ks[cur][row * 64 + ((lg ^ rx) * 8)];
      short8 k1 = *(const short8*)&Ks[cur][row * 64 + (((4 + lg) ^ rx) * 8)];
      sac[jf] = mfma16(aq0u, k0, sac[jf]);
      sac[jf] = mfma16(aq1u, k1, sac[jf]);
    }
    __builtin_amdgcn_s_setprio(0);
    const int kbw = j0 + 1008 - i0 - w * 16;
    f32x4 gb[5];
#pragma unroll
    for (int jg = 0; jg < 5; ++jg) {
      int rowK = kbw + jg * 16 + lr;
      short8 b0 = {}, b1 = {};
      if (rowK < C_LEN) {
        const unsigned short* rp = Rkbase + (size_t)rowK * 64 + lg * 8;
        b0 = *(const short8*)rp;
        b1 = *(const short8*)(rp + 32);
      }
      f32x4 g = (f32x4){0.f, 0.f, 0.f, 0.f};
      g = mfma16(aq0v, b0, g);
      g = mfma16(aq1v, b1, g);
      gb[jg] = g;
    }
    const bool needMask = (j0 + 63 > i0 + w * 16 + MEM_LEN);
    float p[4][4];
#pragma unroll
    for (int r = 0; r < 4; ++r) {
      const int R = lg * 4 + r;
      const int delta = lr + 15 - R;
      const int src = (l & 48) | (delta & 15);
      float v0 = __shfl(gb[0][r], src);
      float v1 = __shfl(gb[1][r], src);
      float v2 = __shfl(gb[2][r], src);
      float v3 = __shfl(gb[3][r], src);
      float v4 = __shfl(gb[4][r], src);
      const bool hi = delta >= 16;
      float bd0 = hi ? v1 : v0;
      float bd1 = hi ? v2 : v1;
      float bd2 = hi ? v3 : v2;
      float bd3 = hi ? v4 : v3;
      float e0 = exp2f((sac[0][r] + bd0) * EXPC);
      float e1 = exp2f((sac[1][r] + bd1) * EXPC);
      float e2 = exp2f((sac[2][r] + bd2) * EXPC);
      float e3 = exp2f((sac[3][r] + bd3) * EXPC);
      if (needMask) {
        const int jlim = i0 + w * 16 + R + MEM_LEN;
        int j = j0 + lr;
        e0 = (j > jlim) ? 0.f : e0;  j += 16;
        e1 = (j > jlim) ? 0.f : e1;  j += 16;
        e2 = (j > jlim) ? 0.f : e2;  j += 16;
        e3 = (j > jlim) ? 0.f : e3;
      }
      p[0][r] = e0; p[1][r] = e1; p[2][r] = e2; p[3][r] = e3;
    }
#pragma unroll
    for (int jf = 0; jf < 4; ++jf)
#pragma unroll
      for (int r = 0; r < 4; ++r) psum[r] += p[jf][r];
#pragma unroll
    for (int r = 0; r < 4; ++r) {
      unsigned int a01 = cvtpk(p[0][r], p[1][r]);
      unsigned int a23 = cvtpk(p[2][r], p[3][r]);
      const int R = lg * 4 + r;
      P[w][R][lr]      = (unsigned short)a01;
      P[w][R][16 + lr] = (unsigned short)(a01 >> 16);
      P[w][R][32 + lr] = (unsigned short)a23;
      P[w][R][48 + lr] = (unsigned short)(a23 >> 16);
    }
    __builtin_amdgcn_s_setprio(1);
#pragma unroll
    for (int ks = 0; ks < 2; ++ks) {
      short8 ap = *(const short8*)&P[w][lr][ks * 32 + lg * 8];
#pragma unroll
      for (int df = 0; df < 4; ++df) {
        int row = df * 16 + lr;
        int rx = row & 7;
        short8 vv = *(const short8*)&Vs[cur][row * 64 + (((ks * 4 + lg) ^ rx) * 8)];
        o[df] = mfma16(ap, vv, o[df]);
      }
    }
    __builtin_amdgcn_s_setprio(0);
    __builtin_amdgcn_s_barrier();
    if (jt + 2 < t1)
      stage_tile(Kbase, Vbase, Ks[cur], Vs[cur], (jt + 2) * 64, tid);
  }
  const int pbase = (bn * 16 + xt) * 3 + s;
  unsigned short* poB = po + (size_t)pbase * 4096;
#pragma unroll
  for (int r = 0; r < 4; ++r) {
    float v = psum[r];
    v += __shfl_xor(v, 1);
    v += __shfl_xor(v, 2);
    v += __shfl_xor(v, 4);
    v += __shfl_xor(v, 8);
    if (lr == 0) psumG[pbase * 64 + w * 16 + lg * 4 + r] = v;
  }
#pragma unroll
  for (int df = 0; df < 4; ++df)
#pragma unroll
    for (int r = 0; r < 4; ++r)
      poB[(w * 16 + lg * 4 + r) * 64 + df * 16 + lr] = f2bf(o[df][r]);
}

// combine split partials, normalize, emit bf16 vec[t][b][n*64+d]
__global__ __launch_bounds__(256) void k_ared(const unsigned short* __restrict__ po,
                                              const float* __restrict__ psumG,
                                              unsigned short* __restrict__ vec) {
  const int idx = blockIdx.x;
  const int tid = threadIdx.x;
  const int bn = idx >> 4, xt = idx & 15;
  const int b = bn >> 4, n = bn & 15;
  __shared__ float rs[64];
  if (tid < 64) {
    const float* q = psumG + idx * 192;
    rs[tid] = q[tid] + q[tid + 64] + q[tid + 128];
  }
  __syncthreads();
  const ushort8v* p0 = (const ushort8v*)(po + (size_t)(idx * 3 + 0) * 4096);
  const ushort8v* p1 = (const ushort8v*)(po + (size_t)(idx * 3 + 1) * 4096);
  const ushort8v* p2 = (const ushort8v*)(po + (size_t)(idx * 3 + 2) * 4096);
#pragma unroll
  for (int k = 0; k < 2; ++k) {
    int e = tid + k * 256;          // ushort8 index 0..511
    int row = e >> 3, d8 = e & 7;
    ushort8v a = p0[e], bb = p1[e], c = p2[e];
    float inv = 1.f / rs[row];
    int t = xt * 64 + row;
    ushort8v ov;
#pragma unroll
    for (int q = 0; q < 8; ++q)
      ov[q] = f2bf((bf2f(a[q]) + bf2f(bb[q]) + bf2f(c[q])) * inv);
    *(ushort8v*)&vec[(size_t)(t * 4 + b) * 1024 + n * 64 + d8 * 8] = ov;
  }
}

// ---------------- residual + layernorm ----------------
__global__ __launch_bounds__(256) void k_ln(const float* __restrict__ xg, const float* __restrict__ h,
                                            const float* __restrict__ gamma, const float* __restrict__ beta,
                                            float* __restrict__ out) {
  const int row = blockIdx.x;
  const int t = threadIdx.x;
  __shared__ float red1[4], red2[4];
  float4v xv = ((const float4v*)(xg + (size_t)row * 1024))[t];
  float4v hv = ((const float4v*)(h + (size_t)row * 1024))[t];
  float x0 = xv.x + hv.x, x1 = xv.y + hv.y, x2 = xv.z + hv.z, x3 = xv.w + hv.w;
  float s = x0 + x1 + x2 + x3;
#pragma unroll
  for (int off = 1; off < 64; off <<= 1) s += __shfl_xor(s, off);
  if ((t & 63) == 0) red1[t >> 6] = s;
  __syncthreads();
  float mean = (red1[0] + red1[1] + red1[2] + red1[3]) * (1.f / 1024.f);
  float d0 = x0 - mean, d1 = x1 - mean, d2 = x2 - mean, d3 = x3 - mean;
  float q = d0 * d0 + d1 * d1 + d2 * d2 + d3 * d3;
#pragma unroll
  for (int off = 1; off < 64; off <<= 1) q += __shfl_xor(q, off);
  if ((t & 63) == 0) red2[t >> 6] = q;
  __syncthreads();
  float var = (red2[0] + red2[1] + red2[2] + red2[3]) * (1.f / 1024.f);
  float rs = rsqrtf(var + 1e-5f);
  float4v gv = ((const float4v*)gamma)[t];
  float4v bv = ((const float4v*)beta)[t];
  float4v ov;
  ov.x = d0 * rs * gv.x + bv.x;
  ov.y = d1 * rs * gv.y + bv.y;
  ov.z = d2 * rs * gv.z + bv.z;
  ov.w = d3 * rs * gv.w + bv.w;
  ((float4v*)(out + (size_t)row * 1024))[t] = ov;
}

extern "C" void kernel_launch(void* const* d_in, const int* in_sizes, int n_in,
                              void* d_out, int out_size, void* d_ws, size_t ws_size,
                              hipStream_t stream) {
  (void)in_sizes; (void)n_in; (void)out_size; (void)ws_size;
  const float* h    = (const float*)d_in[0];
  const float* m    = (const float*)d_in[1];
  const float* r    = (const float*)d_in[2];
  const float* Wqkv = (const float*)d_in[4];
  const float* Wr   = (const float*)d_in[5];
  const float* Wo   = (const float*)d_in[6];
  const float* rwb  = (const float*)d_in[7];
  const float* rrb  = (const float*)d_in[8];
  const float* gam  = (const float*)d_in[9];
  const float* bet  = (const float*)d_in[10];
  float* out = (float*)d_out;

  char* ws = (char*)d_ws;
  unsigned short* catB   = (unsigned short*)(ws + 0);          // 16 MB
  unsigned short* WqkvT  = (unsigned short*)(ws + 16777216);   // 6 MB
  unsigned short* WrT    = (unsigned short*)(ws + 23068672);   // 2 MB
  unsigned short* WoT    = (unsigned short*)(ws + 25165824);   // 2 MB
  unsigned short* Vp     = (unsigned short*)(ws + 27262976);   // 16 MB
  unsigned short* po     = (unsigned short*)(ws + 44040192);   // 24 MB bf16 partials
  unsigned short* VT     = (unsigned short*)(ws + 81788928);   // 16 MB
  unsigned short* vec    = (unsigned short*)(ws + 99221504);   // 8 MB
  float* xbuf            = (float*)(ws + 107610112);           // 16 MB
  unsigned short* rB     = (unsigned short*)(ws + 124387328);  // 4 MB (reused as psumG)
  unsigned short* Kp     = (unsigned short*)(ws + 128581632);  // 16 MB
  unsigned short* Qp     = (unsigned short*)(ws + 145358848);  // 8 MB
  unsigned short* Rkp    = (unsigned short*)(ws + 153747456);  // 4 MB -> ~158 MB total
  float* psumG = (float*)(ws + 124387328);                     // over dead rB

  // fused converts: 2M (cat) + 512K (r) quads = 2.5M -> 10240 blocks
  hipLaunchKernelGGL(k_convert_all, dim3(10240), dim3(256), 0, stream, m, h, r, catB, rB);
  // fused weight transposes
  hipLaunchKernelGGL(k_transpose_w, dim3(96, 32, 3), dim3(256), 0, stream,
                     Wqkv, Wr, Wo, WqkvT, WrT, WoT);
  hipLaunchKernelGGL(k_gemm<2>, dim3(16, 64), dim3(256), 0, stream,
                     catB, WqkvT + (size_t)1024 * 1024, (void*)Kp, (void*)Vp, 8192, 2048, 1024, 0);
  hipLaunchKernelGGL(k_gemm<3>, dim3(8, 32), dim3(256), 0, stream,
                     catB + (size_t)4096 * 1024, WqkvT, (void*)Qp, nullptr, 4096, 1024, 1024, 0);
  hipLaunchKernelGGL(k_gemm<4>, dim3(8, 16), dim3(256), 0, stream,
                     rB, WrT, (void*)Rkp, nullptr, 2048, 1024, 1024, 0);
  hipLaunchKernelGGL(k_vt, dim3(32, 16, 4), dim3(256), 0, stream, Vp, VT);
  hipLaunchKernelGGL(k_attn, dim3(3072), dim3(256), 0, stream, Qp, Kp, VT, Rkp, rwb, rrb, po, psumG);
  hipLaunchKernelGGL(k_ared, dim3(1024), dim3(256), 0, stream, po, psumG, vec);
  hipLaunchKernelGGL(k_gemm<1>, dim3(8, 32), dim3(256), 0, stream,
                     vec, WoT, (void*)xbuf, nullptr, 4096, 1024, 1024, 1024);
  hipLaunchKernelGGL(k_ln, dim3(4096), dim3(256), 0, stream, xbuf, h, gam, bet, out);
}

// Round 16
// 312.309 us; speedup vs baseline: 1.1238x; 1.0340x over previous
//
#include <hip/hip_runtime.h>
#include <stdint.h>

#define T_LEN 1024
#define MEM_LEN 1024
#define C_LEN 2048
#define B_SZ 4
#define DM_ 1024
#define NH 16
#define HD 64

typedef __attribute__((ext_vector_type(8))) short short8;
typedef __attribute__((ext_vector_type(4))) float f32x4;
typedef __attribute__((ext_vector_type(4))) unsigned short ushort4v;
typedef __attribute__((ext_vector_type(8))) unsigned short ushort8v;
typedef __attribute__((ext_vector_type(4))) float float4v;

__device__ __forceinline__ unsigned short f2bf(float f) {
  union { float f; unsigned int u; } v; v.f = f;
  unsigned int r = v.u + 0x7fffu + ((v.u >> 16) & 1u);
  return (unsigned short)(r >> 16);
}
__device__ __forceinline__ float bf2f(unsigned short b) {
  union { unsigned int u; float f; } v; v.u = ((unsigned int)b) << 16;
  return v.f;
}
__device__ __forceinline__ unsigned int cvtpk(float lo, float hi) {
  unsigned int r;
  asm("v_cvt_pk_bf16_f32 %0, %1, %2" : "=v"(r) : "v"(lo), "v"(hi));
  return r;
}
__device__ __forceinline__ f32x4 mfma16(short8 a, short8 b, f32x4 c) {
  return __builtin_amdgcn_mfma_f32_16x16x32_bf16(a, b, c, 0, 0, 0);
}

// ---------------- fused converts: cat=[m;h] -> catB, r -> rB ----------------
__global__ void k_convert_all(const float* __restrict__ m, const float* __restrict__ h,
                              const float* __restrict__ r,
                              unsigned short* __restrict__ catB,
                              unsigned short* __restrict__ rB) {
  int idx = blockIdx.x * 256 + threadIdx.x;
  const int MQ = (MEM_LEN * B_SZ * DM_) / 4;
  const int CQ = 2 * MQ;
  float4v v;
  unsigned short* dst;
  int di;
  if (idx < MQ)      { v = ((const float4v*)m)[idx];       dst = catB; di = idx; }
  else if (idx < CQ) { v = ((const float4v*)h)[idx - MQ];  dst = catB; di = idx; }
  else               { v = ((const float4v*)r)[idx - CQ];  dst = rB;   di = idx - CQ; }
  ushort4v o;
  o.x = f2bf(v.x); o.y = f2bf(v.y); o.z = f2bf(v.z); o.w = f2bf(v.w);
  ((ushort4v*)dst)[di] = o;
}

// fused transpose of the three weights
__global__ void k_transpose_w(const float* __restrict__ Wqkv, const float* __restrict__ Wr,
                              const float* __restrict__ Wo,
                              unsigned short* __restrict__ WqkvT, unsigned short* __restrict__ WrT,
                              unsigned short* __restrict__ WoT) {
  __shared__ float tile[32][33];
  const int z = blockIdx.z;
  const int Ccols = (z == 0) ? 3072 : 1024;
  if (blockIdx.x * 32 >= Ccols) return;
  const float* in = (z == 0) ? Wqkv : (z == 1) ? Wr : Wo;
  unsigned short* out = (z == 0) ? WqkvT : (z == 1) ? WrT : WoT;
  int c0 = blockIdx.x * 32, r0 = blockIdx.y * 32;
  int tx = threadIdx.x & 31, ty = threadIdx.x >> 5;
#pragma unroll
  for (int p = 0; p < 4; ++p)
    tile[ty + 8 * p][tx] = in[(size_t)(r0 + ty + 8 * p) * Ccols + c0 + tx];
  __syncthreads();
#pragma unroll
  for (int p = 0; p < 4; ++p)
    out[(size_t)(c0 + ty + 8 * p) * 1024 + r0 + tx] = f2bf(tile[tx][ty + 8 * p]);
}

// ---------------- fused QKV+Rk GEMM (1408 blocks), direct-layout epilogues, XCD swizzle ----
__global__ __launch_bounds__(256) void k_gemm_qkv(const unsigned short* __restrict__ catB,
                                                  const unsigned short* __restrict__ rB,
                                                  const unsigned short* __restrict__ WqkvT,
                                                  const unsigned short* __restrict__ WrT,
                                                  unsigned short* __restrict__ Kp,
                                                  unsigned short* __restrict__ Vp,
                                                  unsigned short* __restrict__ Qp,
                                                  unsigned short* __restrict__ Rkp) {
  __shared__ unsigned short As[128 * 64];
  __shared__ unsigned short Bs[128 * 64];
  const int tid = threadIdx.x;
  const int w = tid >> 6, l = tid & 63;
  const int wm = w >> 1, wn = w & 1;
  const int lg = l >> 4, lr = l & 15;
  const int bid = blockIdx.x;
  int mode, lpid, gx;
  const unsigned short *A, *BT;
  if (bid < 1024)      { mode = 2; lpid = bid;        gx = 16; A = catB;                        BT = WqkvT + (size_t)1024 * 1024; }
  else if (bid < 1280) { mode = 3; lpid = bid - 1024; gx = 8;  A = catB + (size_t)4096 * 1024;  BT = WqkvT; }
  else                 { mode = 4; lpid = bid - 1280; gx = 8;  A = rB;                          BT = WrT; }
  const int K = 1024;
  const int xcd = lpid & 7;
  const int idx = lpid >> 3;
  const int cb = idx % gx;
  const int rb = (idx / gx) * 8 + xcd;
  const int m0 = rb * 128, n0 = cb * 128;
  f32x4 acc[4][4] = {};
  const int lrow8 = l >> 3;
  const int scol = (l & 7) * 8;
  const unsigned short* Abase = A + (size_t)m0 * K;
  const unsigned short* Bbase = BT + (size_t)n0 * K;
  for (int kt = 0; kt < K; kt += 64) {
    __syncthreads();
#pragma unroll
    for (int q = 0; q < 4; ++q) {
      int chunk = w * 4 + q;
      int row = chunk * 8 + lrow8;
      __builtin_amdgcn_global_load_lds(
          (const __attribute__((address_space(1))) void*)(Abase + (size_t)row * K + kt + scol),
          (__attribute__((address_space(3))) void*)(As + chunk * 512), 16, 0, 0);
      __builtin_amdgcn_global_load_lds(
          (const __attribute__((address_space(1))) void*)(Bbase + (size_t)row * K + kt + scol),
          (__attribute__((address_space(3))) void*)(Bs + chunk * 512), 16, 0, 0);
    }
    __syncthreads();
#pragma unroll
    for (int ks = 0; ks < 2; ++ks) {
      short8 a[4], bb[4];
#pragma unroll
      for (int mi = 0; mi < 4; ++mi)
        a[mi] = *(const short8*)&As[(wm * 64 + mi * 16 + lr) * 64 + ks * 32 + lg * 8];
#pragma unroll
      for (int ni = 0; ni < 4; ++ni)
        bb[ni] = *(const short8*)&Bs[(wn * 64 + ni * 16 + lr) * 64 + ks * 32 + lg * 8];
#pragma unroll
      for (int mi = 0; mi < 4; ++mi)
#pragma unroll
        for (int ni = 0; ni < 4; ++ni)
          acc[mi][ni] = mfma16(a[mi], bb[ni], acc[mi][ni]);
    }
  }
#pragma unroll
  for (int mi = 0; mi < 4; ++mi)
#pragma unroll
    for (int ni = 0; ni < 4; ++ni)
#pragma unroll
      for (int r = 0; r < 4; ++r) {
        int row = m0 + wm * 64 + mi * 16 + lg * 4 + r;
        int cc = n0 + wn * 64 + ni * 16 + lr;
        float val = acc[mi][ni][r];
        if (mode == 2) {
          int nn = (cc & 1023) >> 6, d = cc & 63;
          int c = row >> 2, b = row & 3;
          size_t addr = ((size_t)((b * 16 + nn) * 2048 + c)) * 64 + d;
          unsigned short* dst = (cc < 1024) ? Kp : Vp;
          dst[addr] = f2bf(val);
        } else if (mode == 3) {
          int nn = cc >> 6, d = cc & 63;
          int t = row >> 2, b = row & 3;
          Qp[((size_t)((b * 16 + nn) * 1024 + t)) * 64 + d] = f2bf(val);
        } else {
          int nn = cc >> 6, d = cc & 63;
          Rkp[((size_t)(nn * 2048 + row)) * 64 + d] = f2bf(val);
        }
      }
}

// out-projection GEMM (f32 out), XCD swizzle
__global__ __launch_bounds__(256) void k_gemm_o(const unsigned short* __restrict__ A,
                                                const unsigned short* __restrict__ BT,
                                                float* __restrict__ Cout, int M, int N, int K) {
  __shared__ unsigned short As[128 * 64];
  __shared__ unsigned short Bs[128 * 64];
  const int tid = threadIdx.x;
  const int w = tid >> 6, l = tid & 63;
  const int wm = w >> 1, wn = w & 1;
  const int lg = l >> 4, lr = l & 15;
  const int gx = gridDim.x;
  const int pid = blockIdx.y * gx + blockIdx.x;
  const int xcd = pid & 7;
  const int idx = pid >> 3;
  const int cb = idx % gx;
  const int rb = (idx / gx) * 8 + xcd;
  const int m0 = rb * 128, n0 = cb * 128;
  f32x4 acc[4][4] = {};
  const int lrow8 = l >> 3;
  const int scol = (l & 7) * 8;
  const unsigned short* Abase = A + (size_t)m0 * K;
  const unsigned short* Bbase = BT + (size_t)n0 * K;
  for (int kt = 0; kt < K; kt += 64) {
    __syncthreads();
#pragma unroll
    for (int q = 0; q < 4; ++q) {
      int chunk = w * 4 + q;
      int row = chunk * 8 + lrow8;
      __builtin_amdgcn_global_load_lds(
          (const __attribute__((address_space(1))) void*)(Abase + (size_t)row * K + kt + scol),
          (__attribute__((address_space(3))) void*)(As + chunk * 512), 16, 0, 0);
      __builtin_amdgcn_global_load_lds(
          (const __attribute__((address_space(1))) void*)(Bbase + (size_t)row * K + kt + scol),
          (__attribute__((address_space(3))) void*)(Bs + chunk * 512), 16, 0, 0);
    }
    __syncthreads();
#pragma unroll
    for (int ks = 0; ks < 2; ++ks) {
      short8 a[4], bb[4];
#pragma unroll
      for (int mi = 0; mi < 4; ++mi)
        a[mi] = *(const short8*)&As[(wm * 64 + mi * 16 + lr) * 64 + ks * 32 + lg * 8];
#pragma unroll
      for (int ni = 0; ni < 4; ++ni)
        bb[ni] = *(const short8*)&Bs[(wn * 64 + ni * 16 + lr) * 64 + ks * 32 + lg * 8];
#pragma unroll
      for (int mi = 0; mi < 4; ++mi)
#pragma unroll
        for (int ni = 0; ni < 4; ++ni)
          acc[mi][ni] = mfma16(a[mi], bb[ni], acc[mi][ni]);
    }
  }
#pragma unroll
  for (int mi = 0; mi < 4; ++mi)
#pragma unroll
    for (int ni = 0; ni < 4; ++ni)
#pragma unroll
      for (int r = 0; r < 4; ++r) {
        int row = m0 + wm * 64 + mi * 16 + lg * 4 + r;
        int cc = n0 + wn * 64 + ni * 16 + lr;
        Cout[(size_t)row * N + cc] = acc[mi][ni][r];
      }
}

// ---------------- V transpose: Vp[b][n][c][d] -> VT[b][n][d][c] ----------------
__global__ void k_vt(const unsigned short* __restrict__ Vp, unsigned short* __restrict__ VT) {
  __shared__ unsigned short tile[64][72];
  int c0 = blockIdx.x * 64;
  int n = blockIdx.y, b = blockIdx.z;
  int t = threadIdx.x;
  const unsigned short* src = Vp + ((size_t)((b * 16 + n) * 2048 + c0)) * 64;
#pragma unroll
  for (int p = 0; p < 16; ++p) {
    int idx = p * 256 + t;
    int r = idx >> 6, d = idx & 63;
    tile[d][r] = src[(size_t)r * 64 + d];
  }
  __syncthreads();
#pragma unroll
  for (int p = 0; p < 16; ++p) {
    int idx = p * 256 + t;
    int d = idx >> 6, c = idx & 63;
    VT[(size_t)((b * 16 + n) * 64 + d) * 2048 + c0 + c] = tile[d][c];
  }
}

// ---------------- split-j flash attention: single-V-buffer, 4 blocks/CU ----------------
__device__ __forceinline__ void stage_k(const unsigned short* __restrict__ Kbase,
                                        unsigned short* ksBuf, int j0, int tid) {
#pragma unroll
  for (int q = 0; q < 2; ++q) {
    int chunk = q * 256 + tid;
    int row = chunk >> 3;
    int slot = chunk & 7;
    int ss = slot ^ (row & 7);
    __builtin_amdgcn_global_load_lds(
        (const __attribute__((address_space(1))) void*)(Kbase + (size_t)(j0 + row) * 64 + ss * 8),
        (__attribute__((address_space(3))) void*)(ksBuf + chunk * 8), 16, 0, 0);
  }
}
__device__ __forceinline__ void stage_v(const unsigned short* __restrict__ Vbase,
                                        unsigned short* vsBuf, int j0, int tid) {
#pragma unroll
  for (int q = 0; q < 2; ++q) {
    int chunk = q * 256 + tid;
    int row = chunk >> 3;       // d 0..63
    int slot = chunk & 7;
    int ss = slot ^ (row & 7);
    __builtin_amdgcn_global_load_lds(
        (const __attribute__((address_space(1))) void*)(Vbase + (size_t)row * 2048 + j0 + ss * 8),
        (__attribute__((address_space(3))) void*)(vsBuf + chunk * 8), 16, 0, 0);
  }
}

__global__ __launch_bounds__(256) void k_attn(const unsigned short* __restrict__ Qp,
                                              const unsigned short* __restrict__ Kp,
                                              const unsigned short* __restrict__ VT,
                                              const unsigned short* __restrict__ Rkp,
                                              const float* __restrict__ rwb,
                                              const float* __restrict__ rrb,
                                              unsigned short* __restrict__ po,
                                              float* __restrict__ psumG) {
  __shared__ __align__(16) unsigned short Ks[2][64 * 64];
  __shared__ __align__(16) unsigned short Vs[64 * 64];
  __shared__ unsigned short P[4][16][72];
  const int tid = threadIdx.x;
  const int w = tid >> 6, l = tid & 63;
  const int lg = l >> 4, lr = l & 15;
  const int L = blockIdx.x;
  const int bnlo = L & 7;
  const int rest = L >> 3;
  const int bnhi = rest / 48;
  const int inner = rest - bnhi * 48;
  const int xt = inner / 3;
  const int s  = inner - xt * 3;
  const int bn = bnhi * 8 + bnlo;
  const int i0 = xt * 64;
  const int n = bn & 15, b = bn >> 4;
  const int wrow = i0 + w * 16;

  const int ntile = xt + 17;
  const int t0 = (s * ntile) / 3;
  const int t1 = ((s + 1) * ntile) / 3;   // chunk length 5..11

  const unsigned short* Kbase = Kp + (size_t)bn * 2048 * 64;
  const unsigned short* Vbase = VT + (size_t)bn * 64 * 2048;
  const unsigned short* Rkbase = Rkp + (size_t)n * 2048 * 64;

  short8 aq0u, aq1u, aq0v, aq1v;
  {
    const unsigned short* qp = Qp + (size_t)(bn * 1024 + wrow + lr) * 64 + lg * 8;
    short8 q0 = *(const short8*)qp;
    short8 q1 = *(const short8*)(qp + 32);
    const float* up = rwb + n * 64 + lg * 8;
    const float* vp = rrb + n * 64 + lg * 8;
#pragma unroll
    for (int e = 0; e < 8; ++e) {
      float q0f = bf2f((unsigned short)q0[e]);
      float q1f = bf2f((unsigned short)q1[e]);
      aq0u[e] = (short)f2bf(q0f + up[e]);
      aq1u[e] = (short)f2bf(q1f + up[e + 32]);
      aq0v[e] = (short)f2bf(q0f + vp[e]);
      aq1v[e] = (short)f2bf(q1f + vp[e + 32]);
    }
  }
  float psum[4];
  f32x4 o[4];
#pragma unroll
  for (int r = 0; r < 4; ++r) psum[r] = 0.f;
#pragma unroll
  for (int df = 0; df < 4; ++df) o[df] = (f32x4){0.f, 0.f, 0.f, 0.f};

  // prologue FIFO order: K[t0](2), V[t0](2), K[t0+1](2)
  stage_k(Kbase, Ks[0], t0 * 64, tid);
  stage_v(Vbase, Vs, t0 * 64, tid);
  stage_k(Kbase, Ks[1], (t0 + 1) * 64, tid);

  const float EXPC = 0.18033688011112042f;

  for (int jt = t0; jt < t1; ++jt) {
    const int j0 = jt * 64;
    const int cur = (jt - t0) & 1;
    const bool more = (jt + 1 < t1);
    // top wait: K[jt] landed. Newer in flight: V[jt](2) + K[jt+1](2 if staged).
    if (more) { asm volatile("s_waitcnt vmcnt(4)" ::: "memory"); }
    else      { asm volatile("s_waitcnt vmcnt(2)" ::: "memory"); }
    __builtin_amdgcn_s_barrier();

    f32x4 sac[4];
#pragma unroll
    for (int jf = 0; jf < 4; ++jf) sac[jf] = (f32x4){0.f, 0.f, 0.f, 0.f};
#pragma unroll
    for (int jf = 0; jf < 4; ++jf) {
      int row = jf * 16 + lr;
      int rx = row & 7;
      short8 k0 = *(const short8*)&Ks[cur][row * 64 + ((lg ^ rx) * 8)];
      short8 k1 = *(const short8*)&Ks[cur][row * 64 + (((4 + lg) ^ rx) * 8)];
      sac[jf] = mfma16(aq0u, k0, sac[jf]);
      sac[jf] = mfma16(aq1u, k1, sac[jf]);
    }
    const int kbw = j0 + 1008 - i0 - w * 16;
    f32x4 gb[5];
#pragma unroll
    for (int jg = 0; jg < 5; ++jg) {
      int rowK = kbw + jg * 16 + lr;
      short8 b0 = {}, b1 = {};
      if (rowK < C_LEN) {
        const unsigned short* rp = Rkbase + (size_t)rowK * 64 + lg * 8;
        b0 = *(const short8*)rp;
        b1 = *(const short8*)(rp + 32);
      }
      f32x4 g = (f32x4){0.f, 0.f, 0.f, 0.f};
      g = mfma16(aq0v, b0, g);
      g = mfma16(aq1v, b1, g);
      gb[jg] = g;
    }
    const bool needMask = (j0 + 63 > i0 + w * 16 + MEM_LEN);
    float p[4][4];
#pragma unroll
    for (int r = 0; r < 4; ++r) {
      const int R = lg * 4 + r;
      const int delta = lr + 15 - R;
      const int src = (l & 48) | (delta & 15);
      float v0 = __shfl(gb[0][r], src);
      float v1 = __shfl(gb[1][r], src);
      float v2 = __shfl(gb[2][r], src);
      float v3 = __shfl(gb[3][r], src);
      float v4 = __shfl(gb[4][r], src);
      const bool hi = delta >= 16;
      float bd0 = hi ? v1 : v0;
      float bd1 = hi ? v2 : v1;
      float bd2 = hi ? v3 : v2;
      float bd3 = hi ? v4 : v3;
      float e0 = exp2f((sac[0][r] + bd0) * EXPC);
      float e1 = exp2f((sac[1][r] + bd1) * EXPC);
      float e2 = exp2f((sac[2][r] + bd2) * EXPC);
      float e3 = exp2f((sac[3][r] + bd3) * EXPC);
      if (needMask) {
        const int jlim = i0 + w * 16 + R + MEM_LEN;
        int j = j0 + lr;
        e0 = (j > jlim) ? 0.f : e0;  j += 16;
        e1 = (j > jlim) ? 0.f : e1;  j += 16;
        e2 = (j > jlim) ? 0.f : e2;  j += 16;
        e3 = (j > jlim) ? 0.f : e3;
      }
      p[0][r] = e0; p[1][r] = e1; p[2][r] = e2; p[3][r] = e3;
    }
#pragma unroll
    for (int jf = 0; jf < 4; ++jf)
#pragma unroll
      for (int r = 0; r < 4; ++r) psum[r] += p[jf][r];
#pragma unroll
    for (int r = 0; r < 4; ++r) {
      unsigned int a01 = cvtpk(p[0][r], p[1][r]);
      unsigned int a23 = cvtpk(p[2][r], p[3][r]);
      const int R = lg * 4 + r;
      P[w][R][lr]      = (unsigned short)a01;
      P[w][R][16 + lr] = (unsigned short)(a01 >> 16);
      P[w][R][32 + lr] = (unsigned short)a23;
      P[w][R][48 + lr] = (unsigned short)(a23 >> 16);
    }
    // pre-PV wait: V[jt] landed. Newer: K[jt+1] (2) if staged at end of jt-1.
    if (more) { asm volatile("s_waitcnt vmcnt(2)" ::: "memory"); }
    else      { asm volatile("s_waitcnt vmcnt(0)" ::: "memory"); }
    __builtin_amdgcn_s_barrier();   // cross-wave: all V loads landed
#pragma unroll
    for (int ks = 0; ks < 2; ++ks) {
      short8 ap = *(const short8*)&P[w][lr][ks * 32 + lg * 8];
#pragma unroll
      for (int df = 0; df < 4; ++df) {
        int row = df * 16 + lr;
        int rx = row & 7;
        short8 vv = *(const short8*)&Vs[row * 64 + (((ks * 4 + lg) ^ rx) * 8)];
        o[df] = mfma16(ap, vv, o[df]);
      }
    }
    __builtin_amdgcn_s_barrier();   // all waves done reading Vs/Ks[cur]
    if (jt + 1 < t1) stage_v(Vbase, Vs, (jt + 1) * 64, tid);       // V first (FIFO)
    if (jt + 2 < t1) stage_k(Kbase, Ks[cur], (jt + 2) * 64, tid);  // then K
  }
  const int pbase = (bn * 16 + xt) * 3 + s;
  unsigned short* poB = po + (size_t)pbase * 4096;
#pragma unroll
  for (int r = 0; r < 4; ++r) {
    float v = psum[r];
    v += __shfl_xor(v, 1);
    v += __shfl_xor(v, 2);
    v += __shfl_xor(v, 4);
    v += __shfl_xor(v, 8);
    if (lr == 0) psumG[pbase * 64 + w * 16 + lg * 4 + r] = v;
  }
#pragma unroll
  for (int df = 0; df < 4; ++df)
#pragma unroll
    for (int r = 0; r < 4; ++r)
      poB[(w * 16 + lg * 4 + r) * 64 + df * 16 + lr] = f2bf(o[df][r]);
}

// combine split partials, normalize, emit bf16 vec[t][b][n*64+d]
__global__ __launch_bounds__(256) void k_ared(const unsigned short* __restrict__ po,
                                              const float* __restrict__ psumG,
                                              unsigned short* __restrict__ vec) {
  const int idx = blockIdx.x;
  const int tid = threadIdx.x;
  const int bn = idx >> 4, xt = idx & 15;
  const int b = bn >> 4, n = bn & 15;
  __shared__ float rs[64];
  if (tid < 64) {
    const float* q = psumG + idx * 192;
    rs[tid] = q[tid] + q[tid + 64] + q[tid + 128];
  }
  __syncthreads();
  const ushort8v* p0 = (const ushort8v*)(po + (size_t)(idx * 3 + 0) * 4096);
  const ushort8v* p1 = (const ushort8v*)(po + (size_t)(idx * 3 + 1) * 4096);
  const ushort8v* p2 = (const ushort8v*)(po + (size_t)(idx * 3 + 2) * 4096);
#pragma unroll
  for (int k = 0; k < 2; ++k) {
    int e = tid + k * 256;
    int row = e >> 3, d8 = e & 7;
    ushort8v a = p0[e], bb = p1[e], c = p2[e];
    float inv = 1.f / rs[row];
    int t = xt * 64 + row;
    ushort8v ov;
#pragma unroll
    for (int q = 0; q < 8; ++q)
      ov[q] = f2bf((bf2f(a[q]) + bf2f(bb[q]) + bf2f(c[q])) * inv);
    *(ushort8v*)&vec[(size_t)(t * 4 + b) * 1024 + n * 64 + d8 * 8] = ov;
  }
}

// ---------------- residual + layernorm ----------------
__global__ __launch_bounds__(256) void k_ln(const float* __restrict__ xg, const float* __restrict__ h,
                                            const float* __restrict__ gamma, const float* __restrict__ beta,
                                            float* __restrict__ out) {
  const int row = blockIdx.x;
  const int t = threadIdx.x;
  __shared__ float red1[4], red2[4];
  float4v xv = ((const float4v*)(xg + (size_t)row * 1024))[t];
  float4v hv = ((const float4v*)(h + (size_t)row * 1024))[t];
  float x0 = xv.x + hv.x, x1 = xv.y + hv.y, x2 = xv.z + hv.z, x3 = xv.w + hv.w;
  float s = x0 + x1 + x2 + x3;
#pragma unroll
  for (int off = 1; off < 64; off <<= 1) s += __shfl_xor(s, off);
  if ((t & 63) == 0) red1[t >> 6] = s;
  __syncthreads();
  float mean = (red1[0] + red1[1] + red1[2] + red1[3]) * (1.f / 1024.f);
  float d0 = x0 - mean, d1 = x1 - mean, d2 = x2 - mean, d3 = x3 - mean;
  float q = d0 * d0 + d1 * d1 + d2 * d2 + d3 * d3;
#pragma unroll
  for (int off = 1; off < 64; off <<= 1) q += __shfl_xor(q, off);
  if ((t & 63) == 0) red2[t >> 6] = q;
  __syncthreads();
  float var = (red2[0] + red2[1] + red2[2] + red2[3]) * (1.f / 1024.f);
  float rs = rsqrtf(var + 1e-5f);
  float4v gv = ((const float4v*)gamma)[t];
  float4v bv = ((const float4v*)beta)[t];
  float4v ov;
  ov.x = d0 * rs * gv.x + bv.x;
  ov.y = d1 * rs * gv.y + bv.y;
  ov.z = d2 * rs * gv.z + bv.z;
  ov.w = d3 * rs * gv.w + bv.w;
  ((float4v*)(out + (size_t)row * 1024))[t] = ov;
}

extern "C" void kernel_launch(void* const* d_in, const int* in_sizes, int n_in,
                              void* d_out, int out_size, void* d_ws, size_t ws_size,
                              hipStream_t stream) {
  (void)in_sizes; (void)n_in; (void)out_size; (void)ws_size;
  const float* h    = (const float*)d_in[0];
  const float* m    = (const float*)d_in[1];
  const float* r    = (const float*)d_in[2];
  const float* Wqkv = (const float*)d_in[4];
  const float* Wr   = (const float*)d_in[5];
  const float* Wo   = (const float*)d_in[6];
  const float* rwb  = (const float*)d_in[7];
  const float* rrb  = (const float*)d_in[8];
  const float* gam  = (const float*)d_in[9];
  const float* bet  = (const float*)d_in[10];
  float* out = (float*)d_out;

  char* ws = (char*)d_ws;
  unsigned short* catB   = (unsigned short*)(ws + 0);          // 16 MB
  unsigned short* WqkvT  = (unsigned short*)(ws + 16777216);   // 6 MB
  unsigned short* WrT    = (unsigned short*)(ws + 23068672);   // 2 MB
  unsigned short* WoT    = (unsigned short*)(ws + 25165824);   // 2 MB
  unsigned short* Vp     = (unsigned short*)(ws + 27262976);   // 16 MB
  unsigned short* po     = (unsigned short*)(ws + 44040192);   // 24 MB bf16 partials
  unsigned short* VT     = (unsigned short*)(ws + 81788928);   // 16 MB
  unsigned short* vec    = (unsigned short*)(ws + 99221504);   // 8 MB
  float* xbuf            = (float*)(ws + 107610112);           // 16 MB
  unsigned short* rB     = (unsigned short*)(ws + 124387328);  // 4 MB (reused as psumG)
  unsigned short* Kp     = (unsigned short*)(ws + 128581632);  // 16 MB
  unsigned short* Qp     = (unsigned short*)(ws + 145358848);  // 8 MB
  unsigned short* Rkp    = (unsigned short*)(ws + 153747456);  // 4 MB
  float* psumG = (float*)(ws + 124387328);                     // over dead rB

  hipLaunchKernelGGL(k_convert_all, dim3(10240), dim3(256), 0, stream, m, h, r, catB, rB);
  hipLaunchKernelGGL(k_transpose_w, dim3(96, 32, 3), dim3(256), 0, stream,
                     Wqkv, Wr, Wo, WqkvT, WrT, WoT);
  hipLaunchKernelGGL(k_gemm_qkv, dim3(1408), dim3(256), 0, stream,
                     catB, rB, WqkvT, WrT, Kp, Vp, Qp, Rkp);
  hipLaunchKernelGGL(k_vt, dim3(32, 16, 4), dim3(256), 0, stream, Vp, VT);
  hipLaunchKernelGGL(k_attn, dim3(3072), dim3(256), 0, stream, Qp, Kp, VT, Rkp, rwb, rrb, po, psumG);
  hipLaunchKernelGGL(k_ared, dim3(1024), dim3(256), 0, stream, po, psumG, vec);
  hipLaunchKernelGGL(k_gemm_o, dim3(8, 32), dim3(256), 0, stream, vec, WoT, xbuf, 4096, 1024, 1024);
  hipLaunchKernelGGL(k_ln, dim3(4096), dim3(256), 0, stream, xbuf, h, gam, bet, out);
}

// Round 17
// 307.375 us; speedup vs baseline: 1.1418x; 1.0160x over previous
//
#include <hip/hip_runtime.h>
#include <stdint.h>

#define T_LEN 1024
#define MEM_LEN 1024
#define C_LEN 2048
#define B_SZ 4
#define DM_ 1024
#define NH 16
#define HD 64

typedef __attribute__((ext_vector_type(8))) short short8;
typedef __attribute__((ext_vector_type(4))) float f32x4;
typedef __attribute__((ext_vector_type(4))) unsigned short ushort4v;
typedef __attribute__((ext_vector_type(8))) unsigned short ushort8v;
typedef __attribute__((ext_vector_type(4))) float float4v;

__device__ __forceinline__ unsigned short f2bf(float f) {
  union { float f; unsigned int u; } v; v.f = f;
  unsigned int r = v.u + 0x7fffu + ((v.u >> 16) & 1u);
  return (unsigned short)(r >> 16);
}
__device__ __forceinline__ float bf2f(unsigned short b) {
  union { unsigned int u; float f; } v; v.u = ((unsigned int)b) << 16;
  return v.f;
}
__device__ __forceinline__ unsigned int cvtpk(float lo, float hi) {
  unsigned int r;
  asm("v_cvt_pk_bf16_f32 %0, %1, %2" : "=v"(r) : "v"(lo), "v"(hi));
  return r;
}
__device__ __forceinline__ f32x4 mfma16(short8 a, short8 b, f32x4 c) {
  return __builtin_amdgcn_mfma_f32_16x16x32_bf16(a, b, c, 0, 0, 0);
}

// ---------------- fused converts: cat=[m;h] -> catB, r -> rB ----------------
__global__ void k_convert_all(const float* __restrict__ m, const float* __restrict__ h,
                              const float* __restrict__ r,
                              unsigned short* __restrict__ catB,
                              unsigned short* __restrict__ rB) {
  int idx = blockIdx.x * 256 + threadIdx.x;
  const int MQ = (MEM_LEN * B_SZ * DM_) / 4;
  const int CQ = 2 * MQ;
  float4v v;
  unsigned short* dst;
  int di;
  if (idx < MQ)      { v = ((const float4v*)m)[idx];       dst = catB; di = idx; }
  else if (idx < CQ) { v = ((const float4v*)h)[idx - MQ];  dst = catB; di = idx; }
  else               { v = ((const float4v*)r)[idx - CQ];  dst = rB;   di = idx - CQ; }
  ushort4v o;
  o.x = f2bf(v.x); o.y = f2bf(v.y); o.z = f2bf(v.z); o.w = f2bf(v.w);
  ((ushort4v*)dst)[di] = o;
}

// fused transpose of the three weights
__global__ void k_transpose_w(const float* __restrict__ Wqkv, const float* __restrict__ Wr,
                              const float* __restrict__ Wo,
                              unsigned short* __restrict__ WqkvT, unsigned short* __restrict__ WrT,
                              unsigned short* __restrict__ WoT) {
  __shared__ float tile[32][33];
  const int z = blockIdx.z;
  const int Ccols = (z == 0) ? 3072 : 1024;
  if (blockIdx.x * 32 >= Ccols) return;
  const float* in = (z == 0) ? Wqkv : (z == 1) ? Wr : Wo;
  unsigned short* out = (z == 0) ? WqkvT : (z == 1) ? WrT : WoT;
  int c0 = blockIdx.x * 32, r0 = blockIdx.y * 32;
  int tx = threadIdx.x & 31, ty = threadIdx.x >> 5;
#pragma unroll
  for (int p = 0; p < 4; ++p)
    tile[ty + 8 * p][tx] = in[(size_t)(r0 + ty + 8 * p) * Ccols + c0 + tx];
  __syncthreads();
#pragma unroll
  for (int p = 0; p < 4; ++p)
    out[(size_t)(c0 + ty + 8 * p) * 1024 + r0 + tx] = f2bf(tile[tx][ty + 8 * p]);
}

// ---------------- fused QKV+Rk GEMM (1408 blocks), direct-layout epilogues, XCD swizzle ----
__global__ __launch_bounds__(256) void k_gemm_qkv(const unsigned short* __restrict__ catB,
                                                  const unsigned short* __restrict__ rB,
                                                  const unsigned short* __restrict__ WqkvT,
                                                  const unsigned short* __restrict__ WrT,
                                                  unsigned short* __restrict__ Kp,
                                                  unsigned short* __restrict__ Vp,
                                                  unsigned short* __restrict__ Qp,
                                                  unsigned short* __restrict__ Rkp) {
  __shared__ unsigned short As[128 * 64];
  __shared__ unsigned short Bs[128 * 64];
  const int tid = threadIdx.x;
  const int w = tid >> 6, l = tid & 63;
  const int wm = w >> 1, wn = w & 1;
  const int lg = l >> 4, lr = l & 15;
  const int bid = blockIdx.x;
  int mode, lpid, gx;
  const unsigned short *A, *BT;
  if (bid < 1024)      { mode = 2; lpid = bid;        gx = 16; A = catB;                        BT = WqkvT + (size_t)1024 * 1024; }
  else if (bid < 1280) { mode = 3; lpid = bid - 1024; gx = 8;  A = catB + (size_t)4096 * 1024;  BT = WqkvT; }
  else                 { mode = 4; lpid = bid - 1280; gx = 8;  A = rB;                          BT = WrT; }
  const int K = 1024;
  const int xcd = lpid & 7;
  const int idx = lpid >> 3;
  const int cb = idx % gx;
  const int rb = (idx / gx) * 8 + xcd;
  const int m0 = rb * 128, n0 = cb * 128;
  f32x4 acc[4][4] = {};
  const int lrow8 = l >> 3;
  const int scol = (l & 7) * 8;
  const unsigned short* Abase = A + (size_t)m0 * K;
  const unsigned short* Bbase = BT + (size_t)n0 * K;
  for (int kt = 0; kt < K; kt += 64) {
    __syncthreads();
#pragma unroll
    for (int q = 0; q < 4; ++q) {
      int chunk = w * 4 + q;
      int row = chunk * 8 + lrow8;
      __builtin_amdgcn_global_load_lds(
          (const __attribute__((address_space(1))) void*)(Abase + (size_t)row * K + kt + scol),
          (__attribute__((address_space(3))) void*)(As + chunk * 512), 16, 0, 0);
      __builtin_amdgcn_global_load_lds(
          (const __attribute__((address_space(1))) void*)(Bbase + (size_t)row * K + kt + scol),
          (__attribute__((address_space(3))) void*)(Bs + chunk * 512), 16, 0, 0);
    }
    __syncthreads();
#pragma unroll
    for (int ks = 0; ks < 2; ++ks) {
      short8 a[4], bb[4];
#pragma unroll
      for (int mi = 0; mi < 4; ++mi)
        a[mi] = *(const short8*)&As[(wm * 64 + mi * 16 + lr) * 64 + ks * 32 + lg * 8];
#pragma unroll
      for (int ni = 0; ni < 4; ++ni)
        bb[ni] = *(const short8*)&Bs[(wn * 64 + ni * 16 + lr) * 64 + ks * 32 + lg * 8];
#pragma unroll
      for (int mi = 0; mi < 4; ++mi)
#pragma unroll
        for (int ni = 0; ni < 4; ++ni)
          acc[mi][ni] = mfma16(a[mi], bb[ni], acc[mi][ni]);
    }
  }
#pragma unroll
  for (int mi = 0; mi < 4; ++mi)
#pragma unroll
    for (int ni = 0; ni < 4; ++ni)
#pragma unroll
      for (int r = 0; r < 4; ++r) {
        int row = m0 + wm * 64 + mi * 16 + lg * 4 + r;
        int cc = n0 + wn * 64 + ni * 16 + lr;
        float val = acc[mi][ni][r];
        if (mode == 2) {
          int nn = (cc & 1023) >> 6, d = cc & 63;
          int c = row >> 2, b = row & 3;
          size_t addr = ((size_t)((b * 16 + nn) * 2048 + c)) * 64 + d;
          unsigned short* dst = (cc < 1024) ? Kp : Vp;
          dst[addr] = f2bf(val);
        } else if (mode == 3) {
          int nn = cc >> 6, d = cc & 63;
          int t = row >> 2, b = row & 3;
          Qp[((size_t)((b * 16 + nn) * 1024 + t)) * 64 + d] = f2bf(val);
        } else {
          int nn = cc >> 6, d = cc & 63;
          Rkp[((size_t)(nn * 2048 + row)) * 64 + d] = f2bf(val);
        }
      }
}

// out-projection GEMM (f32 out), XCD swizzle
__global__ __launch_bounds__(256) void k_gemm_o(const unsigned short* __restrict__ A,
                                                const unsigned short* __restrict__ BT,
                                                float* __restrict__ Cout, int M, int N, int K) {
  __shared__ unsigned short As[128 * 64];
  __shared__ unsigned short Bs[128 * 64];
  const int tid = threadIdx.x;
  const int w = tid >> 6, l = tid & 63;
  const int wm = w >> 1, wn = w & 1;
  const int lg = l >> 4, lr = l & 15;
  const int gx = gridDim.x;
  const int pid = blockIdx.y * gx + blockIdx.x;
  const int xcd = pid & 7;
  const int idx = pid >> 3;
  const int cb = idx % gx;
  const int rb = (idx / gx) * 8 + xcd;
  const int m0 = rb * 128, n0 = cb * 128;
  f32x4 acc[4][4] = {};
  const int lrow8 = l >> 3;
  const int scol = (l & 7) * 8;
  const unsigned short* Abase = A + (size_t)m0 * K;
  const unsigned short* Bbase = BT + (size_t)n0 * K;
  for (int kt = 0; kt < K; kt += 64) {
    __syncthreads();
#pragma unroll
    for (int q = 0; q < 4; ++q) {
      int chunk = w * 4 + q;
      int row = chunk * 8 + lrow8;
      __builtin_amdgcn_global_load_lds(
          (const __attribute__((address_space(1))) void*)(Abase + (size_t)row * K + kt + scol),
          (__attribute__((address_space(3))) void*)(As + chunk * 512), 16, 0, 0);
      __builtin_amdgcn_global_load_lds(
          (const __attribute__((address_space(1))) void*)(Bbase + (size_t)row * K + kt + scol),
          (__attribute__((address_space(3))) void*)(Bs + chunk * 512), 16, 0, 0);
    }
    __syncthreads();
#pragma unroll
    for (int ks = 0; ks < 2; ++ks) {
      short8 a[4], bb[4];
#pragma unroll
      for (int mi = 0; mi < 4; ++mi)
        a[mi] = *(const short8*)&As[(wm * 64 + mi * 16 + lr) * 64 + ks * 32 + lg * 8];
#pragma unroll
      for (int ni = 0; ni < 4; ++ni)
        bb[ni] = *(const short8*)&Bs[(wn * 64 + ni * 16 + lr) * 64 + ks * 32 + lg * 8];
#pragma unroll
      for (int mi = 0; mi < 4; ++mi)
#pragma unroll
        for (int ni = 0; ni < 4; ++ni)
          acc[mi][ni] = mfma16(a[mi], bb[ni], acc[mi][ni]);
    }
  }
#pragma unroll
  for (int mi = 0; mi < 4; ++mi)
#pragma unroll
    for (int ni = 0; ni < 4; ++ni)
#pragma unroll
      for (int r = 0; r < 4; ++r) {
        int row = m0 + wm * 64 + mi * 16 + lg * 4 + r;
        int cc = n0 + wn * 64 + ni * 16 + lr;
        Cout[(size_t)row * N + cc] = acc[mi][ni][r];
      }
}

// ---------------- V transpose: Vp[b][n][c][d] -> VT[b][n][d][c] ----------------
__global__ void k_vt(const unsigned short* __restrict__ Vp, unsigned short* __restrict__ VT) {
  __shared__ unsigned short tile[64][72];
  int c0 = blockIdx.x * 64;
  int n = blockIdx.y, b = blockIdx.z;
  int t = threadIdx.x;
  const unsigned short* src = Vp + ((size_t)((b * 16 + n) * 2048 + c0)) * 64;
#pragma unroll
  for (int p = 0; p < 16; ++p) {
    int idx = p * 256 + t;
    int r = idx >> 6, d = idx & 63;
    tile[d][r] = src[(size_t)r * 64 + d];
  }
  __syncthreads();
#pragma unroll
  for (int p = 0; p < 16; ++p) {
    int idx = p * 256 + t;
    int d = idx >> 6, c = idx & 63;
    VT[(size_t)((b * 16 + n) * 64 + d) * 2048 + c0 + c] = tile[d][c];
  }
}

// ---------------- split-j flash attention (R15 best: dbuf K+V, 2 barriers, bias-folded Q) --
__device__ __forceinline__ void stage_tile(const unsigned short* __restrict__ Kbase,
                                           const unsigned short* __restrict__ Vbase,
                                           unsigned short* ksBuf, unsigned short* vsBuf,
                                           int j0, int tid) {
#pragma unroll
  for (int q = 0; q < 2; ++q) {
    int chunk = q * 256 + tid;   // 0..511
    int row = chunk >> 3;        // 0..63
    int slot = chunk & 7;
    int ss = slot ^ (row & 7);   // source pre-swizzle (rule #21)
    __builtin_amdgcn_global_load_lds(
        (const __attribute__((address_space(1))) void*)(Kbase + (size_t)(j0 + row) * 64 + ss * 8),
        (__attribute__((address_space(3))) void*)(ksBuf + chunk * 8), 16, 0, 0);
    __builtin_amdgcn_global_load_lds(
        (const __attribute__((address_space(1))) void*)(Vbase + (size_t)row * 2048 + j0 + ss * 8),
        (__attribute__((address_space(3))) void*)(vsBuf + chunk * 8), 16, 0, 0);
  }
}

__global__ __launch_bounds__(256) void k_attn(const unsigned short* __restrict__ Qp,
                                              const unsigned short* __restrict__ Kp,
                                              const unsigned short* __restrict__ VT,
                                              const unsigned short* __restrict__ Rkp,
                                              const float* __restrict__ rwb,
                                              const float* __restrict__ rrb,
                                              unsigned short* __restrict__ po,
                                              float* __restrict__ psumG) {
  __shared__ __align__(16) unsigned short Ks[2][64 * 64];
  __shared__ __align__(16) unsigned short Vs[2][64 * 64];
  __shared__ unsigned short P[4][16][72];
  const int tid = threadIdx.x;
  const int w = tid >> 6, l = tid & 63;
  const int lg = l >> 4, lr = l & 15;
  const int L = blockIdx.x;
  const int bnlo = L & 7;
  const int rest = L >> 3;
  const int bnhi = rest / 48;
  const int inner = rest - bnhi * 48;
  const int xt = inner / 3;
  const int s  = inner - xt * 3;
  const int bn = bnhi * 8 + bnlo;
  const int i0 = xt * 64;
  const int n = bn & 15, b = bn >> 4;
  const int wrow = i0 + w * 16;

  const int ntile = xt + 17;
  const int t0 = (s * ntile) / 3;
  const int t1 = ((s + 1) * ntile) / 3;

  const unsigned short* Kbase = Kp + (size_t)bn * 2048 * 64;
  const unsigned short* Vbase = VT + (size_t)bn * 64 * 2048;
  const unsigned short* Rkbase = Rkp + (size_t)n * 2048 * 64;

  short8 aq0u, aq1u, aq0v, aq1v;
  {
    const unsigned short* qp = Qp + (size_t)(bn * 1024 + wrow + lr) * 64 + lg * 8;
    short8 q0 = *(const short8*)qp;
    short8 q1 = *(const short8*)(qp + 32);
    const float* up = rwb + n * 64 + lg * 8;
    const float* vp = rrb + n * 64 + lg * 8;
#pragma unroll
    for (int e = 0; e < 8; ++e) {
      float q0f = bf2f((unsigned short)q0[e]);
      float q1f = bf2f((unsigned short)q1[e]);
      aq0u[e] = (short)f2bf(q0f + up[e]);
      aq1u[e] = (short)f2bf(q1f + up[e + 32]);
      aq0v[e] = (short)f2bf(q0f + vp[e]);
      aq1v[e] = (short)f2bf(q1f + vp[e + 32]);
    }
  }
  float psum[4];
  f32x4 o[4];
#pragma unroll
  for (int r = 0; r < 4; ++r) psum[r] = 0.f;
#pragma unroll
  for (int df = 0; df < 4; ++df) o[df] = (f32x4){0.f, 0.f, 0.f, 0.f};

  stage_tile(Kbase, Vbase, Ks[0], Vs[0], t0 * 64, tid);
  stage_tile(Kbase, Vbase, Ks[1], Vs[1], (t0 + 1) * 64, tid);

  const float EXPC = 0.18033688011112042f;

  for (int jt = t0; jt < t1; ++jt) {
    const int j0 = jt * 64;
    const int cur = (jt - t0) & 1;
    if (jt + 1 < t1) { asm volatile("s_waitcnt vmcnt(4)" ::: "memory"); }
    else             { asm volatile("s_waitcnt vmcnt(0)" ::: "memory"); }
    __builtin_amdgcn_s_barrier();

    f32x4 sac[4];
#pragma unroll
    for (int jf = 0; jf < 4; ++jf) sac[jf] = (f32x4){0.f, 0.f, 0.f, 0.f};
    __builtin_amdgcn_s_setprio(1);
#pragma unroll
    for (int jf = 0; jf < 4; ++jf) {
      int row = jf * 16 + lr;
      int rx = row & 7;
      short8 k0 = *(const short8*)&Ks[cur][row * 64 + ((lg ^ rx) * 8)];
      short8 k1 = *(const short8*)&Ks[cur][row * 64 + (((4 + lg) ^ rx) * 8)];
      sac[jf] = mfma16(aq0u, k0, sac[jf]);
      sac[jf] = mfma16(aq1u, k1, sac[jf]);
    }
    __builtin_amdgcn_s_setprio(0);
    const int kbw = j0 + 1008 - i0 - w * 16;
    f32x4 gb[5];
#pragma unroll
    for (int jg = 0; jg < 5; ++jg) {
      int rowK = kbw + jg * 16 + lr;
      short8 b0 = {}, b1 = {};
      if (rowK < C_LEN) {
        const unsigned short* rp = Rkbase + (size_t)rowK * 64 + lg * 8;
        b0 = *(const short8*)rp;
        b1 = *(const short8*)(rp + 32);
      }
      f32x4 g = (f32x4){0.f, 0.f, 0.f, 0.f};
      g = mfma16(aq0v, b0, g);
      g = mfma16(aq1v, b1, g);
      gb[jg] = g;
    }
    const bool needMask = (j0 + 63 > i0 + w * 16 + MEM_LEN);
    float p[4][4];
#pragma unroll
    for (int r = 0; r < 4; ++r) {
      const int R = lg * 4 + r;
      const int delta = lr + 15 - R;
      const int src = (l & 48) | (delta & 15);
      float v0 = __shfl(gb[0][r], src);
      float v1 = __shfl(gb[1][r], src);
      float v2 = __shfl(gb[2][r], src);
      float v3 = __shfl(gb[3][r], src);
      float v4 = __shfl(gb[4][r], src);
      const bool hi = delta >= 16;
      float bd0 = hi ? v1 : v0;
      float bd1 = hi ? v2 : v1;
      float bd2 = hi ? v3 : v2;
      float bd3 = hi ? v4 : v3;
      float e0 = exp2f((sac[0][r] + bd0) * EXPC);
      float e1 = exp2f((sac[1][r] + bd1) * EXPC);
      float e2 = exp2f((sac[2][r] + bd2) * EXPC);
      float e3 = exp2f((sac[3][r] + bd3) * EXPC);
      if (needMask) {
        const int jlim = i0 + w * 16 + R + MEM_LEN;
        int j = j0 + lr;
        e0 = (j > jlim) ? 0.f : e0;  j += 16;
        e1 = (j > jlim) ? 0.f : e1;  j += 16;
        e2 = (j > jlim) ? 0.f : e2;  j += 16;
        e3 = (j > jlim) ? 0.f : e3;
      }
      p[0][r] = e0; p[1][r] = e1; p[2][r] = e2; p[3][r] = e3;
    }
#pragma unroll
    for (int jf = 0; jf < 4; ++jf)
#pragma unroll
      for (int r = 0; r < 4; ++r) psum[r] += p[jf][r];
#pragma unroll
    for (int r = 0; r < 4; ++r) {
      unsigned int a01 = cvtpk(p[0][r], p[1][r]);
      unsigned int a23 = cvtpk(p[2][r], p[3][r]);
      const int R = lg * 4 + r;
      P[w][R][lr]      = (unsigned short)a01;
      P[w][R][16 + lr] = (unsigned short)(a01 >> 16);
      P[w][R][32 + lr] = (unsigned short)a23;
      P[w][R][48 + lr] = (unsigned short)(a23 >> 16);
    }
    __builtin_amdgcn_s_setprio(1);
#pragma unroll
    for (int ks = 0; ks < 2; ++ks) {
      short8 ap = *(const short8*)&P[w][lr][ks * 32 + lg * 8];
#pragma unroll
      for (int df = 0; df < 4; ++df) {
        int row = df * 16 + lr;
        int rx = row & 7;
        short8 vv = *(const short8*)&Vs[cur][row * 64 + (((ks * 4 + lg) ^ rx) * 8)];
        o[df] = mfma16(ap, vv, o[df]);
      }
    }
    __builtin_amdgcn_s_setprio(0);
    __builtin_amdgcn_s_barrier();
    if (jt + 2 < t1)
      stage_tile(Kbase, Vbase, Ks[cur], Vs[cur], (jt + 2) * 64, tid);
  }
  const int pbase = (bn * 16 + xt) * 3 + s;
  unsigned short* poB = po + (size_t)pbase * 4096;
#pragma unroll
  for (int r = 0; r < 4; ++r) {
    float v = psum[r];
    v += __shfl_xor(v, 1);
    v += __shfl_xor(v, 2);
    v += __shfl_xor(v, 4);
    v += __shfl_xor(v, 8);
    if (lr == 0) psumG[pbase * 64 + w * 16 + lg * 4 + r] = v;
  }
#pragma unroll
  for (int df = 0; df < 4; ++df)
#pragma unroll
    for (int r = 0; r < 4; ++r)
      poB[(w * 16 + lg * 4 + r) * 64 + df * 16 + lr] = f2bf(o[df][r]);
}

// combine split partials, normalize, emit bf16 vec[t][b][n*64+d]
__global__ __launch_bounds__(256) void k_ared(const unsigned short* __restrict__ po,
                                              const float* __restrict__ psumG,
                                              unsigned short* __restrict__ vec) {
  const int idx = blockIdx.x;
  const int tid = threadIdx.x;
  const int bn = idx >> 4, xt = idx & 15;
  const int b = bn >> 4, n = bn & 15;
  __shared__ float rs[64];
  if (tid < 64) {
    const float* q = psumG + idx * 192;
    rs[tid] = q[tid] + q[tid + 64] + q[tid + 128];
  }
  __syncthreads();
  const ushort8v* p0 = (const ushort8v*)(po + (size_t)(idx * 3 + 0) * 4096);
  const ushort8v* p1 = (const ushort8v*)(po + (size_t)(idx * 3 + 1) * 4096);
  const ushort8v* p2 = (const ushort8v*)(po + (size_t)(idx * 3 + 2) * 4096);
#pragma unroll
  for (int k = 0; k < 2; ++k) {
    int e = tid + k * 256;
    int row = e >> 3, d8 = e & 7;
    ushort8v a = p0[e], bb = p1[e], c = p2[e];
    float inv = 1.f / rs[row];
    int t = xt * 64 + row;
    ushort8v ov;
#pragma unroll
    for (int q = 0; q < 8; ++q)
      ov[q] = f2bf((bf2f(a[q]) + bf2f(bb[q]) + bf2f(c[q])) * inv);
    *(ushort8v*)&vec[(size_t)(t * 4 + b) * 1024 + n * 64 + d8 * 8] = ov;
  }
}

// ---------------- residual + layernorm ----------------
__global__ __launch_bounds__(256) void k_ln(const float* __restrict__ xg, const float* __restrict__ h,
                                            const float* __restrict__ gamma, const float* __restrict__ beta,
                                            float* __restrict__ out) {
  const int row = blockIdx.x;
  const int t = threadIdx.x;
  __shared__ float red1[4], red2[4];
  float4v xv = ((const float4v*)(xg + (size_t)row * 1024))[t];
  float4v hv = ((const float4v*)(h + (size_t)row * 1024))[t];
  float x0 = xv.x + hv.x, x1 = xv.y + hv.y, x2 = xv.z + hv.z, x3 = xv.w + hv.w;
  float s = x0 + x1 + x2 + x3;
#pragma unroll
  for (int off = 1; off < 64; off <<= 1) s += __shfl_xor(s, off);
  if ((t & 63) == 0) red1[t >> 6] = s;
  __syncthreads();
  float mean = (red1[0] + red1[1] + red1[2] + red1[3]) * (1.f / 1024.f);
  float d0 = x0 - mean, d1 = x1 - mean, d2 = x2 - mean, d3 = x3 - mean;
  float q = d0 * d0 + d1 * d1 + d2 * d2 + d3 * d3;
#pragma unroll
  for (int off = 1; off < 64; off <<= 1) q += __shfl_xor(q, off);
  if ((t & 63) == 0) red2[t >> 6] = q;
  __syncthreads();
  float var = (red2[0] + red2[1] + red2[2] + red2[3]) * (1.f / 1024.f);
  float rs = rsqrtf(var + 1e-5f);
  float4v gv = ((const float4v*)gamma)[t];
  float4v bv = ((const float4v*)beta)[t];
  float4v ov;
  ov.x = d0 * rs * gv.x + bv.x;
  ov.y = d1 * rs * gv.y + bv.y;
  ov.z = d2 * rs * gv.z + bv.z;
  ov.w = d3 * rs * gv.w + bv.w;
  ((float4v*)(out + (size_t)row * 1024))[t] = ov;
}

extern "C" void kernel_launch(void* const* d_in, const int* in_sizes, int n_in,
                              void* d_out, int out_size, void* d_ws, size_t ws_size,
                              hipStream_t stream) {
  (void)in_sizes; (void)n_in; (void)out_size; (void)ws_size;
  const float* h    = (const float*)d_in[0];
  const float* m    = (const float*)d_in[1];
  const float* r    = (const float*)d_in[2];
  const float* Wqkv = (const float*)d_in[4];
  const float* Wr   = (const float*)d_in[5];
  const float* Wo   = (const float*)d_in[6];
  const float* rwb  = (const float*)d_in[7];
  const float* rrb  = (const float*)d_in[8];
  const float* gam  = (const float*)d_in[9];
  const float* bet  = (const float*)d_in[10];
  float* out = (float*)d_out;

  char* ws = (char*)d_ws;
  unsigned short* catB   = (unsigned short*)(ws + 0);          // 16 MB
  unsigned short* WqkvT  = (unsigned short*)(ws + 16777216);   // 6 MB
  unsigned short* WrT    = (unsigned short*)(ws + 23068672);   // 2 MB
  unsigned short* WoT    = (unsigned short*)(ws + 25165824);   // 2 MB
  unsigned short* Vp     = (unsigned short*)(ws + 27262976);   // 16 MB
  unsigned short* po     = (unsigned short*)(ws + 44040192);   // 24 MB bf16 partials
  unsigned short* VT     = (unsigned short*)(ws + 81788928);   // 16 MB
  unsigned short* vec    = (unsigned short*)(ws + 99221504);   // 8 MB
  float* xbuf            = (float*)(ws + 107610112);           // 16 MB
  unsigned short* rB     = (unsigned short*)(ws + 124387328);  // 4 MB (reused as psumG)
  unsigned short* Kp     = (unsigned short*)(ws + 128581632);  // 16 MB
  unsigned short* Qp     = (unsigned short*)(ws + 145358848);  // 8 MB
  unsigned short* Rkp    = (unsigned short*)(ws + 153747456);  // 4 MB
  float* psumG = (float*)(ws + 124387328);                     // over dead rB

  hipLaunchKernelGGL(k_convert_all, dim3(10240), dim3(256), 0, stream, m, h, r, catB, rB);
  hipLaunchKernelGGL(k_transpose_w, dim3(96, 32, 3), dim3(256), 0, stream,
                     Wqkv, Wr, Wo, WqkvT, WrT, WoT);
  hipLaunchKernelGGL(k_gemm_qkv, dim3(1408), dim3(256), 0, stream,
                     catB, rB, WqkvT, WrT, Kp, Vp, Qp, Rkp);
  hipLaunchKernelGGL(k_vt, dim3(32, 16, 4), dim3(256), 0, stream, Vp, VT);
  hipLaunchKernelGGL(k_attn, dim3(3072), dim3(256), 0, stream, Qp, Kp, VT, Rkp, rwb, rrb, po, psumG);
  hipLaunchKernelGGL(k_ared, dim3(1024), dim3(256), 0, stream, po, psumG, vec);
  hipLaunchKernelGGL(k_gemm_o, dim3(8, 32), dim3(256), 0, stream, vec, WoT, xbuf, 4096, 1024, 1024);
  hipLaunchKernelGGL(k_ln, dim3(4096), dim3(256), 0, stream, xbuf, h, gam, bet, out);
}

// Round 18
// 305.308 us; speedup vs baseline: 1.1495x; 1.0068x over previous
//
#include <hip/hip_runtime.h>
#include <stdint.h>

#define T_LEN 1024
#define MEM_LEN 1024
#define C_LEN 2048
#define B_SZ 4
#define DM_ 1024
#define NH 16
#define HD 64

typedef __attribute__((ext_vector_type(8))) short short8;
typedef __attribute__((ext_vector_type(4))) float f32x4;
typedef __attribute__((ext_vector_type(4))) unsigned short ushort4v;
typedef __attribute__((ext_vector_type(8))) unsigned short ushort8v;
typedef __attribute__((ext_vector_type(4))) float float4v;

__device__ __forceinline__ unsigned short f2bf(float f) {
  union { float f; unsigned int u; } v; v.f = f;
  unsigned int r = v.u + 0x7fffu + ((v.u >> 16) & 1u);
  return (unsigned short)(r >> 16);
}
__device__ __forceinline__ float bf2f(unsigned short b) {
  union { unsigned int u; float f; } v; v.u = ((unsigned int)b) << 16;
  return v.f;
}
__device__ __forceinline__ unsigned int cvtpk(float lo, float hi) {
  unsigned int r;
  asm("v_cvt_pk_bf16_f32 %0, %1, %2" : "=v"(r) : "v"(lo), "v"(hi));
  return r;
}
__device__ __forceinline__ f32x4 mfma16(short8 a, short8 b, f32x4 c) {
  return __builtin_amdgcn_mfma_f32_16x16x32_bf16(a, b, c, 0, 0, 0);
}

// ---------------- fused converts: cat=[m;h] -> catB, r -> rB ----------------
__global__ void k_convert_all(const float* __restrict__ m, const float* __restrict__ h,
                              const float* __restrict__ r,
                              unsigned short* __restrict__ catB,
                              unsigned short* __restrict__ rB) {
  int idx = blockIdx.x * 256 + threadIdx.x;
  const int MQ = (MEM_LEN * B_SZ * DM_) / 4;
  const int CQ = 2 * MQ;
  float4v v;
  unsigned short* dst;
  int di;
  if (idx < MQ)      { v = ((const float4v*)m)[idx];       dst = catB; di = idx; }
  else if (idx < CQ) { v = ((const float4v*)h)[idx - MQ];  dst = catB; di = idx; }
  else               { v = ((const float4v*)r)[idx - CQ];  dst = rB;   di = idx - CQ; }
  ushort4v o;
  o.x = f2bf(v.x); o.y = f2bf(v.y); o.z = f2bf(v.z); o.w = f2bf(v.w);
  ((ushort4v*)dst)[di] = o;
}

// fused transpose of the three weights
__global__ void k_transpose_w(const float* __restrict__ Wqkv, const float* __restrict__ Wr,
                              const float* __restrict__ Wo,
                              unsigned short* __restrict__ WqkvT, unsigned short* __restrict__ WrT,
                              unsigned short* __restrict__ WoT) {
  __shared__ float tile[32][33];
  const int z = blockIdx.z;
  const int Ccols = (z == 0) ? 3072 : 1024;
  if (blockIdx.x * 32 >= Ccols) return;
  const float* in = (z == 0) ? Wqkv : (z == 1) ? Wr : Wo;
  unsigned short* out = (z == 0) ? WqkvT : (z == 1) ? WrT : WoT;
  int c0 = blockIdx.x * 32, r0 = blockIdx.y * 32;
  int tx = threadIdx.x & 31, ty = threadIdx.x >> 5;
#pragma unroll
  for (int p = 0; p < 4; ++p)
    tile[ty + 8 * p][tx] = in[(size_t)(r0 + ty + 8 * p) * Ccols + c0 + tx];
  __syncthreads();
#pragma unroll
  for (int p = 0; p < 4; ++p)
    out[(size_t)(c0 + ty + 8 * p) * 1024 + r0 + tx] = f2bf(tile[tx][ty + 8 * p]);
}

// ---------------- 8-phase 256x256 QKV+Rk GEMM (m201 template port) ----------------
// BM=BN=256, BK=64, 8 waves (2Mx4N), 128 KiB LDS as two 4-slot half-tile rings
// (slot=(2t+h)&3). Stream order per tile: (B0,B1,A0,A1); B consumed in phase 0
// so B-slots restage in phases 1-2, A-slots in phases 0/3. Counted vmcnt(6)
// once per K-tile (3 half-tiles x 2 loads in flight); barrier AFTER vmcnt
// (per-wave counters -> cross-wave landing needs the barrier). st_16x32
// swizzle: col ^= ((row>>2)&1)<<4, applied both-sides (rule #21).
__device__ __forceinline__ void stage_half_g(const unsigned short* __restrict__ src, int ldK,
                                             unsigned short* dst, int tid) {
#pragma unroll
  for (int q = 0; q < 2; ++q) {
    int idx = q * 512 + tid;            // 0..1023
    int row = idx >> 3;                 // 0..127
    int g = idx & 7;                    // colgroup of 8 elems
    int gs = g ^ (((row >> 2) & 1) << 1);  // source pre-swizzle
    __builtin_amdgcn_global_load_lds(
        (const __attribute__((address_space(1))) void*)(src + (size_t)row * ldK + gs * 8),
        (__attribute__((address_space(3))) void*)(dst + idx * 8), 16, 0, 0);
  }
}
__device__ __forceinline__ short8 frag_rd(const unsigned short* half, int row, int kg) {
  int g = kg ^ (((row >> 2) & 1) << 1);  // read-side swizzle (same involution)
  return *(const short8*)&half[row * 64 + g * 8];
}

__global__ __launch_bounds__(512, 2) void k_gemm_qkv8(const unsigned short* __restrict__ catB,
                                                      const unsigned short* __restrict__ rB,
                                                      const unsigned short* __restrict__ WqkvT,
                                                      const unsigned short* __restrict__ WrT,
                                                      unsigned short* __restrict__ Kp,
                                                      unsigned short* __restrict__ Vp,
                                                      unsigned short* __restrict__ Qp,
                                                      unsigned short* __restrict__ Rkp) {
  __shared__ unsigned short Ash[4][128 * 64];   // 64 KB (4 half-slots)
  __shared__ unsigned short Bsh[4][128 * 64];   // 64 KB
  const int tid = threadIdx.x;
  const int w = tid >> 6, l = tid & 63;
  const int wr = w >> 2, wc = w & 3;            // wave = (wr 0..1, wc 0..3)
  const int lg = l >> 4, lr = l & 15;
  const int bid = blockIdx.x;
  int mode, lpid, gx;
  const unsigned short *A, *BT;
  if (bid < 256)      { mode = 2; lpid = bid;       gx = 8; A = catB;                      BT = WqkvT + (size_t)1024 * 1024; }
  else if (bid < 320) { mode = 3; lpid = bid - 256; gx = 4; A = catB + (size_t)4096 * 1024; BT = WqkvT; }
  else                { mode = 4; lpid = bid - 320; gx = 4; A = rB;                        BT = WrT; }
  const int K = 1024, NT = 16;
  const int xcd = lpid & 7;
  const int idx = lpid >> 3;
  const int cb = idx % gx;
  const int rb = (idx / gx) * 8 + xcd;
  const int m0 = rb * 256, n0 = cb * 256;
  const unsigned short* Ab = A + (size_t)m0 * K;
  const unsigned short* Bb = BT + (size_t)n0 * K;

  f32x4 acc[8][4];
#pragma unroll
  for (int i = 0; i < 8; ++i)
#pragma unroll
    for (int j = 0; j < 4; ++j) acc[i][j] = (f32x4){0.f, 0.f, 0.f, 0.f};

  // prologue: tile0 (B0,B1,A0,A1) -> vmcnt(4) -> tile1 (B0,B1,A0) -> vmcnt(6)
  stage_half_g(Bb,                       K, Bsh[0], tid);
  stage_half_g(Bb + (size_t)128 * K,     K, Bsh[1], tid);
  stage_half_g(Ab,                       K, Ash[0], tid);
  stage_half_g(Ab + (size_t)128 * K,     K, Ash[1], tid);
  asm volatile("s_waitcnt vmcnt(4)" ::: "memory");
  stage_half_g(Bb + 64,                   K, Bsh[2], tid);
  stage_half_g(Bb + (size_t)128 * K + 64, K, Bsh[3], tid);
  stage_half_g(Ab + 64,                   K, Ash[2], tid);
  asm volatile("s_waitcnt vmcnt(6)" ::: "memory");   // tile0 fully landed
  __builtin_amdgcn_s_barrier();

  for (int t = 0; t < NT; ++t) {
    const unsigned short* Ah = Ash[(2 * t + wr) & 3];
    const unsigned short* Bh = Bsh[(2 * t + (wc >> 1)) & 3];
    const int brow = (wc & 1) * 64;
    short8 bf[4][2];
#pragma unroll
    for (int p = 0; p < 4; ++p) {
      if (p == 0) {
#pragma unroll
        for (int ni = 0; ni < 4; ++ni)
#pragma unroll
          for (int ks = 0; ks < 2; ++ks)
            bf[ni][ks] = frag_rd(Bh, brow + ni * 16 + lr, ks * 4 + lg);
      }
      short8 af[2][2];
#pragma unroll
      for (int j = 0; j < 2; ++j)
#pragma unroll
        for (int ks = 0; ks < 2; ++ks)
          af[j][ks] = frag_rd(Ah, (2 * p + j) * 16 + lr, ks * 4 + lg);
      // stage stream: p0: A1(t+1); p1: B0(t+2); p2: B1(t+2); p3: A0(t+2)
      if (p == 0)      { if (t + 1 < NT) stage_half_g(Ab + (size_t)128 * K + (t + 1) * 64, K, Ash[(2 * t + 3) & 3], tid); }
      else if (p == 1) { if (t + 2 < NT) stage_half_g(Bb + (t + 2) * 64,                   K, Bsh[(2 * t + 4) & 3], tid); }
      else if (p == 2) { if (t + 2 < NT) stage_half_g(Bb + (size_t)128 * K + (t + 2) * 64, K, Bsh[(2 * t + 5) & 3], tid); }
      else             { if (t + 2 < NT) stage_half_g(Ab + (t + 2) * 64,                   K, Ash[(2 * t + 4) & 3], tid); }
      __builtin_amdgcn_s_barrier();
      asm volatile("s_waitcnt lgkmcnt(0)" ::: "memory");
      __builtin_amdgcn_s_setprio(1);
#pragma unroll
      for (int j = 0; j < 2; ++j)
#pragma unroll
        for (int ni = 0; ni < 4; ++ni)
#pragma unroll
          for (int ks = 0; ks < 2; ++ks)
            acc[2 * p + j][ni] = mfma16(af[j][ks], bf[ni][ks], acc[2 * p + j][ni]);
      __builtin_amdgcn_s_setprio(0);
      if (p == 3) {
        if (t < NT - 2)       { asm volatile("s_waitcnt vmcnt(6)" ::: "memory"); }
        else if (t == NT - 2) { asm volatile("s_waitcnt vmcnt(0)" ::: "memory"); }
      }
      __builtin_amdgcn_s_barrier();   // after vmcnt: cross-wave landing guarantee
    }
  }
  // epilogue: direct-layout C writes
#pragma unroll
  for (int mi = 0; mi < 8; ++mi)
#pragma unroll
    for (int ni = 0; ni < 4; ++ni)
#pragma unroll
      for (int r = 0; r < 4; ++r) {
        int row = m0 + wr * 128 + mi * 16 + lg * 4 + r;
        int cc = n0 + wc * 64 + ni * 16 + lr;
        float val = acc[mi][ni][r];
        if (mode == 2) {
          int nn = (cc & 1023) >> 6, d = cc & 63;
          int c = row >> 2, b = row & 3;
          size_t addr = ((size_t)((b * 16 + nn) * 2048 + c)) * 64 + d;
          unsigned short* dst = (cc < 1024) ? Kp : Vp;
          dst[addr] = f2bf(val);
        } else if (mode == 3) {
          int nn = cc >> 6, d = cc & 63;
          int t2 = row >> 2, b = row & 3;
          Qp[((size_t)((b * 16 + nn) * 1024 + t2)) * 64 + d] = f2bf(val);
        } else {
          int nn = cc >> 6, d = cc & 63;
          Rkp[((size_t)(nn * 2048 + row)) * 64 + d] = f2bf(val);
        }
      }
}

// out-projection GEMM (f32 out), 128^2 structure, XCD swizzle
__global__ __launch_bounds__(256) void k_gemm_o(const unsigned short* __restrict__ A,
                                                const unsigned short* __restrict__ BT,
                                                float* __restrict__ Cout, int M, int N, int K) {
  __shared__ unsigned short As[128 * 64];
  __shared__ unsigned short Bs[128 * 64];
  const int tid = threadIdx.x;
  const int w = tid >> 6, l = tid & 63;
  const int wm = w >> 1, wn = w & 1;
  const int lg = l >> 4, lr = l & 15;
  const int gx = gridDim.x;
  const int pid = blockIdx.y * gx + blockIdx.x;
  const int xcd = pid & 7;
  const int idx = pid >> 3;
  const int cb = idx % gx;
  const int rb = (idx / gx) * 8 + xcd;
  const int m0 = rb * 128, n0 = cb * 128;
  f32x4 acc[4][4] = {};
  const int lrow8 = l >> 3;
  const int scol = (l & 7) * 8;
  const unsigned short* Abase = A + (size_t)m0 * K;
  const unsigned short* Bbase = BT + (size_t)n0 * K;
  for (int kt = 0; kt < K; kt += 64) {
    __syncthreads();
#pragma unroll
    for (int q = 0; q < 4; ++q) {
      int chunk = w * 4 + q;
      int row = chunk * 8 + lrow8;
      __builtin_amdgcn_global_load_lds(
          (const __attribute__((address_space(1))) void*)(Abase + (size_t)row * K + kt + scol),
          (__attribute__((address_space(3))) void*)(As + chunk * 512), 16, 0, 0);
      __builtin_amdgcn_global_load_lds(
          (const __attribute__((address_space(1))) void*)(Bbase + (size_t)row * K + kt + scol),
          (__attribute__((address_space(3))) void*)(Bs + chunk * 512), 16, 0, 0);
    }
    __syncthreads();
#pragma unroll
    for (int ks = 0; ks < 2; ++ks) {
      short8 a[4], bb[4];
#pragma unroll
      for (int mi = 0; mi < 4; ++mi)
        a[mi] = *(const short8*)&As[(wm * 64 + mi * 16 + lr) * 64 + ks * 32 + lg * 8];
#pragma unroll
      for (int ni = 0; ni < 4; ++ni)
        bb[ni] = *(const short8*)&Bs[(wn * 64 + ni * 16 + lr) * 64 + ks * 32 + lg * 8];
#pragma unroll
      for (int mi = 0; mi < 4; ++mi)
#pragma unroll
        for (int ni = 0; ni < 4; ++ni)
          acc[mi][ni] = mfma16(a[mi], bb[ni], acc[mi][ni]);
    }
  }
#pragma unroll
  for (int mi = 0; mi < 4; ++mi)
#pragma unroll
    for (int ni = 0; ni < 4; ++ni)
#pragma unroll
      for (int r = 0; r < 4; ++r) {
        int row = m0 + wm * 64 + mi * 16 + lg * 4 + r;
        int cc = n0 + wn * 64 + ni * 16 + lr;
        Cout[(size_t)row * N + cc] = acc[mi][ni][r];
      }
}

// ---------------- V transpose: Vp[b][n][c][d] -> VT[b][n][d][c] ----------------
__global__ void k_vt(const unsigned short* __restrict__ Vp, unsigned short* __restrict__ VT) {
  __shared__ unsigned short tile[64][72];
  int c0 = blockIdx.x * 64;
  int n = blockIdx.y, b = blockIdx.z;
  int t = threadIdx.x;
  const unsigned short* src = Vp + ((size_t)((b * 16 + n) * 2048 + c0)) * 64;
#pragma unroll
  for (int p = 0; p < 16; ++p) {
    int idx = p * 256 + t;
    int r = idx >> 6, d = idx & 63;
    tile[d][r] = src[(size_t)r * 64 + d];
  }
  __syncthreads();
#pragma unroll
  for (int p = 0; p < 16; ++p) {
    int idx = p * 256 + t;
    int d = idx >> 6, c = idx & 63;
    VT[(size_t)((b * 16 + n) * 64 + d) * 2048 + c0 + c] = tile[d][c];
  }
}

// ---------------- split-j flash attention (R15/R17 best) ----------------
__device__ __forceinline__ void stage_tile(const unsigned short* __restrict__ Kbase,
                                           const unsigned short* __restrict__ Vbase,
                                           unsigned short* ksBuf, unsigned short* vsBuf,
                                           int j0, int tid) {
#pragma unroll
  for (int q = 0; q < 2; ++q) {
    int chunk = q * 256 + tid;   // 0..511
    int row = chunk >> 3;        // 0..63
    int slot = chunk & 7;
    int ss = slot ^ (row & 7);   // source pre-swizzle (rule #21)
    __builtin_amdgcn_global_load_lds(
        (const __attribute__((address_space(1))) void*)(Kbase + (size_t)(j0 + row) * 64 + ss * 8),
        (__attribute__((address_space(3))) void*)(ksBuf + chunk * 8), 16, 0, 0);
    __builtin_amdgcn_global_load_lds(
        (const __attribute__((address_space(1))) void*)(Vbase + (size_t)row * 2048 + j0 + ss * 8),
        (__attribute__((address_space(3))) void*)(vsBuf + chunk * 8), 16, 0, 0);
  }
}

__global__ __launch_bounds__(256) void k_attn(const unsigned short* __restrict__ Qp,
                                              const unsigned short* __restrict__ Kp,
                                              const unsigned short* __restrict__ VT,
                                              const unsigned short* __restrict__ Rkp,
                                              const float* __restrict__ rwb,
                                              const float* __restrict__ rrb,
                                              unsigned short* __restrict__ po,
                                              float* __restrict__ psumG) {
  __shared__ __align__(16) unsigned short Ks[2][64 * 64];
  __shared__ __align__(16) unsigned short Vs[2][64 * 64];
  __shared__ unsigned short P[4][16][72];
  const int tid = threadIdx.x;
  const int w = tid >> 6, l = tid & 63;
  const int lg = l >> 4, lr = l & 15;
  const int L = blockIdx.x;
  const int bnlo = L & 7;
  const int rest = L >> 3;
  const int bnhi = rest / 48;
  const int inner = rest - bnhi * 48;
  const int xt = inner / 3;
  const int s  = inner - xt * 3;
  const int bn = bnhi * 8 + bnlo;
  const int i0 = xt * 64;
  const int n = bn & 15, b = bn >> 4;
  const int wrow = i0 + w * 16;

  const int ntile = xt + 17;
  const int t0 = (s * ntile) / 3;
  const int t1 = ((s + 1) * ntile) / 3;

  const unsigned short* Kbase = Kp + (size_t)bn * 2048 * 64;
  const unsigned short* Vbase = VT + (size_t)bn * 64 * 2048;
  const unsigned short* Rkbase = Rkp + (size_t)n * 2048 * 64;

  short8 aq0u, aq1u, aq0v, aq1v;
  {
    const unsigned short* qp = Qp + (size_t)(bn * 1024 + wrow + lr) * 64 + lg * 8;
    short8 q0 = *(const short8*)qp;
    short8 q1 = *(const short8*)(qp + 32);
    const float* up = rwb + n * 64 + lg * 8;
    const float* vp = rrb + n * 64 + lg * 8;
#pragma unroll
    for (int e = 0; e < 8; ++e) {
      float q0f = bf2f((unsigned short)q0[e]);
      float q1f = bf2f((unsigned short)q1[e]);
      aq0u[e] = (short)f2bf(q0f + up[e]);
      aq1u[e] = (short)f2bf(q1f + up[e + 32]);
      aq0v[e] = (short)f2bf(q0f + vp[e]);
      aq1v[e] = (short)f2bf(q1f + vp[e + 32]);
    }
  }
  float psum[4];
  f32x4 o[4];
#pragma unroll
  for (int r = 0; r < 4; ++r) psum[r] = 0.f;
#pragma unroll
  for (int df = 0; df < 4; ++df) o[df] = (f32x4){0.f, 0.f, 0.f, 0.f};

  stage_tile(Kbase, Vbase, Ks[0], Vs[0], t0 * 64, tid);
  stage_tile(Kbase, Vbase, Ks[1], Vs[1], (t0 + 1) * 64, tid);

  const float EXPC = 0.18033688011112042f;

  for (int jt = t0; jt < t1; ++jt) {
    const int j0 = jt * 64;
    const int cur = (jt - t0) & 1;
    if (jt + 1 < t1) { asm volatile("s_waitcnt vmcnt(4)" ::: "memory"); }
    else             { asm volatile("s_waitcnt vmcnt(0)" ::: "memory"); }
    __builtin_amdgcn_s_barrier();

    f32x4 sac[4];
#pragma unroll
    for (int jf = 0; jf < 4; ++jf) sac[jf] = (f32x4){0.f, 0.f, 0.f, 0.f};
    __builtin_amdgcn_s_setprio(1);
#pragma unroll
    for (int jf = 0; jf < 4; ++jf) {
      int row = jf * 16 + lr;
      int rx = row & 7;
      short8 k0 = *(const short8*)&Ks[cur][row * 64 + ((lg ^ rx) * 8)];
      short8 k1 = *(const short8*)&Ks[cur][row * 64 + (((4 + lg) ^ rx) * 8)];
      sac[jf] = mfma16(aq0u, k0, sac[jf]);
      sac[jf] = mfma16(aq1u, k1, sac[jf]);
    }
    __builtin_amdgcn_s_setprio(0);
    const int kbw = j0 + 1008 - i0 - w * 16;
    f32x4 gb[5];
#pragma unroll
    for (int jg = 0; jg < 5; ++jg) {
      int rowK = kbw + jg * 16 + lr;
      short8 b0 = {}, b1 = {};
      if (rowK < C_LEN) {
        const unsigned short* rp = Rkbase + (size_t)rowK * 64 + lg * 8;
        b0 = *(const short8*)rp;
        b1 = *(const short8*)(rp + 32);
      }
      f32x4 g = (f32x4){0.f, 0.f, 0.f, 0.f};
      g = mfma16(aq0v, b0, g);
      g = mfma16(aq1v, b1, g);
      gb[jg] = g;
    }
    const bool needMask = (j0 + 63 > i0 + w * 16 + MEM_LEN);
    float p[4][4];
#pragma unroll
    for (int r = 0; r < 4; ++r) {
      const int R = lg * 4 + r;
      const int delta = lr + 15 - R;
      const int src = (l & 48) | (delta & 15);
      float v0 = __shfl(gb[0][r], src);
      float v1 = __shfl(gb[1][r], src);
      float v2 = __shfl(gb[2][r], src);
      float v3 = __shfl(gb[3][r], src);
      float v4 = __shfl(gb[4][r], src);
      const bool hi = delta >= 16;
      float bd0 = hi ? v1 : v0;
      float bd1 = hi ? v2 : v1;
      float bd2 = hi ? v3 : v2;
      float bd3 = hi ? v4 : v3;
      float e0 = exp2f((sac[0][r] + bd0) * EXPC);
      float e1 = exp2f((sac[1][r] + bd1) * EXPC);
      float e2 = exp2f((sac[2][r] + bd2) * EXPC);
      float e3 = exp2f((sac[3][r] + bd3) * EXPC);
      if (needMask) {
        const int jlim = i0 + w * 16 + R + MEM_LEN;
        int j = j0 + lr;
        e0 = (j > jlim) ? 0.f : e0;  j += 16;
        e1 = (j > jlim) ? 0.f : e1;  j += 16;
        e2 = (j > jlim) ? 0.f : e2;  j += 16;
        e3 = (j > jlim) ? 0.f : e3;
      }
      p[0][r] = e0; p[1][r] = e1; p[2][r] = e2; p[3][r] = e3;
    }
#pragma unroll
    for (int jf = 0; jf < 4; ++jf)
#pragma unroll
      for (int r = 0; r < 4; ++r) psum[r] += p[jf][r];
#pragma unroll
    for (int r = 0; r < 4; ++r) {
      unsigned int a01 = cvtpk(p[0][r], p[1][r]);
      unsigned int a23 = cvtpk(p[2][r], p[3][r]);
      const int R = lg * 4 + r;
      P[w][R][lr]      = (unsigned short)a01;
      P[w][R][16 + lr] = (unsigned short)(a01 >> 16);
      P[w][R][32 + lr] = (unsigned short)a23;
      P[w][R][48 + lr] = (unsigned short)(a23 >> 16);
    }
    __builtin_amdgcn_s_setprio(1);
#pragma unroll
    for (int ks = 0; ks < 2; ++ks) {
      short8 ap = *(const short8*)&P[w][lr][ks * 32 + lg * 8];
#pragma unroll
      for (int df = 0; df < 4; ++df) {
        int row = df * 16 + lr;
        int rx = row & 7;
        short8 vv = *(const short8*)&Vs[cur][row * 64 + (((ks * 4 + lg) ^ rx) * 8)];
        o[df] = mfma16(ap, vv, o[df]);
      }
    }
    __builtin_amdgcn_s_setprio(0);
    __builtin_amdgcn_s_barrier();
    if (jt + 2 < t1)
      stage_tile(Kbase, Vbase, Ks[cur], Vs[cur], (jt + 2) * 64, tid);
  }
  const int pbase = (bn * 16 + xt) * 3 + s;
  unsigned short* poB = po + (size_t)pbase * 4096;
#pragma unroll
  for (int r = 0; r < 4; ++r) {
    float v = psum[r];
    v += __shfl_xor(v, 1);
    v += __shfl_xor(v, 2);
    v += __shfl_xor(v, 4);
    v += __shfl_xor(v, 8);
    if (lr == 0) psumG[pbase * 64 + w * 16 + lg * 4 + r] = v;
  }
#pragma unroll
  for (int df = 0; df < 4; ++df)
#pragma unroll
    for (int r = 0; r < 4; ++r)
      poB[(w * 16 + lg * 4 + r) * 64 + df * 16 + lr] = f2bf(o[df][r]);
}

// combine split partials, normalize, emit bf16 vec[t][b][n*64+d]
__global__ __launch_bounds__(256) void k_ared(const unsigned short* __restrict__ po,
                                              const float* __restrict__ psumG,
                                              unsigned short* __restrict__ vec) {
  const int idx = blockIdx.x;
  const int tid = threadIdx.x;
  const int bn = idx >> 4, xt = idx & 15;
  const int b = bn >> 4, n = bn & 15;
  __shared__ float rs[64];
  if (tid < 64) {
    const float* q = psumG + idx * 192;
    rs[tid] = q[tid] + q[tid + 64] + q[tid + 128];
  }
  __syncthreads();
  const ushort8v* p0 = (const ushort8v*)(po + (size_t)(idx * 3 + 0) * 4096);
  const ushort8v* p1 = (const ushort8v*)(po + (size_t)(idx * 3 + 1) * 4096);
  const ushort8v* p2 = (const ushort8v*)(po + (size_t)(idx * 3 + 2) * 4096);
#pragma unroll
  for (int k = 0; k < 2; ++k) {
    int e = tid + k * 256;
    int row = e >> 3, d8 = e & 7;
    ushort8v a = p0[e], bb = p1[e], c = p2[e];
    float inv = 1.f / rs[row];
    int t = xt * 64 + row;
    ushort8v ov;
#pragma unroll
    for (int q = 0; q < 8; ++q)
      ov[q] = f2bf((bf2f(a[q]) + bf2f(bb[q]) + bf2f(c[q])) * inv);
    *(ushort8v*)&vec[(size_t)(t * 4 + b) * 1024 + n * 64 + d8 * 8] = ov;
  }
}

// ---------------- residual + layernorm ----------------
__global__ __launch_bounds__(256) void k_ln(const float* __restrict__ xg, const float* __restrict__ h,
                                            const float* __restrict__ gamma, const float* __restrict__ beta,
                                            float* __restrict__ out) {
  const int row = blockIdx.x;
  const int t = threadIdx.x;
  __shared__ float red1[4], red2[4];
  float4v xv = ((const float4v*)(xg + (size_t)row * 1024))[t];
  float4v hv = ((const float4v*)(h + (size_t)row * 1024))[t];
  float x0 = xv.x + hv.x, x1 = xv.y + hv.y, x2 = xv.z + hv.z, x3 = xv.w + hv.w;
  float s = x0 + x1 + x2 + x3;
#pragma unroll
  for (int off = 1; off < 64; off <<= 1) s += __shfl_xor(s, off);
  if ((t & 63) == 0) red1[t >> 6] = s;
  __syncthreads();
  float mean = (red1[0] + red1[1] + red1[2] + red1[3]) * (1.f / 1024.f);
  float d0 = x0 - mean, d1 = x1 - mean, d2 = x2 - mean, d3 = x3 - mean;
  float q = d0 * d0 + d1 * d1 + d2 * d2 + d3 * d3;
#pragma unroll
  for (int off = 1; off < 64; off <<= 1) q += __shfl_xor(q, off);
  if ((t & 63) == 0) red2[t >> 6] = q;
  __syncthreads();
  float var = (red2[0] + red2[1] + red2[2] + red2[3]) * (1.f / 1024.f);
  float rs = rsqrtf(var + 1e-5f);
  float4v gv = ((const float4v*)gamma)[t];
  float4v bv = ((const float4v*)beta)[t];
  float4v ov;
  ov.x = d0 * rs * gv.x + bv.x;
  ov.y = d1 * rs * gv.y + bv.y;
  ov.z = d2 * rs * gv.z + bv.z;
  ov.w = d3 * rs * gv.w + bv.w;
  ((float4v*)(out + (size_t)row * 1024))[t] = ov;
}

extern "C" void kernel_launch(void* const* d_in, const int* in_sizes, int n_in,
                              void* d_out, int out_size, void* d_ws, size_t ws_size,
                              hipStream_t stream) {
  (void)in_sizes; (void)n_in; (void)out_size; (void)ws_size;
  const float* h    = (const float*)d_in[0];
  const float* m    = (const float*)d_in[1];
  const float* r    = (const float*)d_in[2];
  const float* Wqkv = (const float*)d_in[4];
  const float* Wr   = (const float*)d_in[5];
  const float* Wo   = (const float*)d_in[6];
  const float* rwb  = (const float*)d_in[7];
  const float* rrb  = (const float*)d_in[8];
  const float* gam  = (const float*)d_in[9];
  const float* bet  = (const float*)d_in[10];
  float* out = (float*)d_out;

  char* ws = (char*)d_ws;
  unsigned short* catB   = (unsigned short*)(ws + 0);          // 16 MB
  unsigned short* WqkvT  = (unsigned short*)(ws + 16777216);   // 6 MB
  unsigned short* WrT    = (unsigned short*)(ws + 23068672);   // 2 MB
  unsigned short* WoT    = (unsigned short*)(ws + 25165824);   // 2 MB
  unsigned short* Vp     = (unsigned short*)(ws + 27262976);   // 16 MB
  unsigned short* po     = (unsigned short*)(ws + 44040192);   // 24 MB bf16 partials
  unsigned short* VT     = (unsigned short*)(ws + 81788928);   // 16 MB
  unsigned short* vec    = (unsigned short*)(ws + 99221504);   // 8 MB
  float* xbuf            = (float*)(ws + 107610112);           // 16 MB
  unsigned short* rB     = (unsigned short*)(ws + 124387328);  // 4 MB (reused as psumG)
  unsigned short* Kp     = (unsigned short*)(ws + 128581632);  // 16 MB
  unsigned short* Qp     = (unsigned short*)(ws + 145358848);  // 8 MB
  unsigned short* Rkp    = (unsigned short*)(ws + 153747456);  // 4 MB
  float* psumG = (float*)(ws + 124387328);                     // over dead rB

  hipLaunchKernelGGL(k_convert_all, dim3(10240), dim3(256), 0, stream, m, h, r, catB, rB);
  hipLaunchKernelGGL(k_transpose_w, dim3(96, 32, 3), dim3(256), 0, stream,
                     Wqkv, Wr, Wo, WqkvT, WrT, WoT);
  hipLaunchKernelGGL(k_gemm_qkv8, dim3(352), dim3(512), 0, stream,
                     catB, rB, WqkvT, WrT, Kp, Vp, Qp, Rkp);
  hipLaunchKernelGGL(k_vt, dim3(32, 16, 4), dim3(256), 0, stream, Vp, VT);
  hipLaunchKernelGGL(k_attn, dim3(3072), dim3(256), 0, stream, Qp, Kp, VT, Rkp, rwb, rrb, po, psumG);
  hipLaunchKernelGGL(k_ared, dim3(1024), dim3(256), 0, stream, po, psumG, vec);
  hipLaunchKernelGGL(k_gemm_o, dim3(8, 32), dim3(256), 0, stream, vec, WoT, xbuf, 4096, 1024, 1024);
  hipLaunchKernelGGL(k_ln, dim3(4096), dim3(256), 0, stream, xbuf, h, gam, bet, out);
}

// Round 19
// 302.610 us; speedup vs baseline: 1.1598x; 1.0089x over previous
//
#include <hip/hip_runtime.h>
#include <stdint.h>

#define T_LEN 1024
#define MEM_LEN 1024
#define C_LEN 2048
#define B_SZ 4
#define DM_ 1024
#define NH 16
#define HD 64

typedef __attribute__((ext_vector_type(8))) short short8;
typedef __attribute__((ext_vector_type(4))) float f32x4;
typedef __attribute__((ext_vector_type(4))) unsigned short ushort4v;
typedef __attribute__((ext_vector_type(8))) unsigned short ushort8v;
typedef __attribute__((ext_vector_type(4))) float float4v;

__device__ __forceinline__ unsigned short f2bf(float f) {
  union { float f; unsigned int u; } v; v.f = f;
  unsigned int r = v.u + 0x7fffu + ((v.u >> 16) & 1u);
  return (unsigned short)(r >> 16);
}
__device__ __forceinline__ float bf2f(unsigned short b) {
  union { unsigned int u; float f; } v; v.u = ((unsigned int)b) << 16;
  return v.f;
}
__device__ __forceinline__ unsigned int cvtpk(float lo, float hi) {
  unsigned int r;
  asm("v_cvt_pk_bf16_f32 %0, %1, %2" : "=v"(r) : "v"(lo), "v"(hi));
  return r;
}
__device__ __forceinline__ f32x4 mfma16(short8 a, short8 b, f32x4 c) {
  return __builtin_amdgcn_mfma_f32_16x16x32_bf16(a, b, c, 0, 0, 0);
}

// ---------------- fused converts: cat=[m;h] -> catB, r -> rB ----------------
__global__ void k_convert_all(const float* __restrict__ m, const float* __restrict__ h,
                              const float* __restrict__ r,
                              unsigned short* __restrict__ catB,
                              unsigned short* __restrict__ rB) {
  int idx = blockIdx.x * 256 + threadIdx.x;
  const int MQ = (MEM_LEN * B_SZ * DM_) / 4;
  const int CQ = 2 * MQ;
  float4v v;
  unsigned short* dst;
  int di;
  if (idx < MQ)      { v = ((const float4v*)m)[idx];       dst = catB; di = idx; }
  else if (idx < CQ) { v = ((const float4v*)h)[idx - MQ];  dst = catB; di = idx; }
  else               { v = ((const float4v*)r)[idx - CQ];  dst = rB;   di = idx - CQ; }
  ushort4v o;
  o.x = f2bf(v.x); o.y = f2bf(v.y); o.z = f2bf(v.z); o.w = f2bf(v.w);
  ((ushort4v*)dst)[di] = o;
}

// fused transpose of the three weights
__global__ void k_transpose_w(const float* __restrict__ Wqkv, const float* __restrict__ Wr,
                              const float* __restrict__ Wo,
                              unsigned short* __restrict__ WqkvT, unsigned short* __restrict__ WrT,
                              unsigned short* __restrict__ WoT) {
  __shared__ float tile[32][33];
  const int z = blockIdx.z;
  const int Ccols = (z == 0) ? 3072 : 1024;
  if (blockIdx.x * 32 >= Ccols) return;
  const float* in = (z == 0) ? Wqkv : (z == 1) ? Wr : Wo;
  unsigned short* out = (z == 0) ? WqkvT : (z == 1) ? WrT : WoT;
  int c0 = blockIdx.x * 32, r0 = blockIdx.y * 32;
  int tx = threadIdx.x & 31, ty = threadIdx.x >> 5;
#pragma unroll
  for (int p = 0; p < 4; ++p)
    tile[ty + 8 * p][tx] = in[(size_t)(r0 + ty + 8 * p) * Ccols + c0 + tx];
  __syncthreads();
#pragma unroll
  for (int p = 0; p < 4; ++p)
    out[(size_t)(c0 + ty + 8 * p) * 1024 + r0 + tx] = f2bf(tile[tx][ty + 8 * p]);
}

// ---------------- 8-phase 256x256 QKV+Rk GEMM (m201 template port, R18-verified) ----------
__device__ __forceinline__ void stage_half_g(const unsigned short* __restrict__ src, int ldK,
                                             unsigned short* dst, int tid) {
#pragma unroll
  for (int q = 0; q < 2; ++q) {
    int idx = q * 512 + tid;            // 0..1023
    int row = idx >> 3;                 // 0..127
    int g = idx & 7;
    int gs = g ^ (((row >> 2) & 1) << 1);  // source pre-swizzle
    __builtin_amdgcn_global_load_lds(
        (const __attribute__((address_space(1))) void*)(src + (size_t)row * ldK + gs * 8),
        (__attribute__((address_space(3))) void*)(dst + idx * 8), 16, 0, 0);
  }
}
__device__ __forceinline__ short8 frag_rd(const unsigned short* half, int row, int kg) {
  int g = kg ^ (((row >> 2) & 1) << 1);
  return *(const short8*)&half[row * 64 + g * 8];
}

__global__ __launch_bounds__(512, 2) void k_gemm_qkv8(const unsigned short* __restrict__ catB,
                                                      const unsigned short* __restrict__ rB,
                                                      const unsigned short* __restrict__ WqkvT,
                                                      const unsigned short* __restrict__ WrT,
                                                      unsigned short* __restrict__ Kp,
                                                      unsigned short* __restrict__ Vp,
                                                      unsigned short* __restrict__ Qp,
                                                      unsigned short* __restrict__ Rkp) {
  __shared__ unsigned short Ash[4][128 * 64];
  __shared__ unsigned short Bsh[4][128 * 64];
  const int tid = threadIdx.x;
  const int w = tid >> 6, l = tid & 63;
  const int wr = w >> 2, wc = w & 3;
  const int lg = l >> 4, lr = l & 15;
  const int bid = blockIdx.x;
  int mode, lpid, gx;
  const unsigned short *A, *BT;
  if (bid < 256)      { mode = 2; lpid = bid;       gx = 8; A = catB;                      BT = WqkvT + (size_t)1024 * 1024; }
  else if (bid < 320) { mode = 3; lpid = bid - 256; gx = 4; A = catB + (size_t)4096 * 1024; BT = WqkvT; }
  else                { mode = 4; lpid = bid - 320; gx = 4; A = rB;                        BT = WrT; }
  const int K = 1024, NT = 16;
  const int xcd = lpid & 7;
  const int idx = lpid >> 3;
  const int cb = idx % gx;
  const int rb = (idx / gx) * 8 + xcd;
  const int m0 = rb * 256, n0 = cb * 256;
  const unsigned short* Ab = A + (size_t)m0 * K;
  const unsigned short* Bb = BT + (size_t)n0 * K;

  f32x4 acc[8][4];
#pragma unroll
  for (int i = 0; i < 8; ++i)
#pragma unroll
    for (int j = 0; j < 4; ++j) acc[i][j] = (f32x4){0.f, 0.f, 0.f, 0.f};

  stage_half_g(Bb,                       K, Bsh[0], tid);
  stage_half_g(Bb + (size_t)128 * K,     K, Bsh[1], tid);
  stage_half_g(Ab,                       K, Ash[0], tid);
  stage_half_g(Ab + (size_t)128 * K,     K, Ash[1], tid);
  asm volatile("s_waitcnt vmcnt(4)" ::: "memory");
  stage_half_g(Bb + 64,                   K, Bsh[2], tid);
  stage_half_g(Bb + (size_t)128 * K + 64, K, Bsh[3], tid);
  stage_half_g(Ab + 64,                   K, Ash[2], tid);
  asm volatile("s_waitcnt vmcnt(6)" ::: "memory");
  __builtin_amdgcn_s_barrier();

  for (int t = 0; t < NT; ++t) {
    const unsigned short* Ah = Ash[(2 * t + wr) & 3];
    const unsigned short* Bh = Bsh[(2 * t + (wc >> 1)) & 3];
    const int brow = (wc & 1) * 64;
    short8 bf[4][2];
#pragma unroll
    for (int p = 0; p < 4; ++p) {
      if (p == 0) {
#pragma unroll
        for (int ni = 0; ni < 4; ++ni)
#pragma unroll
          for (int ks = 0; ks < 2; ++ks)
            bf[ni][ks] = frag_rd(Bh, brow + ni * 16 + lr, ks * 4 + lg);
      }
      short8 af[2][2];
#pragma unroll
      for (int j = 0; j < 2; ++j)
#pragma unroll
        for (int ks = 0; ks < 2; ++ks)
          af[j][ks] = frag_rd(Ah, (2 * p + j) * 16 + lr, ks * 4 + lg);
      if (p == 0)      { if (t + 1 < NT) stage_half_g(Ab + (size_t)128 * K + (t + 1) * 64, K, Ash[(2 * t + 3) & 3], tid); }
      else if (p == 1) { if (t + 2 < NT) stage_half_g(Bb + (t + 2) * 64,                   K, Bsh[(2 * t + 4) & 3], tid); }
      else if (p == 2) { if (t + 2 < NT) stage_half_g(Bb + (size_t)128 * K + (t + 2) * 64, K, Bsh[(2 * t + 5) & 3], tid); }
      else             { if (t + 2 < NT) stage_half_g(Ab + (t + 2) * 64,                   K, Ash[(2 * t + 4) & 3], tid); }
      __builtin_amdgcn_s_barrier();
      asm volatile("s_waitcnt lgkmcnt(0)" ::: "memory");
      __builtin_amdgcn_s_setprio(1);
#pragma unroll
      for (int j = 0; j < 2; ++j)
#pragma unroll
        for (int ni = 0; ni < 4; ++ni)
#pragma unroll
          for (int ks = 0; ks < 2; ++ks)
            acc[2 * p + j][ni] = mfma16(af[j][ks], bf[ni][ks], acc[2 * p + j][ni]);
      __builtin_amdgcn_s_setprio(0);
      if (p == 3) {
        if (t < NT - 2)       { asm volatile("s_waitcnt vmcnt(6)" ::: "memory"); }
        else if (t == NT - 2) { asm volatile("s_waitcnt vmcnt(0)" ::: "memory"); }
      }
      __builtin_amdgcn_s_barrier();
    }
  }
#pragma unroll
  for (int mi = 0; mi < 8; ++mi)
#pragma unroll
    for (int ni = 0; ni < 4; ++ni)
#pragma unroll
      for (int r = 0; r < 4; ++r) {
        int row = m0 + wr * 128 + mi * 16 + lg * 4 + r;
        int cc = n0 + wc * 64 + ni * 16 + lr;
        float val = acc[mi][ni][r];
        if (mode == 2) {
          int nn = (cc & 1023) >> 6, d = cc & 63;
          int c = row >> 2, b = row & 3;
          size_t addr = ((size_t)((b * 16 + nn) * 2048 + c)) * 64 + d;
          unsigned short* dst = (cc < 1024) ? Kp : Vp;
          dst[addr] = f2bf(val);
        } else if (mode == 3) {
          int nn = cc >> 6, d = cc & 63;
          int t2 = row >> 2, b = row & 3;
          Qp[((size_t)((b * 16 + nn) * 1024 + t2)) * 64 + d] = f2bf(val);
        } else {
          int nn = cc >> 6, d = cc & 63;
          Rkp[((size_t)(nn * 2048 + row)) * 64 + d] = f2bf(val);
        }
      }
}

// out-projection GEMM (bf16 out), 128^2 structure, XCD swizzle
__global__ __launch_bounds__(256) void k_gemm_o(const unsigned short* __restrict__ A,
                                                const unsigned short* __restrict__ BT,
                                                unsigned short* __restrict__ Cout, int M, int N, int K) {
  __shared__ unsigned short As[128 * 64];
  __shared__ unsigned short Bs[128 * 64];
  const int tid = threadIdx.x;
  const int w = tid >> 6, l = tid & 63;
  const int wm = w >> 1, wn = w & 1;
  const int lg = l >> 4, lr = l & 15;
  const int gx = gridDim.x;
  const int pid = blockIdx.y * gx + blockIdx.x;
  const int xcd = pid & 7;
  const int idx = pid >> 3;
  const int cb = idx % gx;
  const int rb = (idx / gx) * 8 + xcd;
  const int m0 = rb * 128, n0 = cb * 128;
  f32x4 acc[4][4] = {};
  const int lrow8 = l >> 3;
  const int scol = (l & 7) * 8;
  const unsigned short* Abase = A + (size_t)m0 * K;
  const unsigned short* Bbase = BT + (size_t)n0 * K;
  for (int kt = 0; kt < K; kt += 64) {
    __syncthreads();
#pragma unroll
    for (int q = 0; q < 4; ++q) {
      int chunk = w * 4 + q;
      int row = chunk * 8 + lrow8;
      __builtin_amdgcn_global_load_lds(
          (const __attribute__((address_space(1))) void*)(Abase + (size_t)row * K + kt + scol),
          (__attribute__((address_space(3))) void*)(As + chunk * 512), 16, 0, 0);
      __builtin_amdgcn_global_load_lds(
          (const __attribute__((address_space(1))) void*)(Bbase + (size_t)row * K + kt + scol),
          (__attribute__((address_space(3))) void*)(Bs + chunk * 512), 16, 0, 0);
    }
    __syncthreads();
#pragma unroll
    for (int ks = 0; ks < 2; ++ks) {
      short8 a[4], bb[4];
#pragma unroll
      for (int mi = 0; mi < 4; ++mi)
        a[mi] = *(const short8*)&As[(wm * 64 + mi * 16 + lr) * 64 + ks * 32 + lg * 8];
#pragma unroll
      for (int ni = 0; ni < 4; ++ni)
        bb[ni] = *(const short8*)&Bs[(wn * 64 + ni * 16 + lr) * 64 + ks * 32 + lg * 8];
#pragma unroll
      for (int mi = 0; mi < 4; ++mi)
#pragma unroll
        for (int ni = 0; ni < 4; ++ni)
          acc[mi][ni] = mfma16(a[mi], bb[ni], acc[mi][ni]);
    }
  }
#pragma unroll
  for (int mi = 0; mi < 4; ++mi)
#pragma unroll
    for (int ni = 0; ni < 4; ++ni)
#pragma unroll
      for (int r = 0; r < 4; ++r) {
        int row = m0 + wm * 64 + mi * 16 + lg * 4 + r;
        int cc = n0 + wn * 64 + ni * 16 + lr;
        Cout[(size_t)row * N + cc] = f2bf(acc[mi][ni][r]);
      }
}

// ---------------- V transpose: Vp[b][n][c][d] -> VT[b][n][d][c] ----------------
__global__ void k_vt(const unsigned short* __restrict__ Vp, unsigned short* __restrict__ VT) {
  __shared__ unsigned short tile[64][72];
  int c0 = blockIdx.x * 64;
  int n = blockIdx.y, b = blockIdx.z;
  int t = threadIdx.x;
  const unsigned short* src = Vp + ((size_t)((b * 16 + n) * 2048 + c0)) * 64;
#pragma unroll
  for (int p = 0; p < 16; ++p) {
    int idx = p * 256 + t;
    int r = idx >> 6, d = idx & 63;
    tile[d][r] = src[(size_t)r * 64 + d];
  }
  __syncthreads();
#pragma unroll
  for (int p = 0; p < 16; ++p) {
    int idx = p * 256 + t;
    int d = idx >> 6, c = idx & 63;
    VT[(size_t)((b * 16 + n) * 64 + d) * 2048 + c0 + c] = tile[d][c];
  }
}

// ---------------- split-j flash attention (R15/R17 best) ----------------
__device__ __forceinline__ void stage_tile(const unsigned short* __restrict__ Kbase,
                                           const unsigned short* __restrict__ Vbase,
                                           unsigned short* ksBuf, unsigned short* vsBuf,
                                           int j0, int tid) {
#pragma unroll
  for (int q = 0; q < 2; ++q) {
    int chunk = q * 256 + tid;   // 0..511
    int row = chunk >> 3;        // 0..63
    int slot = chunk & 7;
    int ss = slot ^ (row & 7);   // source pre-swizzle (rule #21)
    __builtin_amdgcn_global_load_lds(
        (const __attribute__((address_space(1))) void*)(Kbase + (size_t)(j0 + row) * 64 + ss * 8),
        (__attribute__((address_space(3))) void*)(ksBuf + chunk * 8), 16, 0, 0);
    __builtin_amdgcn_global_load_lds(
        (const __attribute__((address_space(1))) void*)(Vbase + (size_t)row * 2048 + j0 + ss * 8),
        (__attribute__((address_space(3))) void*)(vsBuf + chunk * 8), 16, 0, 0);
  }
}

__global__ __launch_bounds__(256) void k_attn(const unsigned short* __restrict__ Qp,
                                              const unsigned short* __restrict__ Kp,
                                              const unsigned short* __restrict__ VT,
                                              const unsigned short* __restrict__ Rkp,
                                              const float* __restrict__ rwb,
                                              const float* __restrict__ rrb,
                                              unsigned short* __restrict__ po,
                                              float* __restrict__ psumG) {
  __shared__ __align__(16) unsigned short Ks[2][64 * 64];
  __shared__ __align__(16) unsigned short Vs[2][64 * 64];
  __shared__ unsigned short P[4][16][72];
  const int tid = threadIdx.x;
  const int w = tid >> 6, l = tid & 63;
  const int lg = l >> 4, lr = l & 15;
  const int L = blockIdx.x;
  const int bnlo = L & 7;
  const int rest = L >> 3;
  const int bnhi = rest / 48;
  const int inner = rest - bnhi * 48;
  const int xt = inner / 3;
  const int s  = inner - xt * 3;
  const int bn = bnhi * 8 + bnlo;
  const int i0 = xt * 64;
  const int n = bn & 15, b = bn >> 4;
  const int wrow = i0 + w * 16;

  const int ntile = xt + 17;
  const int t0 = (s * ntile) / 3;
  const int t1 = ((s + 1) * ntile) / 3;

  const unsigned short* Kbase = Kp + (size_t)bn * 2048 * 64;
  const unsigned short* Vbase = VT + (size_t)bn * 64 * 2048;
  const unsigned short* Rkbase = Rkp + (size_t)n * 2048 * 64;

  short8 aq0u, aq1u, aq0v, aq1v;
  {
    const unsigned short* qp = Qp + (size_t)(bn * 1024 + wrow + lr) * 64 + lg * 8;
    short8 q0 = *(const short8*)qp;
    short8 q1 = *(const short8*)(qp + 32);
    const float* up = rwb + n * 64 + lg * 8;
    const float* vp = rrb + n * 64 + lg * 8;
#pragma unroll
    for (int e = 0; e < 8; ++e) {
      float q0f = bf2f((unsigned short)q0[e]);
      float q1f = bf2f((unsigned short)q1[e]);
      aq0u[e] = (short)f2bf(q0f + up[e]);
      aq1u[e] = (short)f2bf(q1f + up[e + 32]);
      aq0v[e] = (short)f2bf(q0f + vp[e]);
      aq1v[e] = (short)f2bf(q1f + vp[e + 32]);
    }
  }
  float psum[4];
  f32x4 o[4];
#pragma unroll
  for (int r = 0; r < 4; ++r) psum[r] = 0.f;
#pragma unroll
  for (int df = 0; df < 4; ++df) o[df] = (f32x4){0.f, 0.f, 0.f, 0.f};

  stage_tile(Kbase, Vbase, Ks[0], Vs[0], t0 * 64, tid);
  stage_tile(Kbase, Vbase, Ks[1], Vs[1], (t0 + 1) * 64, tid);

  const float EXPC = 0.18033688011112042f;

  for (int jt = t0; jt < t1; ++jt) {
    const int j0 = jt * 64;
    const int cur = (jt - t0) & 1;
    if (jt + 1 < t1) { asm volatile("s_waitcnt vmcnt(4)" ::: "memory"); }
    else             { asm volatile("s_waitcnt vmcnt(0)" ::: "memory"); }
    __builtin_amdgcn_s_barrier();

    f32x4 sac[4];
#pragma unroll
    for (int jf = 0; jf < 4; ++jf) sac[jf] = (f32x4){0.f, 0.f, 0.f, 0.f};
    __builtin_amdgcn_s_setprio(1);
#pragma unroll
    for (int jf = 0; jf < 4; ++jf) {
      int row = jf * 16 + lr;
      int rx = row & 7;
      short8 k0 = *(const short8*)&Ks[cur][row * 64 + ((lg ^ rx) * 8)];
      short8 k1 = *(const short8*)&Ks[cur][row * 64 + (((4 + lg) ^ rx) * 8)];
      sac[jf] = mfma16(aq0u, k0, sac[jf]);
      sac[jf] = mfma16(aq1u, k1, sac[jf]);
    }
    __builtin_amdgcn_s_setprio(0);
    const int kbw = j0 + 1008 - i0 - w * 16;
    f32x4 gb[5];
#pragma unroll
    for (int jg = 0; jg < 5; ++jg) {
      int rowK = kbw + jg * 16 + lr;
      short8 b0 = {}, b1 = {};
      if (rowK < C_LEN) {
        const unsigned short* rp = Rkbase + (size_t)rowK * 64 + lg * 8;
        b0 = *(const short8*)rp;
        b1 = *(const short8*)(rp + 32);
      }
      f32x4 g = (f32x4){0.f, 0.f, 0.f, 0.f};
      g = mfma16(aq0v, b0, g);
      g = mfma16(aq1v, b1, g);
      gb[jg] = g;
    }
    const bool needMask = (j0 + 63 > i0 + w * 16 + MEM_LEN);
    float p[4][4];
#pragma unroll
    for (int r = 0; r < 4; ++r) {
      const int R = lg * 4 + r;
      const int delta = lr + 15 - R;
      const int src = (l & 48) | (delta & 15);
      float v0 = __shfl(gb[0][r], src);
      float v1 = __shfl(gb[1][r], src);
      float v2 = __shfl(gb[2][r], src);
      float v3 = __shfl(gb[3][r], src);
      float v4 = __shfl(gb[4][r], src);
      const bool hi = delta >= 16;
      float bd0 = hi ? v1 : v0;
      float bd1 = hi ? v2 : v1;
      float bd2 = hi ? v3 : v2;
      float bd3 = hi ? v4 : v3;
      float e0 = exp2f((sac[0][r] + bd0) * EXPC);
      float e1 = exp2f((sac[1][r] + bd1) * EXPC);
      float e2 = exp2f((sac[2][r] + bd2) * EXPC);
      float e3 = exp2f((sac[3][r] + bd3) * EXPC);
      if (needMask) {
        const int jlim = i0 + w * 16 + R + MEM_LEN;
        int j = j0 + lr;
        e0 = (j > jlim) ? 0.f : e0;  j += 16;
        e1 = (j > jlim) ? 0.f : e1;  j += 16;
        e2 = (j > jlim) ? 0.f : e2;  j += 16;
        e3 = (j > jlim) ? 0.f : e3;
      }
      p[0][r] = e0; p[1][r] = e1; p[2][r] = e2; p[3][r] = e3;
    }
#pragma unroll
    for (int jf = 0; jf < 4; ++jf)
#pragma unroll
      for (int r = 0; r < 4; ++r) psum[r] += p[jf][r];
#pragma unroll
    for (int r = 0; r < 4; ++r) {
      unsigned int a01 = cvtpk(p[0][r], p[1][r]);
      unsigned int a23 = cvtpk(p[2][r], p[3][r]);
      const int R = lg * 4 + r;
      P[w][R][lr]      = (unsigned short)a01;
      P[w][R][16 + lr] = (unsigned short)(a01 >> 16);
      P[w][R][32 + lr] = (unsigned short)a23;
      P[w][R][48 + lr] = (unsigned short)(a23 >> 16);
    }
    __builtin_amdgcn_s_setprio(1);
#pragma unroll
    for (int ks = 0; ks < 2; ++ks) {
      short8 ap = *(const short8*)&P[w][lr][ks * 32 + lg * 8];
#pragma unroll
      for (int df = 0; df < 4; ++df) {
        int row = df * 16 + lr;
        int rx = row & 7;
        short8 vv = *(const short8*)&Vs[cur][row * 64 + (((ks * 4 + lg) ^ rx) * 8)];
        o[df] = mfma16(ap, vv, o[df]);
      }
    }
    __builtin_amdgcn_s_setprio(0);
    __builtin_amdgcn_s_barrier();
    if (jt + 2 < t1)
      stage_tile(Kbase, Vbase, Ks[cur], Vs[cur], (jt + 2) * 64, tid);
  }
  const int pbase = (bn * 16 + xt) * 3 + s;
  unsigned short* poB = po + (size_t)pbase * 4096;
#pragma unroll
  for (int r = 0; r < 4; ++r) {
    float v = psum[r];
    v += __shfl_xor(v, 1);
    v += __shfl_xor(v, 2);
    v += __shfl_xor(v, 4);
    v += __shfl_xor(v, 8);
    if (lr == 0) psumG[pbase * 64 + w * 16 + lg * 4 + r] = v;
  }
#pragma unroll
  for (int df = 0; df < 4; ++df)
#pragma unroll
    for (int r = 0; r < 4; ++r)
      poB[(w * 16 + lg * 4 + r) * 64 + df * 16 + lr] = f2bf(o[df][r]);
}

// combine split partials, normalize, emit bf16 vec[t][b][n*64+d]
__global__ __launch_bounds__(256) void k_ared(const unsigned short* __restrict__ po,
                                              const float* __restrict__ psumG,
                                              unsigned short* __restrict__ vec) {
  const int idx = blockIdx.x;
  const int tid = threadIdx.x;
  const int bn = idx >> 4, xt = idx & 15;
  const int b = bn >> 4, n = bn & 15;
  __shared__ float rs[64];
  if (tid < 64) {
    const float* q = psumG + idx * 192;
    rs[tid] = q[tid] + q[tid + 64] + q[tid + 128];
  }
  __syncthreads();
  const ushort8v* p0 = (const ushort8v*)(po + (size_t)(idx * 3 + 0) * 4096);
  const ushort8v* p1 = (const ushort8v*)(po + (size_t)(idx * 3 + 1) * 4096);
  const ushort8v* p2 = (const ushort8v*)(po + (size_t)(idx * 3 + 2) * 4096);
#pragma unroll
  for (int k = 0; k < 2; ++k) {
    int e = tid + k * 256;
    int row = e >> 3, d8 = e & 7;
    ushort8v a = p0[e], bb = p1[e], c = p2[e];
    float inv = 1.f / rs[row];
    int t = xt * 64 + row;
    ushort8v ov;
#pragma unroll
    for (int q = 0; q < 8; ++q)
      ov[q] = f2bf((bf2f(a[q]) + bf2f(bb[q]) + bf2f(c[q])) * inv);
    *(ushort8v*)&vec[(size_t)(t * 4 + b) * 1024 + n * 64 + d8 * 8] = ov;
  }
}

// ---------------- residual + layernorm (bf16 attn_out input) ----------------
__global__ __launch_bounds__(256) void k_ln(const unsigned short* __restrict__ xg,
                                            const float* __restrict__ h,
                                            const float* __restrict__ gamma, const float* __restrict__ beta,
                                            float* __restrict__ out) {
  const int row = blockIdx.x;
  const int t = threadIdx.x;
  __shared__ float red1[4], red2[4];
  ushort4v xv = ((const ushort4v*)(xg + (size_t)row * 1024))[t];
  float4v hv = ((const float4v*)(h + (size_t)row * 1024))[t];
  float x0 = bf2f(xv.x) + hv.x, x1 = bf2f(xv.y) + hv.y;
  float x2 = bf2f(xv.z) + hv.z, x3 = bf2f(xv.w) + hv.w;
  float s = x0 + x1 + x2 + x3;
#pragma unroll
  for (int off = 1; off < 64; off <<= 1) s += __shfl_xor(s, off);
  if ((t & 63) == 0) red1[t >> 6] = s;
  __syncthreads();
  float mean = (red1[0] + red1[1] + red1[2] + red1[3]) * (1.f / 1024.f);
  float d0 = x0 - mean, d1 = x1 - mean, d2 = x2 - mean, d3 = x3 - mean;
  float q = d0 * d0 + d1 * d1 + d2 * d2 + d3 * d3;
#pragma unroll
  for (int off = 1; off < 64; off <<= 1) q += __shfl_xor(q, off);
  if ((t & 63) == 0) red2[t >> 6] = q;
  __syncthreads();
  float var = (red2[0] + red2[1] + red2[2] + red2[3]) * (1.f / 1024.f);
  float rs = rsqrtf(var + 1e-5f);
  float4v gv = ((const float4v*)gamma)[t];
  float4v bv = ((const float4v*)beta)[t];
  float4v ov;
  ov.x = d0 * rs * gv.x + bv.x;
  ov.y = d1 * rs * gv.y + bv.y;
  ov.z = d2 * rs * gv.z + bv.z;
  ov.w = d3 * rs * gv.w + bv.w;
  ((float4v*)(out + (size_t)row * 1024))[t] = ov;
}

extern "C" void kernel_launch(void* const* d_in, const int* in_sizes, int n_in,
                              void* d_out, int out_size, void* d_ws, size_t ws_size,
                              hipStream_t stream) {
  (void)in_sizes; (void)n_in; (void)out_size; (void)ws_size;
  const float* h    = (const float*)d_in[0];
  const float* m    = (const float*)d_in[1];
  const float* r    = (const float*)d_in[2];
  const float* Wqkv = (const float*)d_in[4];
  const float* Wr   = (const float*)d_in[5];
  const float* Wo   = (const float*)d_in[6];
  const float* rwb  = (const float*)d_in[7];
  const float* rrb  = (const float*)d_in[8];
  const float* gam  = (const float*)d_in[9];
  const float* bet  = (const float*)d_in[10];
  float* out = (float*)d_out;

  char* ws = (char*)d_ws;
  unsigned short* catB   = (unsigned short*)(ws + 0);          // 16 MB
  unsigned short* WqkvT  = (unsigned short*)(ws + 16777216);   // 6 MB
  unsigned short* WrT    = (unsigned short*)(ws + 23068672);   // 2 MB
  unsigned short* WoT    = (unsigned short*)(ws + 25165824);   // 2 MB
  unsigned short* Vp     = (unsigned short*)(ws + 27262976);   // 16 MB
  unsigned short* po     = (unsigned short*)(ws + 44040192);   // 24 MB bf16 partials
  unsigned short* VT     = (unsigned short*)(ws + 81788928);   // 16 MB
  unsigned short* vec    = (unsigned short*)(ws + 99221504);   // 8 MB
  unsigned short* xbufB  = (unsigned short*)(ws + 107610112);  // 8 MB bf16 attn_out
  unsigned short* rB     = (unsigned short*)(ws + 124387328);  // 4 MB (reused as psumG)
  unsigned short* Kp     = (unsigned short*)(ws + 128581632);  // 16 MB
  unsigned short* Qp     = (unsigned short*)(ws + 145358848);  // 8 MB
  unsigned short* Rkp    = (unsigned short*)(ws + 153747456);  // 4 MB
  float* psumG = (float*)(ws + 124387328);                     // over dead rB

  hipLaunchKernelGGL(k_convert_all, dim3(10240), dim3(256), 0, stream, m, h, r, catB, rB);
  hipLaunchKernelGGL(k_transpose_w, dim3(96, 32, 3), dim3(256), 0, stream,
                     Wqkv, Wr, Wo, WqkvT, WrT, WoT);
  hipLaunchKernelGGL(k_gemm_qkv8, dim3(352), dim3(512), 0, stream,
                     catB, rB, WqkvT, WrT, Kp, Vp, Qp, Rkp);
  hipLaunchKernelGGL(k_vt, dim3(32, 16, 4), dim3(256), 0, stream, Vp, VT);
  hipLaunchKernelGGL(k_attn, dim3(3072), dim3(256), 0, stream, Qp, Kp, VT, Rkp, rwb, rrb, po, psumG);
  hipLaunchKernelGGL(k_ared, dim3(1024), dim3(256), 0, stream, po, psumG, vec);
  hipLaunchKernelGGL(k_gemm_o, dim3(8, 32), dim3(256), 0, stream, vec, WoT, xbufB, 4096, 1024, 1024);
  hipLaunchKernelGGL(k_ln, dim3(4096), dim3(256), 0, stream, xbufB, h, gam, bet, out);
}